// Round 1
// baseline (2733.695 us; speedup 1.0000x reference)
//
#include <hip/hip_runtime.h>
#include <math.h>

// Problem dims (fixed by reference)
#define N_NODES 50000
#define N_EDGES 500000
#define DA 64    // A
#define DR 20    // R
#define DEB 32   // EB
#define DEH 64   // EH
#define DH 4     // H
#define DC 32    // C
#define DAH 128  // AH
#define DSH 64   // SH
#define DS 32    // S
#define DAV 32   // AV
#define EIN_DIM 149  // 2A + R + 1
#define NODEIN_DIM 224 // A + H*EB + S

#define EPSC 1e-8f

__device__ __forceinline__ float siluf(float v) { return v / (1.0f + __expf(-v)); }

__device__ __forceinline__ void atomAddF(float* p, float v) {
#if defined(__HIP_DEVICE_COMPILE__)
  unsafeAtomicAdd(p, v);
#else
  atomicAdd(p, v);
#endif
}

// ---------------------------------------------------------------------------
// Pass A: per-edge geometry + RBF + edge MLP + celu logits + softmax denom
// wave-per-edge; weights staged in LDS (~60 KB)
// ---------------------------------------------------------------------------
__global__ __launch_bounds__(256) void edge_pass_a(
    const float* __restrict__ h, const float* __restrict__ x,
    const int* __restrict__ idx_i, const int* __restrict__ idx_j,
    const float* __restrict__ W_in, const float* __restrict__ b_in,
    const float* __restrict__ W_h, const float* __restrict__ b_h,
    const float* __restrict__ W_out, const float* __restrict__ b_out,
    const float* __restrict__ W_att, const float* __restrict__ b_att,
    float* __restrict__ he_out, float* __restrict__ expl_out,
    float* __restrict__ dir_out, float* __restrict__ denom,
    float* __restrict__ counts, int E, int nIter)
{
  __shared__ float sWin[128 * 20];
  __shared__ float sbin[20];
  __shared__ float sWh[EIN_DIM * 64];
  __shared__ float sbh[64];
  __shared__ float sWo[64 * 32];
  __shared__ float sbo[32];
  __shared__ float sWa[32 * 4];
  __shared__ float sba[4];
  __shared__ float ein[4][152];
  __shared__ float hid[4][64];
  __shared__ float hesh[4][32];

  const int tid = threadIdx.x;
  for (int k = tid; k < 128 * 20; k += 256) sWin[k] = W_in[k];
  for (int k = tid; k < 20; k += 256) sbin[k] = b_in[k];
  for (int k = tid; k < EIN_DIM * 64; k += 256) sWh[k] = W_h[k];
  for (int k = tid; k < 64; k += 256) sbh[k] = b_h[k];
  for (int k = tid; k < 64 * 32; k += 256) sWo[k] = W_out[k];
  for (int k = tid; k < 32; k += 256) sbo[k] = b_out[k];
  for (int k = tid; k < 32 * 4; k += 256) sWa[k] = W_att[k];
  for (int k = tid; k < 4; k += 256) sba[k] = b_att[k];
  __syncthreads();

  const int lane = tid & 63;
  const int w = tid >> 6;
  const int gw = blockIdx.x * 4 + w;
  const int stride = gridDim.x * 4;

  const float MU0 = 0.60653065971263342f;            // exp(-0.5)
  const float DMU = (1.0f - 0.60653065971263342f) / 19.0f;
  const float BETA = (float)(1.0 / (0.039346934028736658 * 0.039346934028736658));

  for (int it = 0; it < nIter; ++it) {
    const int e = gw + it * stride;
    const bool active = (e < E);
    int ii = 0;
    float d = 1.0f, rx = 0.f, ry = 0.f, rz = 0.f;
    if (active) {
      ii = idx_i[e];
      const int jj = idx_j[e];
      ein[w][lane] = h[ii * DA + lane];
      ein[w][64 + lane] = h[jj * DA + lane];
      rx = x[jj * 3 + 0] - x[ii * 3 + 0];
      ry = x[jj * 3 + 1] - x[ii * 3 + 1];
      rz = x[jj * 3 + 2] - x[ii * 3 + 2];
      d = sqrtf(rx * rx + ry * ry + rz * rz + EPSC);
      if (lane == 0) {
        const float inv = 1.0f / (d + EPSC);
        dir_out[e * 3 + 0] = rx * inv;
        dir_out[e * 3 + 1] = ry * inv;
        dir_out[e * 3 + 2] = rz * inv;
      }
    }
    __syncthreads();
    if (active) {
      if (lane < 20) {
        float acc = sbin[lane];
        #pragma unroll 8
        for (int k = 0; k < 128; ++k) acc += ein[w][k] * sWin[k * 20 + lane];
        const float mu = MU0 + (float)lane * DMU;
        const float t = __expf(-d) - mu;
        ein[w][128 + lane] = acc * __expf(-BETA * t * t);
      }
      if (lane == 0) ein[w][148] = d;  // d / SCALE, SCALE = 1
    }
    __syncthreads();
    if (active) {
      float acc = sbh[lane];
      #pragma unroll 8
      for (int k = 0; k < EIN_DIM; ++k) acc += ein[w][k] * sWh[k * 64 + lane];
      hid[w][lane] = siluf(acc);
    }
    __syncthreads();
    if (active && lane < 32) {
      float acc = sbo[lane];
      #pragma unroll 8
      for (int k = 0; k < 64; ++k) acc += hid[w][k] * sWo[k * 32 + lane];
      hesh[w][lane] = acc;
      he_out[e * 32 + lane] = acc;
    }
    __syncthreads();
    if (active) {
      if (lane < 4) {
        float acc = sba[lane];
        #pragma unroll
        for (int k = 0; k < 32; ++k) acc += hesh[w][k] * sWa[k * 4 + lane];
        // celu(alpha=2)
        const float l = (acc > 0.f) ? acc : 2.0f * (__expf(0.5f * acc) - 1.0f);
        const float el = __expf(l);
        expl_out[e * 4 + lane] = el;
        atomAddF(&denom[ii * 4 + lane], el);
      }
      if (lane == 32) atomAddF(&counts[ii], 1.0f);
    }
    __syncthreads();
  }
}

// ---------------------------------------------------------------------------
// Pass B: attention, semantic scatter-add, mix = tanh(h_sem @ W_x_mix),
// combination + velocity scatter-adds.  wave-per-edge.
// ---------------------------------------------------------------------------
__global__ __launch_bounds__(256) void edge_pass_b(
    const int* __restrict__ idx_i,
    const float* __restrict__ he_in, const float* __restrict__ expl_in,
    const float* __restrict__ dir_in, const float* __restrict__ denom,
    const float* __restrict__ W_xmix, const float* __restrict__ w_vmix,
    float* __restrict__ h_i_sem, float* __restrict__ comb_sum,
    float* __restrict__ dv_sum, int E, int nIter)
{
  __shared__ float sWx[128 * 32];
  __shared__ float swv[32];
  __shared__ float hsem[4][128];

  const int tid = threadIdx.x;
  for (int k = tid; k < 128 * 32; k += 256) sWx[k] = W_xmix[k];
  for (int k = tid; k < 32; k += 256) swv[k] = w_vmix[k];
  __syncthreads();

  const int lane = tid & 63;
  const int w = tid >> 6;
  const int gw = blockIdx.x * 4 + w;
  const int stride = gridDim.x * 4;

  for (int it = 0; it < nIter; ++it) {
    const int e = gw + it * stride;
    const bool active = (e < E);
    int ii = 0;
    if (active) {
      ii = idx_i[e];
      const float he = (lane < 32) ? he_in[e * 32 + lane] : 0.f;
      const int hh = lane >> 5;
      const float a0 = expl_in[e * 4 + hh] / (denom[ii * 4 + hh] + EPSC);
      const float a1 = expl_in[e * 4 + 2 + hh] / (denom[ii * 4 + 2 + hh] + EPSC);
      const float heb = __shfl(he, lane & 31);
      const float hs0 = a0 * heb;          // h_sem[lane]
      const float hs1 = a1 * heb;          // h_sem[64+lane]
      hsem[w][lane] = hs0;
      hsem[w][64 + lane] = hs1;
      atomAddF(&h_i_sem[(long long)ii * 128 + lane], hs0);
      atomAddF(&h_i_sem[(long long)ii * 128 + 64 + lane], hs1);
    }
    __syncthreads();
    float acc = 0.f;
    if (active) {
      const int rbase = (lane < 32) ? 0 : 64;
      const int wbase = (lane < 32) ? lane : (2048 + lane - 32);
      #pragma unroll 8
      for (int m = 0; m < 64; ++m)
        acc += hsem[w][rbase + m] * sWx[wbase + m * 32];
    }
    __syncthreads();
    if (active) {
      const float accHi = __shfl(acc, lane + 32);
      if (lane < 32) {
        const float mix = tanhf(acc + accHi);
        const float dx = dir_in[e * 3 + 0];
        const float dy = dir_in[e * 3 + 1];
        const float dz = dir_in[e * 3 + 2];
        atomAddF(&comb_sum[(long long)ii * 96 + lane * 3 + 0], dx * mix);
        atomAddF(&comb_sum[(long long)ii * 96 + lane * 3 + 1], dy * mix);
        atomAddF(&comb_sum[(long long)ii * 96 + lane * 3 + 2], dz * mix);
        float p = mix * swv[lane];
        p += __shfl_xor(p, 16);
        p += __shfl_xor(p, 8);
        p += __shfl_xor(p, 4);
        p += __shfl_xor(p, 2);
        p += __shfl_xor(p, 1);
        if (lane == 0) {
          atomAddF(&dv_sum[ii * 3 + 0], dx * p);
          atomAddF(&dv_sum[ii * 3 + 1], dy * p);
          atomAddF(&dv_sum[ii * 3 + 2], dz * p);
        }
      }
    }
    __syncthreads();
  }
}

// ---------------------------------------------------------------------------
// Pass C1: per-node spatial MLP + first node-MLP layer (W_node1 in LDS, 114KB)
// ---------------------------------------------------------------------------
__global__ __launch_bounds__(256) void node_pass_c1(
    const float* __restrict__ h, const float* __restrict__ h_i_sem,
    const float* __restrict__ comb_sum, const float* __restrict__ counts,
    const float* __restrict__ W_post1, const float* __restrict__ b_post1,
    const float* __restrict__ W_post2, const float* __restrict__ b_post2,
    const float* __restrict__ W_node1, const float* __restrict__ b_node1,
    float* __restrict__ nh_out, int N, int nIter)
{
  __shared__ float sWp1[32 * 64];
  __shared__ float sWp2[64 * 32];
  __shared__ float sW1[NODEIN_DIM * 128];
  __shared__ float sb1[128];
  __shared__ float sbp1[64];
  __shared__ float sbp2[32];
  __shared__ float nin[4][NODEIN_DIM];
  __shared__ float tmp1[4][32];
  __shared__ float tmp2[4][64];

  const int tid = threadIdx.x;
  for (int k = tid; k < 32 * 64; k += 256) sWp1[k] = W_post1[k];
  for (int k = tid; k < 64 * 32; k += 256) sWp2[k] = W_post2[k];
  for (int k = tid; k < NODEIN_DIM * 128; k += 256) sW1[k] = W_node1[k];
  for (int k = tid; k < 128; k += 256) sb1[k] = b_node1[k];
  for (int k = tid; k < 64; k += 256) sbp1[k] = b_post1[k];
  for (int k = tid; k < 32; k += 256) sbp2[k] = b_post2[k];
  __syncthreads();

  const int lane = tid & 63;
  const int w = tid >> 6;
  const int gw = blockIdx.x * 4 + w;
  const int stride = gridDim.x * 4;

  for (int it = 0; it < nIter; ++it) {
    const int n = gw + it * stride;
    const bool active = (n < N);
    if (active) {
      if (lane < 32) {
        const float inv = 1.0f / fmaxf(counts[n], 1.0f);
        const float c0 = comb_sum[(long long)n * 96 + lane * 3 + 0] * inv;
        const float c1 = comb_sum[(long long)n * 96 + lane * 3 + 1] * inv;
        const float c2 = comb_sum[(long long)n * 96 + lane * 3 + 2] * inv;
        tmp1[w][lane] = c0 * c0 + c1 * c1 + c2 * c2;
      }
      nin[w][lane] = h[n * DA + lane];
      nin[w][64 + lane] = h_i_sem[(long long)n * 128 + lane];
      nin[w][128 + lane] = h_i_sem[(long long)n * 128 + 64 + lane];
    }
    __syncthreads();
    if (active) {
      float acc = sbp1[lane];
      #pragma unroll
      for (int k = 0; k < 32; ++k) acc += tmp1[w][k] * sWp1[k * 64 + lane];
      tmp2[w][lane] = siluf(acc);
    }
    __syncthreads();
    if (active && lane < 32) {
      float acc = sbp2[lane];
      #pragma unroll 8
      for (int k = 0; k < 64; ++k) acc += tmp2[w][k] * sWp2[k * 32 + lane];
      nin[w][192 + lane] = siluf(acc);
    }
    __syncthreads();
    if (active) {
      float acc0 = sb1[lane];
      float acc1 = sb1[64 + lane];
      #pragma unroll 4
      for (int k = 0; k < NODEIN_DIM; ++k) {
        const float e = nin[w][k];
        acc0 += e * sW1[k * 128 + lane];
        acc1 += e * sW1[k * 128 + 64 + lane];
      }
      nh_out[(long long)n * 128 + lane] = siluf(acc0);
      nh_out[(long long)n * 128 + 64 + lane] = siluf(acc1);
    }
    __syncthreads();
  }
}

// ---------------------------------------------------------------------------
// Pass C2: h_upd, gate, v_upd, x_upd -> d_out
// ---------------------------------------------------------------------------
__global__ __launch_bounds__(256) void node_pass_c2(
    const float* __restrict__ h, const float* __restrict__ x,
    const float* __restrict__ v, const float* __restrict__ nh,
    const float* __restrict__ dv_sum, const float* __restrict__ counts,
    const float* __restrict__ W_node2, const float* __restrict__ b_node2,
    const float* __restrict__ W_vel1, const float* __restrict__ b_vel1,
    const float* __restrict__ W_vel2,
    float* __restrict__ out, int N, int nIter)
{
  __shared__ float sW2[128 * 64];
  __shared__ float sWv1[64 * 32];
  __shared__ float sb2[64];
  __shared__ float sbv1[32];
  __shared__ float sWv2[32];
  __shared__ float snh[4][128];
  __shared__ float shu[4][64];

  const int tid = threadIdx.x;
  for (int k = tid; k < 128 * 64; k += 256) sW2[k] = W_node2[k];
  for (int k = tid; k < 64 * 32; k += 256) sWv1[k] = W_vel1[k];
  for (int k = tid; k < 64; k += 256) sb2[k] = b_node2[k];
  for (int k = tid; k < 32; k += 256) sbv1[k] = b_vel1[k];
  for (int k = tid; k < 32; k += 256) sWv2[k] = W_vel2[k];
  __syncthreads();

  const int lane = tid & 63;
  const int w = tid >> 6;
  const int gw = blockIdx.x * 4 + w;
  const int stride = gridDim.x * 4;

  for (int it = 0; it < nIter; ++it) {
    const int n = gw + it * stride;
    const bool active = (n < N);
    if (active) {
      snh[w][lane] = nh[(long long)n * 128 + lane];
      snh[w][64 + lane] = nh[(long long)n * 128 + 64 + lane];
    }
    __syncthreads();
    if (active) {
      float acc = sb2[lane];
      #pragma unroll 8
      for (int k = 0; k < 128; ++k) acc += snh[w][k] * sW2[k * 64 + lane];
      const float hu = h[n * DA + lane] + siluf(acc);
      out[(long long)n * DA + lane] = hu;
      shu[w][lane] = hu;
    }
    __syncthreads();
    if (active) {
      float p = 0.f;
      if (lane < 32) {
        float acc = sbv1[lane];
        #pragma unroll 8
        for (int k = 0; k < 64; ++k) acc += shu[w][k] * sWv1[k * 32 + lane];
        p = siluf(acc) * sWv2[lane];
      }
      p += __shfl_xor(p, 16);
      p += __shfl_xor(p, 8);
      p += __shfl_xor(p, 4);
      p += __shfl_xor(p, 2);
      p += __shfl_xor(p, 1);
      const float s = __shfl(p, 0);
      const float gate = 2.0f / (1.0f + __expf(-s));
      if (lane < 3) {
        const float cnt = fmaxf(counts[n], 1.0f);
        const float dvx = dv_sum[n * 3 + lane] / cnt;
        const float vu = gate * v[n * 3 + lane] + dvx;
        out[(long long)N * 64 + n * 3 + lane] = x[n * 3 + lane] + vu;
        out[(long long)N * 64 + (long long)N * 3 + n * 3 + lane] = vu;
      }
    }
    __syncthreads();
  }
}

// ---------------------------------------------------------------------------
extern "C" void kernel_launch(void* const* d_in, const int* in_sizes, int n_in,
                              void* d_out, int out_size, void* d_ws, size_t ws_size,
                              hipStream_t stream) {
  const float* h   = (const float*)d_in[0];
  const float* x   = (const float*)d_in[1];
  const float* v   = (const float*)d_in[2];
  const int* idx_i = (const int*)d_in[3];
  const int* idx_j = (const int*)d_in[4];
  const float* W_edge_in  = (const float*)d_in[5];
  const float* b_edge_in  = (const float*)d_in[6];
  const float* W_edge_h   = (const float*)d_in[7];
  const float* b_edge_h   = (const float*)d_in[8];
  const float* W_edge_out = (const float*)d_in[9];
  const float* b_edge_out = (const float*)d_in[10];
  const float* W_att      = (const float*)d_in[11];
  const float* b_att      = (const float*)d_in[12];
  const float* W_x_mix    = (const float*)d_in[13];
  const float* W_node1    = (const float*)d_in[14];
  const float* b_node1    = (const float*)d_in[15];
  const float* W_node2    = (const float*)d_in[16];
  const float* b_node2    = (const float*)d_in[17];
  const float* W_post1    = (const float*)d_in[18];
  const float* b_post1    = (const float*)d_in[19];
  const float* W_post2    = (const float*)d_in[20];
  const float* b_post2    = (const float*)d_in[21];
  const float* W_vel1     = (const float*)d_in[22];
  const float* b_vel1     = (const float*)d_in[23];
  const float* W_vel2     = (const float*)d_in[24];
  const float* w_v_mix    = (const float*)d_in[25];

  const int E = in_sizes[3];
  const int N = in_sizes[0] / DA;

  float* ws = (float*)d_ws;
  size_t off = 0;
  float* denom    = ws + off; off += (size_t)N * 4;
  float* counts   = ws + off; off += (size_t)N;
  float* h_i_sem  = ws + off; off += (size_t)N * 128;
  float* comb_sum = ws + off; off += (size_t)N * 96;
  float* dv_sum   = ws + off; off += (size_t)N * 3;
  const size_t zeroBytes = off * sizeof(float);
  float* he   = ws + off; off += (size_t)E * 32;
  float* expl = ws + off; off += (size_t)E * 4;
  float* dirb = ws + off; off += (size_t)E * 3;
  float* nh   = ws + off; off += (size_t)N * 128;

  hipMemsetAsync(d_ws, 0, zeroBytes, stream);

  // Pass A
  {
    const int grid = 2048;
    const int waves = grid * 4;
    const int nIter = (E + waves - 1) / waves;
    edge_pass_a<<<grid, 256, 0, stream>>>(
        h, x, idx_i, idx_j, W_edge_in, b_edge_in, W_edge_h, b_edge_h,
        W_edge_out, b_edge_out, W_att, b_att, he, expl, dirb, denom, counts,
        E, nIter);
  }
  // Pass B
  {
    const int grid = 2048;
    const int waves = grid * 4;
    const int nIter = (E + waves - 1) / waves;
    edge_pass_b<<<grid, 256, 0, stream>>>(
        idx_i, he, expl, dirb, denom, W_x_mix, w_v_mix,
        h_i_sem, comb_sum, dv_sum, E, nIter);
  }
  // Pass C1
  {
    const int grid = 512;
    const int waves = grid * 4;
    const int nIter = (N + waves - 1) / waves;
    node_pass_c1<<<grid, 256, 0, stream>>>(
        h, h_i_sem, comb_sum, counts, W_post1, b_post1, W_post2, b_post2,
        W_node1, b_node1, nh, N, nIter);
  }
  // Pass C2
  {
    const int grid = 1024;
    const int waves = grid * 4;
    const int nIter = (N + waves - 1) / waves;
    node_pass_c2<<<grid, 256, 0, stream>>>(
        h, x, v, nh, dv_sum, counts, W_node2, b_node2, W_vel1, b_vel1, W_vel2,
        (float*)d_out, N, nIter);
  }
}

// Round 3
// 1540.724 us; speedup vs baseline: 1.7743x; 1.7743x over previous
//
#include <hip/hip_runtime.h>
#include <math.h>

// Problem dims (fixed by reference)
#define DA 64    // A
#define NODEIN_DIM 224 // A + H*EB + S

#define EPSC 1e-8f

typedef short v8s __attribute__((ext_vector_type(8)));
typedef float v4f __attribute__((ext_vector_type(4)));
typedef unsigned short ushort_t;

__device__ __forceinline__ float siluf(float v) { return v / (1.0f + __expf(-v)); }

__device__ __forceinline__ void atomAddF(float* p, float v) {
#if defined(__HIP_DEVICE_COMPILE__)
  unsafeAtomicAdd(p, v);
#else
  atomicAdd(p, v);
#endif
}

__device__ __forceinline__ unsigned short f2bfu(float f) {
  union { float f; unsigned u; } v; v.f = f;
  unsigned r = v.u + 0x7fffu + ((v.u >> 16) & 1u);
  return (unsigned short)(r >> 16);
}
__device__ __forceinline__ short f2bfs(float f) { return (short)f2bfu(f); }
__device__ __forceinline__ float bf2f(ushort_t s) {
  union { unsigned u; float f; } v; v.u = ((unsigned)s) << 16; return v.f;
}
__device__ __forceinline__ float bflo(unsigned u) {
  union { unsigned u; float f; } v; v.u = u << 16; return v.f;
}
__device__ __forceinline__ float bfhi(unsigned u) {
  union { unsigned u; float f; } v; v.u = u & 0xffff0000u; return v.f;
}

#define MU0 0.60653065971263342f
#define DMU ((1.0f - 0.60653065971263342f) / 19.0f)
#define BETA ((float)(1.0 / (0.039346934028736658 * 0.039346934028736658)))

// ---------------------------------------------------------------------------
// cast_h: h fp32 -> bf16 copy (one-time; feeds A-fragment gathers)
// ---------------------------------------------------------------------------
__global__ __launch_bounds__(256) void cast_h(
    const float* __restrict__ hsrc, ushort_t* __restrict__ hb, int n4)
{
  const int i = blockIdx.x * blockDim.x + threadIdx.x;
  if (i < n4) {
    const float4 fv = ((const float4*)hsrc)[i];
    ushort4 o;
    o.x = f2bfu(fv.x); o.y = f2bfu(fv.y); o.z = f2bfu(fv.z); o.w = f2bfu(fv.w);
    ((ushort4*)hb)[i] = o;
  }
}

// ---------------------------------------------------------------------------
// F1: gather + geometry + M1 ([E,128] x W_in[128,20]) + RBF epilogue.
// Wave per 16-edge tile. Writes Filt[E,32] bf16 (cols 0-19 filtered, 20 = d,
// 21-31 zero), dirb[E,3], counts[N].
// ---------------------------------------------------------------------------
__global__ __launch_bounds__(256) void edge_f1(
    const ushort_t* __restrict__ h_bf, const float* __restrict__ x,
    const int* __restrict__ idx_i, const int* __restrict__ idx_j,
    const float* __restrict__ W_in, const float* __restrict__ b_in,
    ushort_t* __restrict__ Filt, float* __restrict__ dirb,
    float* __restrict__ counts, int E)
{
  const int tid = blockIdx.x * blockDim.x + threadIdx.x;
  const int wid = tid >> 6;
  const int lane = threadIdx.x & 63;
  const int nw = (gridDim.x * blockDim.x) >> 6;
  const int l15 = lane & 15;
  const int q = lane >> 4;

  // B fragments (W_in fp32 -> bf16, cols >= 20 zero), loaded once.
  v8s bfr[4][2];
  #pragma unroll
  for (int kc = 0; kc < 4; ++kc)
    #pragma unroll
    for (int nt = 0; nt < 2; ++nt)
      #pragma unroll
      for (int j = 0; j < 8; ++j) {
        const int k = kc * 32 + q * 8 + j;
        const int col = nt * 16 + l15;
        bfr[kc][nt][j] = (col < 20) ? f2bfs(W_in[k * 20 + col]) : (short)0;
      }
  float bin[2], mu[2];
  #pragma unroll
  for (int nt = 0; nt < 2; ++nt) {
    const int col = nt * 16 + l15;
    bin[nt] = (col < 20) ? b_in[col] : 0.0f;
    mu[nt] = MU0 + (float)col * DMU;
  }

  const int ntiles = (E + 15) >> 4;
  for (int t = wid; t < ntiles; t += nw) {
    const int row = t * 16 + l15;
    const int rowL = (row < E) ? row : (E - 1);
    const int ii = idx_i[rowL];
    const int jj = idx_j[rowL];

    v8s afr[4];
    afr[0] = *(const v8s*)(h_bf + (size_t)ii * 64 + q * 8);
    afr[1] = *(const v8s*)(h_bf + (size_t)ii * 64 + 32 + q * 8);
    afr[2] = *(const v8s*)(h_bf + (size_t)jj * 64 + q * 8);
    afr[3] = *(const v8s*)(h_bf + (size_t)jj * 64 + 32 + q * 8);

    float dval = 0.0f;
    if (lane < 16 && row < E) {
      const float rx = x[jj * 3 + 0] - x[ii * 3 + 0];
      const float ry = x[jj * 3 + 1] - x[ii * 3 + 1];
      const float rz = x[jj * 3 + 2] - x[ii * 3 + 2];
      const float d = sqrtf(rx * rx + ry * ry + rz * rz + EPSC);
      dval = d;
      const float inv = 1.0f / (d + EPSC);
      dirb[row * 3 + 0] = rx * inv;
      dirb[row * 3 + 1] = ry * inv;
      dirb[row * 3 + 2] = rz * inv;
      atomAddF(&counts[ii], 1.0f);
    }

    v4f acc[2];
    #pragma unroll
    for (int nt = 0; nt < 2; ++nt) {
      v4f a = {0.f, 0.f, 0.f, 0.f};
      #pragma unroll
      for (int kc = 0; kc < 4; ++kc)
        a = __builtin_amdgcn_mfma_f32_16x16x32_bf16(afr[kc], bfr[kc][nt], a, 0, 0, 0);
      acc[nt] = a;
    }

    const int rowb = t * 16 + q * 4;
    float dr[4], edr[4];
    #pragma unroll
    for (int r = 0; r < 4; ++r) {
      dr[r] = __shfl(dval, q * 4 + r);
      edr[r] = __expf(-dr[r]);
    }
    #pragma unroll
    for (int nt = 0; nt < 2; ++nt) {
      const int col = nt * 16 + l15;
      #pragma unroll
      for (int r = 0; r < 4; ++r) {
        ushort_t ov;
        if (col < 20) {
          const float tt = edr[r] - mu[nt];
          ov = f2bfu((acc[nt][r] + bin[nt]) * __expf(-BETA * tt * tt));
        } else if (col == 20) {
          ov = f2bfu(dr[r]);
        } else {
          ov = 0;
        }
        if (rowb + r < E) Filt[(size_t)(rowb + r) * 32 + col] = ov;
      }
    }
  }
}

// ---------------------------------------------------------------------------
// F2: M2 ([E,160] x W_h[149(pad160),64], silu) + per-wave LDS transpose +
//     M3 ([E,64] x W_out[64,32]) -> heb[E,32] bf16.  Wave per 16-edge tile.
// ---------------------------------------------------------------------------
#define THS 72  // LDS transpose-tile row stride in ushorts (144B: 16B aligned)
__global__ __launch_bounds__(256) void edge_f2(
    const ushort_t* __restrict__ h_bf,
    const int* __restrict__ idx_i, const int* __restrict__ idx_j,
    const ushort_t* __restrict__ Filt,
    const float* __restrict__ W_h, const float* __restrict__ b_h,
    const float* __restrict__ W_out, const float* __restrict__ b_out,
    ushort_t* __restrict__ heb, int E)
{
  __shared__ ushort_t tH[4][16 * THS];

  const int tid = blockIdx.x * blockDim.x + threadIdx.x;
  const int wid = tid >> 6;
  const int lane = threadIdx.x & 63;
  const int w = threadIdx.x >> 6;
  const int nw = (gridDim.x * blockDim.x) >> 6;
  const int l15 = lane & 15;
  const int q = lane >> 4;

  // B fragments for W_h (5 k-chunks x 4 col-tiles) and W_out (2x2).
  v8s bfr2[5][4];
  #pragma unroll
  for (int kc = 0; kc < 5; ++kc)
    #pragma unroll
    for (int nt = 0; nt < 4; ++nt)
      #pragma unroll
      for (int j = 0; j < 8; ++j) {
        const int k = kc * 32 + q * 8 + j;
        const int col = nt * 16 + l15;
        bfr2[kc][nt][j] = (k < 149) ? f2bfs(W_h[k * 64 + col]) : (short)0;
      }
  v8s bfr3[2][2];
  #pragma unroll
  for (int kc = 0; kc < 2; ++kc)
    #pragma unroll
    for (int nt = 0; nt < 2; ++nt)
      #pragma unroll
      for (int j = 0; j < 8; ++j) {
        const int k = kc * 32 + q * 8 + j;
        const int col = nt * 16 + l15;
        bfr3[kc][nt][j] = f2bfs(W_out[k * 32 + col]);
      }
  float bias2[4];
  #pragma unroll
  for (int nt = 0; nt < 4; ++nt) bias2[nt] = b_h[nt * 16 + l15];
  float bias3[2];
  #pragma unroll
  for (int nt = 0; nt < 2; ++nt) bias3[nt] = b_out[nt * 16 + l15];

  const int ntiles = (E + 15) >> 4;
  for (int t = wid; t < ntiles; t += nw) {
    const int row = t * 16 + l15;
    const int rowL = (row < E) ? row : (E - 1);
    const int ii = idx_i[rowL];
    const int jj = idx_j[rowL];

    v8s afr[5];
    afr[0] = *(const v8s*)(h_bf + (size_t)ii * 64 + q * 8);
    afr[1] = *(const v8s*)(h_bf + (size_t)ii * 64 + 32 + q * 8);
    afr[2] = *(const v8s*)(h_bf + (size_t)jj * 64 + q * 8);
    afr[3] = *(const v8s*)(h_bf + (size_t)jj * 64 + 32 + q * 8);
    afr[4] = *(const v8s*)(Filt + (size_t)rowL * 32 + q * 8);

    v4f acc2[4];
    #pragma unroll
    for (int nt = 0; nt < 4; ++nt) {
      v4f a = {0.f, 0.f, 0.f, 0.f};
      #pragma unroll
      for (int kc = 0; kc < 5; ++kc)
        a = __builtin_amdgcn_mfma_f32_16x16x32_bf16(afr[kc], bfr2[kc][nt], a, 0, 0, 0);
      acc2[nt] = a;
    }

    // silu -> bf16 -> per-wave LDS transpose tile (C-layout write)
    #pragma unroll
    for (int nt = 0; nt < 4; ++nt) {
      #pragma unroll
      for (int r = 0; r < 4; ++r)
        tH[w][(q * 4 + r) * THS + nt * 16 + l15] =
            f2bfu(siluf(acc2[nt][r] + bias2[nt]));
    }
    __builtin_amdgcn_wave_barrier();  // intra-wave DS ordering (no HW inst)

    // A-layout reads back (16B-aligned b128)
    v8s af3[2];
    af3[0] = *(const v8s*)&tH[w][l15 * THS + q * 8];
    af3[1] = *(const v8s*)&tH[w][l15 * THS + 32 + q * 8];

    v4f acc3[2];
    #pragma unroll
    for (int nt = 0; nt < 2; ++nt) {
      v4f a = {0.f, 0.f, 0.f, 0.f};
      #pragma unroll
      for (int kc = 0; kc < 2; ++kc)
        a = __builtin_amdgcn_mfma_f32_16x16x32_bf16(af3[kc], bfr3[kc][nt], a, 0, 0, 0);
      acc3[nt] = a;
    }

    const int rowb = t * 16 + q * 4;
    #pragma unroll
    for (int nt = 0; nt < 2; ++nt) {
      const int col = nt * 16 + l15;
      #pragma unroll
      for (int r = 0; r < 4; ++r)
        if (rowb + r < E)
          heb[(size_t)(rowb + r) * 32 + col] = f2bfu(acc3[nt][r] + bias3[nt]);
    }
  }
}

// ---------------------------------------------------------------------------
// Att: per-edge celu logits -> exp, denom atomics (reads bf16 heb)
// ---------------------------------------------------------------------------
__global__ __launch_bounds__(256) void att_kernel(
    const ushort_t* __restrict__ heb, const int* __restrict__ idx_i,
    const float* __restrict__ W_att, const float* __restrict__ b_att,
    float* __restrict__ expl, float* __restrict__ denom, int E)
{
  __shared__ float sWa[128];
  __shared__ float sba[4];
  if (threadIdx.x < 128) sWa[threadIdx.x] = W_att[threadIdx.x];
  if (threadIdx.x < 4) sba[threadIdx.x] = b_att[threadIdx.x];
  __syncthreads();
  const int stride = gridDim.x * blockDim.x;
  for (int e = blockIdx.x * blockDim.x + threadIdx.x; e < E; e += stride) {
    float acc[4] = {sba[0], sba[1], sba[2], sba[3]};
    const int4* hv = (const int4*)(heb + (size_t)e * 32);
    #pragma unroll
    for (int blk = 0; blk < 4; ++blk) {
      const int4 pk = hv[blk];
      const unsigned uu[4] = {(unsigned)pk.x, (unsigned)pk.y,
                              (unsigned)pk.z, (unsigned)pk.w};
      #pragma unroll
      for (int u = 0; u < 4; ++u) {
        const int c = blk * 8 + u * 2;
        const float c0 = bflo(uu[u]);
        const float c1 = bfhi(uu[u]);
        #pragma unroll
        for (int tt = 0; tt < 4; ++tt)
          acc[tt] += c0 * sWa[c * 4 + tt] + c1 * sWa[(c + 1) * 4 + tt];
      }
    }
    const int ii = idx_i[e];
    float ev[4];
    #pragma unroll
    for (int tt = 0; tt < 4; ++tt) {
      const float l = (acc[tt] > 0.f) ? acc[tt]
                                      : 2.0f * (__expf(0.5f * acc[tt]) - 1.0f);
      ev[tt] = __expf(l);
    }
    float4 evv = {ev[0], ev[1], ev[2], ev[3]};
    *(float4*)(expl + (size_t)e * 4) = evv;
    #pragma unroll
    for (int tt = 0; tt < 4; ++tt) atomAddF(&denom[ii * 4 + tt], ev[tt]);
  }
}

// ---------------------------------------------------------------------------
// Pass B: attention, semantic scatter-add, mix, combination + velocity
// (he now bf16)
// ---------------------------------------------------------------------------
__global__ __launch_bounds__(256) void edge_pass_b(
    const int* __restrict__ idx_i,
    const ushort_t* __restrict__ he_in, const float* __restrict__ expl_in,
    const float* __restrict__ dir_in, const float* __restrict__ denom,
    const float* __restrict__ W_xmix, const float* __restrict__ w_vmix,
    float* __restrict__ h_i_sem, float* __restrict__ comb_sum,
    float* __restrict__ dv_sum, int E, int nIter)
{
  __shared__ float sWx[128 * 32];
  __shared__ float swv[32];
  __shared__ float hsem[4][128];

  const int tid = threadIdx.x;
  for (int k = tid; k < 128 * 32; k += 256) sWx[k] = W_xmix[k];
  for (int k = tid; k < 32; k += 256) swv[k] = w_vmix[k];
  __syncthreads();

  const int lane = tid & 63;
  const int w = tid >> 6;
  const int gw = blockIdx.x * 4 + w;
  const int stride = gridDim.x * 4;

  for (int it = 0; it < nIter; ++it) {
    const int e = gw + it * stride;
    const bool active = (e < E);
    int ii = 0;
    if (active) {
      ii = idx_i[e];
      const float he = (lane < 32) ? bf2f(he_in[(size_t)e * 32 + lane]) : 0.f;
      const int hh = lane >> 5;
      const float a0 = expl_in[e * 4 + hh] / (denom[ii * 4 + hh] + EPSC);
      const float a1 = expl_in[e * 4 + 2 + hh] / (denom[ii * 4 + 2 + hh] + EPSC);
      const float heb = __shfl(he, lane & 31);
      const float hs0 = a0 * heb;
      const float hs1 = a1 * heb;
      hsem[w][lane] = hs0;
      hsem[w][64 + lane] = hs1;
      atomAddF(&h_i_sem[(size_t)ii * 128 + lane], hs0);
      atomAddF(&h_i_sem[(size_t)ii * 128 + 64 + lane], hs1);
    }
    __syncthreads();
    float acc = 0.f;
    if (active) {
      const int rbase = (lane < 32) ? 0 : 64;
      const int wbase = (lane < 32) ? lane : (2048 + lane - 32);
      #pragma unroll 8
      for (int m = 0; m < 64; ++m)
        acc += hsem[w][rbase + m] * sWx[wbase + m * 32];
    }
    __syncthreads();
    if (active) {
      const float accHi = __shfl(acc, lane + 32);
      if (lane < 32) {
        const float mix = tanhf(acc + accHi);
        const float dx = dir_in[e * 3 + 0];
        const float dy = dir_in[e * 3 + 1];
        const float dz = dir_in[e * 3 + 2];
        atomAddF(&comb_sum[(size_t)ii * 96 + lane * 3 + 0], dx * mix);
        atomAddF(&comb_sum[(size_t)ii * 96 + lane * 3 + 1], dy * mix);
        atomAddF(&comb_sum[(size_t)ii * 96 + lane * 3 + 2], dz * mix);
        float p = mix * swv[lane];
        p += __shfl_xor(p, 16);
        p += __shfl_xor(p, 8);
        p += __shfl_xor(p, 4);
        p += __shfl_xor(p, 2);
        p += __shfl_xor(p, 1);
        if (lane == 0) {
          atomAddF(&dv_sum[ii * 3 + 0], dx * p);
          atomAddF(&dv_sum[ii * 3 + 1], dy * p);
          atomAddF(&dv_sum[ii * 3 + 2], dz * p);
        }
      }
    }
    __syncthreads();
  }
}

// ---------------------------------------------------------------------------
// Pass C1: per-node spatial MLP + first node-MLP layer (unchanged)
// ---------------------------------------------------------------------------
__global__ __launch_bounds__(256) void node_pass_c1(
    const float* __restrict__ h, const float* __restrict__ h_i_sem,
    const float* __restrict__ comb_sum, const float* __restrict__ counts,
    const float* __restrict__ W_post1, const float* __restrict__ b_post1,
    const float* __restrict__ W_post2, const float* __restrict__ b_post2,
    const float* __restrict__ W_node1, const float* __restrict__ b_node1,
    float* __restrict__ nh_out, int N, int nIter)
{
  __shared__ float sWp1[32 * 64];
  __shared__ float sWp2[64 * 32];
  __shared__ float sW1[NODEIN_DIM * 128];
  __shared__ float sb1[128];
  __shared__ float sbp1[64];
  __shared__ float sbp2[32];
  __shared__ float nin[4][NODEIN_DIM];
  __shared__ float tmp1[4][32];
  __shared__ float tmp2[4][64];

  const int tid = threadIdx.x;
  for (int k = tid; k < 32 * 64; k += 256) sWp1[k] = W_post1[k];
  for (int k = tid; k < 64 * 32; k += 256) sWp2[k] = W_post2[k];
  for (int k = tid; k < NODEIN_DIM * 128; k += 256) sW1[k] = W_node1[k];
  for (int k = tid; k < 128; k += 256) sb1[k] = b_node1[k];
  for (int k = tid; k < 64; k += 256) sbp1[k] = b_post1[k];
  for (int k = tid; k < 32; k += 256) sbp2[k] = b_post2[k];
  __syncthreads();

  const int lane = tid & 63;
  const int w = tid >> 6;
  const int gw = blockIdx.x * 4 + w;
  const int stride = gridDim.x * 4;

  for (int it = 0; it < nIter; ++it) {
    const int n = gw + it * stride;
    const bool active = (n < N);
    if (active) {
      if (lane < 32) {
        const float inv = 1.0f / fmaxf(counts[n], 1.0f);
        const float c0 = comb_sum[(size_t)n * 96 + lane * 3 + 0] * inv;
        const float c1 = comb_sum[(size_t)n * 96 + lane * 3 + 1] * inv;
        const float c2 = comb_sum[(size_t)n * 96 + lane * 3 + 2] * inv;
        tmp1[w][lane] = c0 * c0 + c1 * c1 + c2 * c2;
      }
      nin[w][lane] = h[n * DA + lane];
      nin[w][64 + lane] = h_i_sem[(size_t)n * 128 + lane];
      nin[w][128 + lane] = h_i_sem[(size_t)n * 128 + 64 + lane];
    }
    __syncthreads();
    if (active) {
      float acc = sbp1[lane];
      #pragma unroll
      for (int k = 0; k < 32; ++k) acc += tmp1[w][k] * sWp1[k * 64 + lane];
      tmp2[w][lane] = siluf(acc);
    }
    __syncthreads();
    if (active && lane < 32) {
      float acc = sbp2[lane];
      #pragma unroll 8
      for (int k = 0; k < 64; ++k) acc += tmp2[w][k] * sWp2[k * 32 + lane];
      nin[w][192 + lane] = siluf(acc);
    }
    __syncthreads();
    if (active) {
      float acc0 = sb1[lane];
      float acc1 = sb1[64 + lane];
      #pragma unroll 4
      for (int k = 0; k < NODEIN_DIM; ++k) {
        const float e = nin[w][k];
        acc0 += e * sW1[k * 128 + lane];
        acc1 += e * sW1[k * 128 + 64 + lane];
      }
      nh_out[(size_t)n * 128 + lane] = siluf(acc0);
      nh_out[(size_t)n * 128 + 64 + lane] = siluf(acc1);
    }
    __syncthreads();
  }
}

// ---------------------------------------------------------------------------
// Pass C2: h_upd, gate, v_upd, x_upd -> d_out (unchanged)
// ---------------------------------------------------------------------------
__global__ __launch_bounds__(256) void node_pass_c2(
    const float* __restrict__ h, const float* __restrict__ x,
    const float* __restrict__ v, const float* __restrict__ nh,
    const float* __restrict__ dv_sum, const float* __restrict__ counts,
    const float* __restrict__ W_node2, const float* __restrict__ b_node2,
    const float* __restrict__ W_vel1, const float* __restrict__ b_vel1,
    const float* __restrict__ W_vel2,
    float* __restrict__ out, int N, int nIter)
{
  __shared__ float sW2[128 * 64];
  __shared__ float sWv1[64 * 32];
  __shared__ float sb2[64];
  __shared__ float sbv1[32];
  __shared__ float sWv2[32];
  __shared__ float snh[4][128];
  __shared__ float shu[4][64];

  const int tid = threadIdx.x;
  for (int k = tid; k < 128 * 64; k += 256) sW2[k] = W_node2[k];
  for (int k = tid; k < 64 * 32; k += 256) sWv1[k] = W_vel1[k];
  for (int k = tid; k < 64; k += 256) sb2[k] = b_node2[k];
  for (int k = tid; k < 32; k += 256) sbv1[k] = b_vel1[k];
  for (int k = tid; k < 32; k += 256) sWv2[k] = W_vel2[k];
  __syncthreads();

  const int lane = tid & 63;
  const int w = tid >> 6;
  const int gw = blockIdx.x * 4 + w;
  const int stride = gridDim.x * 4;

  for (int it = 0; it < nIter; ++it) {
    const int n = gw + it * stride;
    const bool active = (n < N);
    if (active) {
      snh[w][lane] = nh[(size_t)n * 128 + lane];
      snh[w][64 + lane] = nh[(size_t)n * 128 + 64 + lane];
    }
    __syncthreads();
    if (active) {
      float acc = sb2[lane];
      #pragma unroll 8
      for (int k = 0; k < 128; ++k) acc += snh[w][k] * sW2[k * 64 + lane];
      const float hu = h[n * DA + lane] + siluf(acc);
      out[(size_t)n * DA + lane] = hu;
      shu[w][lane] = hu;
    }
    __syncthreads();
    if (active) {
      float p = 0.f;
      if (lane < 32) {
        float acc = sbv1[lane];
        #pragma unroll 8
        for (int k = 0; k < 64; ++k) acc += shu[w][k] * sWv1[k * 32 + lane];
        p = siluf(acc) * sWv2[lane];
      }
      p += __shfl_xor(p, 16);
      p += __shfl_xor(p, 8);
      p += __shfl_xor(p, 4);
      p += __shfl_xor(p, 2);
      p += __shfl_xor(p, 1);
      const float s = __shfl(p, 0);
      const float gate = 2.0f / (1.0f + __expf(-s));
      if (lane < 3) {
        const float cnt = fmaxf(counts[n], 1.0f);
        const float dvx = dv_sum[n * 3 + lane] / cnt;
        const float vu = gate * v[n * 3 + lane] + dvx;
        out[(size_t)N * 64 + n * 3 + lane] = x[n * 3 + lane] + vu;
        out[(size_t)N * 64 + (size_t)N * 3 + n * 3 + lane] = vu;
      }
    }
    __syncthreads();
  }
}

// ---------------------------------------------------------------------------
extern "C" void kernel_launch(void* const* d_in, const int* in_sizes, int n_in,
                              void* d_out, int out_size, void* d_ws, size_t ws_size,
                              hipStream_t stream) {
  const float* h   = (const float*)d_in[0];
  const float* x   = (const float*)d_in[1];
  const float* v   = (const float*)d_in[2];
  const int* idx_i = (const int*)d_in[3];
  const int* idx_j = (const int*)d_in[4];
  const float* W_edge_in  = (const float*)d_in[5];
  const float* b_edge_in  = (const float*)d_in[6];
  const float* W_edge_h   = (const float*)d_in[7];
  const float* b_edge_h   = (const float*)d_in[8];
  const float* W_edge_out = (const float*)d_in[9];
  const float* b_edge_out = (const float*)d_in[10];
  const float* W_att      = (const float*)d_in[11];
  const float* b_att      = (const float*)d_in[12];
  const float* W_x_mix    = (const float*)d_in[13];
  const float* W_node1    = (const float*)d_in[14];
  const float* b_node1    = (const float*)d_in[15];
  const float* W_node2    = (const float*)d_in[16];
  const float* b_node2    = (const float*)d_in[17];
  const float* W_post1    = (const float*)d_in[18];
  const float* b_post1    = (const float*)d_in[19];
  const float* W_post2    = (const float*)d_in[20];
  const float* b_post2    = (const float*)d_in[21];
  const float* W_vel1     = (const float*)d_in[22];
  const float* b_vel1     = (const float*)d_in[23];
  const float* W_vel2     = (const float*)d_in[24];
  const float* w_v_mix    = (const float*)d_in[25];

  const int E = in_sizes[3];
  const int N = in_sizes[0] / DA;

  // Workspace layout (floats).  Total ~32.7M floats = 130.8 MB
  // (round-1's 150 MB layout is proven safe; round-2's 286 MB crashed).
  float* ws = (float*)d_ws;
  size_t off = 0;
  float* denom    = ws + off; off += (size_t)N * 4;
  float* counts   = ws + off; off += (size_t)N;
  float* h_i_sem  = ws + off; off += (size_t)N * 128;
  float* comb_sum = ws + off; off += (size_t)N * 96;
  float* dv_sum   = ws + off; off += (size_t)N * 3;
  const size_t zeroBytes = off * sizeof(float);
  float* expl = ws + off; off += (size_t)E * 4;
  float* dirb = ws + off; off += (size_t)E * 3;
  float* hbfR = ws + off; off += (size_t)N * 32;      // h_bf bf16 [N,64]
  float* fltR = ws + off; off += (size_t)E * 16;      // Filt bf16 [E,32]
  float* hebR = ws + off; off += (size_t)E * 16;      // heb  bf16 [E,32]

  ushort_t* h_bf = (ushort_t*)hbfR;
  ushort_t* Filt = (ushort_t*)fltR;
  ushort_t* heb  = (ushort_t*)hebR;
  float* nh = fltR;  // aliases Filt (dead after edge_f2)

  hipMemsetAsync(d_ws, 0, zeroBytes, stream);

  {
    const int n4 = (N * 64) / 4;
    cast_h<<<(n4 + 255) / 256, 256, 0, stream>>>(h, h_bf, n4);
  }
  edge_f1<<<1024, 256, 0, stream>>>(h_bf, x, idx_i, idx_j, W_edge_in,
                                    b_edge_in, Filt, dirb, counts, E);
  edge_f2<<<1024, 256, 0, stream>>>(h_bf, idx_i, idx_j, Filt, W_edge_h,
                                    b_edge_h, W_edge_out, b_edge_out, heb, E);
  att_kernel<<<1024, 256, 0, stream>>>(heb, idx_i, W_att, b_att, expl, denom, E);

  {
    const int grid = 2048;
    const int nIter = (E + grid * 4 - 1) / (grid * 4);
    edge_pass_b<<<grid, 256, 0, stream>>>(
        idx_i, heb, expl, dirb, denom, W_x_mix, w_v_mix,
        h_i_sem, comb_sum, dv_sum, E, nIter);
  }
  {
    const int grid = 512;
    const int nIter = (N + grid * 4 - 1) / (grid * 4);
    node_pass_c1<<<grid, 256, 0, stream>>>(
        h, h_i_sem, comb_sum, counts, W_post1, b_post1, W_post2, b_post2,
        W_node1, b_node1, nh, N, nIter);
  }
  {
    const int grid = 1024;
    const int nIter = (N + grid * 4 - 1) / (grid * 4);
    node_pass_c2<<<grid, 256, 0, stream>>>(
        h, x, v, nh, dv_sum, counts, W_node2, b_node2, W_vel1, b_vel1, W_vel2,
        (float*)d_out, N, nIter);
  }
}

// Round 4
// 1087.756 us; speedup vs baseline: 2.5132x; 1.4164x over previous
//
#include <hip/hip_runtime.h>
#include <math.h>

// Problem dims (fixed by reference)
#define DA 64    // A
#define NODEIN_DIM 224 // A + H*EB + S

#define EPSC 1e-8f

typedef short v8s __attribute__((ext_vector_type(8)));
typedef float v4f __attribute__((ext_vector_type(4)));
typedef unsigned short ushort_t;

__device__ __forceinline__ float siluf(float v) { return v / (1.0f + __expf(-v)); }

__device__ __forceinline__ void atomAddF(float* p, float v) {
#if defined(__HIP_DEVICE_COMPILE__)
  unsafeAtomicAdd(p, v);
#else
  atomicAdd(p, v);
#endif
}

__device__ __forceinline__ unsigned short f2bfu(float f) {
  union { float f; unsigned u; } v; v.f = f;
  unsigned r = v.u + 0x7fffu + ((v.u >> 16) & 1u);
  return (unsigned short)(r >> 16);
}
__device__ __forceinline__ short f2bfs(float f) { return (short)f2bfu(f); }
__device__ __forceinline__ float bf2f(ushort_t s) {
  union { unsigned u; float f; } v; v.u = ((unsigned)s) << 16; return v.f;
}
__device__ __forceinline__ float bflo(unsigned u) {
  union { unsigned u; float f; } v; v.u = u << 16; return v.f;
}
__device__ __forceinline__ float bfhi(unsigned u) {
  union { unsigned u; float f; } v; v.u = u & 0xffff0000u; return v.f;
}

#define MU0 0.60653065971263342f
#define DMU ((1.0f - 0.60653065971263342f) / 19.0f)
#define BETA ((float)(1.0 / (0.039346934028736658 * 0.039346934028736658)))

// ---------------------------------------------------------------------------
// cast_h: h fp32 -> bf16 copy
// ---------------------------------------------------------------------------
__global__ __launch_bounds__(256) void cast_h(
    const float* __restrict__ hsrc, ushort_t* __restrict__ hb, int n4)
{
  const int i = blockIdx.x * blockDim.x + threadIdx.x;
  if (i < n4) {
    const float4 fv = ((const float4*)hsrc)[i];
    ushort4 o;
    o.x = f2bfu(fv.x); o.y = f2bfu(fv.y); o.z = f2bfu(fv.z); o.w = f2bfu(fv.w);
    ((ushort4*)hb)[i] = o;
  }
}

// ---------------------------------------------------------------------------
// F1: gather + geometry + M1 ([E,128] x W_in[128,20]) + RBF epilogue.
// Writes Filt[E,32] bf16, dirb[E,3], deg[N] (int).
// ---------------------------------------------------------------------------
__global__ __launch_bounds__(256) void edge_f1(
    const ushort_t* __restrict__ h_bf, const float* __restrict__ x,
    const int* __restrict__ idx_i, const int* __restrict__ idx_j,
    const float* __restrict__ W_in, const float* __restrict__ b_in,
    ushort_t* __restrict__ Filt, float* __restrict__ dirb,
    int* __restrict__ deg, int E)
{
  const int tid = blockIdx.x * blockDim.x + threadIdx.x;
  const int wid = tid >> 6;
  const int lane = threadIdx.x & 63;
  const int nw = (gridDim.x * blockDim.x) >> 6;
  const int l15 = lane & 15;
  const int q = lane >> 4;

  v8s bfr[4][2];
  #pragma unroll
  for (int kc = 0; kc < 4; ++kc)
    #pragma unroll
    for (int nt = 0; nt < 2; ++nt)
      #pragma unroll
      for (int j = 0; j < 8; ++j) {
        const int k = kc * 32 + q * 8 + j;
        const int col = nt * 16 + l15;
        bfr[kc][nt][j] = (col < 20) ? f2bfs(W_in[k * 20 + col]) : (short)0;
      }
  float bin[2], mu[2];
  #pragma unroll
  for (int nt = 0; nt < 2; ++nt) {
    const int col = nt * 16 + l15;
    bin[nt] = (col < 20) ? b_in[col] : 0.0f;
    mu[nt] = MU0 + (float)col * DMU;
  }

  const int ntiles = (E + 15) >> 4;
  for (int t = wid; t < ntiles; t += nw) {
    const int row = t * 16 + l15;
    const int rowL = (row < E) ? row : (E - 1);
    const int ii = idx_i[rowL];
    const int jj = idx_j[rowL];

    v8s afr[4];
    afr[0] = *(const v8s*)(h_bf + (size_t)ii * 64 + q * 8);
    afr[1] = *(const v8s*)(h_bf + (size_t)ii * 64 + 32 + q * 8);
    afr[2] = *(const v8s*)(h_bf + (size_t)jj * 64 + q * 8);
    afr[3] = *(const v8s*)(h_bf + (size_t)jj * 64 + 32 + q * 8);

    float dval = 0.0f;
    if (lane < 16 && row < E) {
      const float rx = x[jj * 3 + 0] - x[ii * 3 + 0];
      const float ry = x[jj * 3 + 1] - x[ii * 3 + 1];
      const float rz = x[jj * 3 + 2] - x[ii * 3 + 2];
      const float d = sqrtf(rx * rx + ry * ry + rz * rz + EPSC);
      dval = d;
      const float inv = 1.0f / (d + EPSC);
      dirb[row * 3 + 0] = rx * inv;
      dirb[row * 3 + 1] = ry * inv;
      dirb[row * 3 + 2] = rz * inv;
      atomicAdd(&deg[ii], 1);
    }

    v4f acc[2];
    #pragma unroll
    for (int nt = 0; nt < 2; ++nt) {
      v4f a = {0.f, 0.f, 0.f, 0.f};
      #pragma unroll
      for (int kc = 0; kc < 4; ++kc)
        a = __builtin_amdgcn_mfma_f32_16x16x32_bf16(afr[kc], bfr[kc][nt], a, 0, 0, 0);
      acc[nt] = a;
    }

    const int rowb = t * 16 + q * 4;
    float dr[4], edr[4];
    #pragma unroll
    for (int r = 0; r < 4; ++r) {
      dr[r] = __shfl(dval, q * 4 + r);
      edr[r] = __expf(-dr[r]);
    }
    #pragma unroll
    for (int nt = 0; nt < 2; ++nt) {
      const int col = nt * 16 + l15;
      #pragma unroll
      for (int r = 0; r < 4; ++r) {
        ushort_t ov;
        if (col < 20) {
          const float tt = edr[r] - mu[nt];
          ov = f2bfu((acc[nt][r] + bin[nt]) * __expf(-BETA * tt * tt));
        } else if (col == 20) {
          ov = f2bfu(dr[r]);
        } else {
          ov = 0;
        }
        if (rowb + r < E) Filt[(size_t)(rowb + r) * 32 + col] = ov;
      }
    }
  }
}

// ---------------------------------------------------------------------------
// F2: M2 ([E,160] x W_h, silu) + LDS transpose + M3 -> heb[E,32] bf16
// ---------------------------------------------------------------------------
#define THS 72
__global__ __launch_bounds__(256) void edge_f2(
    const ushort_t* __restrict__ h_bf,
    const int* __restrict__ idx_i, const int* __restrict__ idx_j,
    const ushort_t* __restrict__ Filt,
    const float* __restrict__ W_h, const float* __restrict__ b_h,
    const float* __restrict__ W_out, const float* __restrict__ b_out,
    ushort_t* __restrict__ heb, int E)
{
  __shared__ ushort_t tH[4][16 * THS];

  const int tid = blockIdx.x * blockDim.x + threadIdx.x;
  const int wid = tid >> 6;
  const int lane = threadIdx.x & 63;
  const int w = threadIdx.x >> 6;
  const int nw = (gridDim.x * blockDim.x) >> 6;
  const int l15 = lane & 15;
  const int q = lane >> 4;

  v8s bfr2[5][4];
  #pragma unroll
  for (int kc = 0; kc < 5; ++kc)
    #pragma unroll
    for (int nt = 0; nt < 4; ++nt)
      #pragma unroll
      for (int j = 0; j < 8; ++j) {
        const int k = kc * 32 + q * 8 + j;
        const int col = nt * 16 + l15;
        bfr2[kc][nt][j] = (k < 149) ? f2bfs(W_h[k * 64 + col]) : (short)0;
      }
  v8s bfr3[2][2];
  #pragma unroll
  for (int kc = 0; kc < 2; ++kc)
    #pragma unroll
    for (int nt = 0; nt < 2; ++nt)
      #pragma unroll
      for (int j = 0; j < 8; ++j) {
        const int k = kc * 32 + q * 8 + j;
        const int col = nt * 16 + l15;
        bfr3[kc][nt][j] = f2bfs(W_out[k * 32 + col]);
      }
  float bias2[4];
  #pragma unroll
  for (int nt = 0; nt < 4; ++nt) bias2[nt] = b_h[nt * 16 + l15];
  float bias3[2];
  #pragma unroll
  for (int nt = 0; nt < 2; ++nt) bias3[nt] = b_out[nt * 16 + l15];

  const int ntiles = (E + 15) >> 4;
  for (int t = wid; t < ntiles; t += nw) {
    const int row = t * 16 + l15;
    const int rowL = (row < E) ? row : (E - 1);
    const int ii = idx_i[rowL];
    const int jj = idx_j[rowL];

    v8s afr[5];
    afr[0] = *(const v8s*)(h_bf + (size_t)ii * 64 + q * 8);
    afr[1] = *(const v8s*)(h_bf + (size_t)ii * 64 + 32 + q * 8);
    afr[2] = *(const v8s*)(h_bf + (size_t)jj * 64 + q * 8);
    afr[3] = *(const v8s*)(h_bf + (size_t)jj * 64 + 32 + q * 8);
    afr[4] = *(const v8s*)(Filt + (size_t)rowL * 32 + q * 8);

    v4f acc2[4];
    #pragma unroll
    for (int nt = 0; nt < 4; ++nt) {
      v4f a = {0.f, 0.f, 0.f, 0.f};
      #pragma unroll
      for (int kc = 0; kc < 5; ++kc)
        a = __builtin_amdgcn_mfma_f32_16x16x32_bf16(afr[kc], bfr2[kc][nt], a, 0, 0, 0);
      acc2[nt] = a;
    }

    #pragma unroll
    for (int nt = 0; nt < 4; ++nt) {
      #pragma unroll
      for (int r = 0; r < 4; ++r)
        tH[w][(q * 4 + r) * THS + nt * 16 + l15] =
            f2bfu(siluf(acc2[nt][r] + bias2[nt]));
    }
    __builtin_amdgcn_wave_barrier();

    v8s af3[2];
    af3[0] = *(const v8s*)&tH[w][l15 * THS + q * 8];
    af3[1] = *(const v8s*)&tH[w][l15 * THS + 32 + q * 8];

    v4f acc3[2];
    #pragma unroll
    for (int nt = 0; nt < 2; ++nt) {
      v4f a = {0.f, 0.f, 0.f, 0.f};
      #pragma unroll
      for (int kc = 0; kc < 2; ++kc)
        a = __builtin_amdgcn_mfma_f32_16x16x32_bf16(af3[kc], bfr3[kc][nt], a, 0, 0, 0);
      acc3[nt] = a;
    }

    const int rowb = t * 16 + q * 4;
    #pragma unroll
    for (int nt = 0; nt < 2; ++nt) {
      const int col = nt * 16 + l15;
      #pragma unroll
      for (int r = 0; r < 4; ++r)
        if (rowb + r < E)
          heb[(size_t)(rowb + r) * 32 + col] = f2bfu(acc3[nt][r] + bias3[nt]);
    }
  }
}

// ---------------------------------------------------------------------------
// Att: per-edge celu logits -> exp, denom atomics
// ---------------------------------------------------------------------------
__global__ __launch_bounds__(256) void att_kernel(
    const ushort_t* __restrict__ heb, const int* __restrict__ idx_i,
    const float* __restrict__ W_att, const float* __restrict__ b_att,
    float* __restrict__ expl, float* __restrict__ denom, int E)
{
  __shared__ float sWa[128];
  __shared__ float sba[4];
  if (threadIdx.x < 128) sWa[threadIdx.x] = W_att[threadIdx.x];
  if (threadIdx.x < 4) sba[threadIdx.x] = b_att[threadIdx.x];
  __syncthreads();
  const int stride = gridDim.x * blockDim.x;
  for (int e = blockIdx.x * blockDim.x + threadIdx.x; e < E; e += stride) {
    float acc[4] = {sba[0], sba[1], sba[2], sba[3]};
    const int4* hv = (const int4*)(heb + (size_t)e * 32);
    #pragma unroll
    for (int blk = 0; blk < 4; ++blk) {
      const int4 pk = hv[blk];
      const unsigned uu[4] = {(unsigned)pk.x, (unsigned)pk.y,
                              (unsigned)pk.z, (unsigned)pk.w};
      #pragma unroll
      for (int u = 0; u < 4; ++u) {
        const int c = blk * 8 + u * 2;
        const float c0 = bflo(uu[u]);
        const float c1 = bfhi(uu[u]);
        #pragma unroll
        for (int tt = 0; tt < 4; ++tt)
          acc[tt] += c0 * sWa[c * 4 + tt] + c1 * sWa[(c + 1) * 4 + tt];
      }
    }
    const int ii = idx_i[e];
    float ev[4];
    #pragma unroll
    for (int tt = 0; tt < 4; ++tt) {
      const float l = (acc[tt] > 0.f) ? acc[tt]
                                      : 2.0f * (__expf(0.5f * acc[tt]) - 1.0f);
      ev[tt] = __expf(l);
    }
    float4 evv = {ev[0], ev[1], ev[2], ev[3]};
    *(float4*)(expl + (size_t)e * 4) = evv;
    #pragma unroll
    for (int tt = 0; tt < 4; ++tt) atomAddF(&denom[ii * 4 + tt], ev[tt]);
  }
}

// ---------------------------------------------------------------------------
// scan_csr: exclusive prefix-sum of deg -> rowstart, cursor, counts (float)
// ONE block, 256 threads.
// ---------------------------------------------------------------------------
__global__ __launch_bounds__(256) void scan_csr(
    const int* __restrict__ deg, int* __restrict__ rowstart,
    int* __restrict__ cursor, float* __restrict__ counts, int N)
{
  __shared__ int partial[256];
  __shared__ int base[256];
  const int t = threadIdx.x;
  const int chunk = (N + 255) / 256;
  const int lo = t * chunk;
  const int hi = (lo + chunk < N) ? (lo + chunk) : N;
  int s = 0;
  for (int i = lo; i < hi; ++i) s += deg[i];
  partial[t] = s;
  __syncthreads();
  if (t == 0) {
    int acc = 0;
    for (int i = 0; i < 256; ++i) { base[i] = acc; acc += partial[i]; }
  }
  __syncthreads();
  int acc = base[t];
  for (int i = lo; i < hi; ++i) {
    rowstart[i] = acc;
    cursor[i] = acc;
    counts[i] = (float)deg[i];
    acc += deg[i];
  }
  if (t == 255) rowstart[N] = acc;
}

// ---------------------------------------------------------------------------
// bucket_edges: perm[pos] = e, pos from cursor atomics
// ---------------------------------------------------------------------------
__global__ __launch_bounds__(256) void bucket_edges(
    const int* __restrict__ idx_i, int* __restrict__ cursor,
    int* __restrict__ perm, int E)
{
  const int stride = gridDim.x * blockDim.x;
  for (int e = blockIdx.x * blockDim.x + threadIdx.x; e < E; e += stride) {
    const int pos = atomicAdd(&cursor[idx_i[e]], 1);
    perm[pos] = e;
  }
}

// ---------------------------------------------------------------------------
// mix_kernel: per-edge A = att (x) he  ->  MFMA [E,128] x W_x_mix[128,32]
//   -> tanh -> mixE[E,32] bf16;  p = mix . w_vmix -> pE[E]
// ---------------------------------------------------------------------------
__global__ __launch_bounds__(256) void mix_kernel(
    const ushort_t* __restrict__ heb, const int* __restrict__ idx_i,
    const float* __restrict__ expl, const float* __restrict__ denom,
    const float* __restrict__ W_xmix, const float* __restrict__ w_vmix,
    ushort_t* __restrict__ mixE, float* __restrict__ pE, int E)
{
  const int tid = blockIdx.x * blockDim.x + threadIdx.x;
  const int wid = tid >> 6;
  const int lane = threadIdx.x & 63;
  const int nw = (gridDim.x * blockDim.x) >> 6;
  const int l15 = lane & 15;
  const int q = lane >> 4;

  v8s bfr[4][2];
  #pragma unroll
  for (int kc = 0; kc < 4; ++kc)
    #pragma unroll
    for (int nt = 0; nt < 2; ++nt)
      #pragma unroll
      for (int j = 0; j < 8; ++j) {
        const int k = kc * 32 + q * 8 + j;
        const int col = nt * 16 + l15;
        bfr[kc][nt][j] = f2bfs(W_xmix[k * 32 + col]);
      }
  float wv[2];
  wv[0] = w_vmix[l15];
  wv[1] = w_vmix[16 + l15];

  const int ntiles = (E + 15) >> 4;
  for (int t = wid; t < ntiles; t += nw) {
    const int row = t * 16 + l15;
    const int rowL = (row < E) ? row : (E - 1);
    const int ii = idx_i[rowL];
    float att[4];
    #pragma unroll
    for (int hh = 0; hh < 4; ++hh)
      att[hh] = expl[(size_t)rowL * 4 + hh] / (denom[ii * 4 + hh] + EPSC);

    const v8s hech = *(const v8s*)(heb + (size_t)rowL * 32 + q * 8);
    float hef[8];
    #pragma unroll
    for (int j = 0; j < 8; ++j) hef[j] = bf2f((ushort_t)hech[j]);

    v8s afr[4];
    #pragma unroll
    for (int kc = 0; kc < 4; ++kc)
      #pragma unroll
      for (int j = 0; j < 8; ++j)
        afr[kc][j] = f2bfs(att[kc] * hef[j]);

    v4f acc[2];
    #pragma unroll
    for (int nt = 0; nt < 2; ++nt) {
      v4f a = {0.f, 0.f, 0.f, 0.f};
      #pragma unroll
      for (int kc = 0; kc < 4; ++kc)
        a = __builtin_amdgcn_mfma_f32_16x16x32_bf16(afr[kc], bfr[kc][nt], a, 0, 0, 0);
      acc[nt] = a;
    }

    const int rowb = t * 16 + q * 4;
    float pr[4];
    #pragma unroll
    for (int r = 0; r < 4; ++r) {
      const float m0 = tanhf(acc[0][r]);
      const float m1 = tanhf(acc[1][r]);
      if (rowb + r < E) {
        mixE[(size_t)(rowb + r) * 32 + l15] = f2bfu(m0);
        mixE[(size_t)(rowb + r) * 32 + 16 + l15] = f2bfu(m1);
      }
      pr[r] = m0 * wv[0] + m1 * wv[1];
    }
    // reduce over the 16 lanes (l15) holding the same row
    #pragma unroll
    for (int r = 0; r < 4; ++r) {
      pr[r] += __shfl_xor(pr[r], 1);
      pr[r] += __shfl_xor(pr[r], 2);
      pr[r] += __shfl_xor(pr[r], 4);
      pr[r] += __shfl_xor(pr[r], 8);
      if (l15 == 0 && rowb + r < E) pE[rowb + r] = pr[r];
    }
  }
}

// ---------------------------------------------------------------------------
// node_reduce: wave per node, CSR gather-reduce.  NO atomics.
//   h_i_sem[n,128], comb_sum[n,32,3], dv_sum[n,3]
// ---------------------------------------------------------------------------
__global__ __launch_bounds__(256) void node_reduce(
    const int* __restrict__ rowstart, const int* __restrict__ perm,
    const ushort_t* __restrict__ heb, const ushort_t* __restrict__ mixE,
    const float* __restrict__ expl, const float* __restrict__ denom,
    const float* __restrict__ dirb, const float* __restrict__ pE,
    float* __restrict__ h_i_sem, float* __restrict__ comb_sum,
    float* __restrict__ dv_sum, int N)
{
  const int tid = blockIdx.x * blockDim.x + threadIdx.x;
  const int wid = tid >> 6;
  const int lane = threadIdx.x & 63;
  const int nw = (gridDim.x * blockDim.x) >> 6;
  const int hh = lane >> 5;   // head pair selector
  const int eb = lane & 31;

  for (int n = wid; n < N; n += nw) {
    const int s = rowstart[n];
    const int epd = rowstart[n + 1];
    float semA = 0.f, semB = 0.f;
    float cx = 0.f, cy = 0.f, cz = 0.f;
    float dvx = 0.f, dvy = 0.f, dvz = 0.f;
    for (int k = s; k < epd; ++k) {
      const int e = perm[k];
      const float he = bf2f(heb[(size_t)e * 32 + eb]);
      const float ea = expl[(size_t)e * 4 + hh];
      const float ec = expl[(size_t)e * 4 + 2 + hh];
      semA += ea * he;
      semB += ec * he;
      const float dx = dirb[e * 3 + 0];
      const float dy = dirb[e * 3 + 1];
      const float dz = dirb[e * 3 + 2];
      if (lane < 32) {
        const float m = bf2f(mixE[(size_t)e * 32 + lane]);
        cx += dx * m; cy += dy * m; cz += dz * m;
      }
      if (lane == 0) {
        const float pe = pE[e];
        dvx += dx * pe; dvy += dy * pe; dvz += dz * pe;
      }
    }
    const float dA = denom[n * 4 + hh] + EPSC;
    const float dB = denom[n * 4 + 2 + hh] + EPSC;
    h_i_sem[(size_t)n * 128 + lane] = semA / dA;
    h_i_sem[(size_t)n * 128 + 64 + lane] = semB / dB;
    if (lane < 32) {
      comb_sum[(size_t)n * 96 + lane * 3 + 0] = cx;
      comb_sum[(size_t)n * 96 + lane * 3 + 1] = cy;
      comb_sum[(size_t)n * 96 + lane * 3 + 2] = cz;
    }
    if (lane == 0) {
      dv_sum[n * 3 + 0] = dvx;
      dv_sum[n * 3 + 1] = dvy;
      dv_sum[n * 3 + 2] = dvz;
    }
  }
}

// ---------------------------------------------------------------------------
// Pass C1: per-node spatial MLP + first node-MLP layer
// ---------------------------------------------------------------------------
__global__ __launch_bounds__(256) void node_pass_c1(
    const float* __restrict__ h, const float* __restrict__ h_i_sem,
    const float* __restrict__ comb_sum, const float* __restrict__ counts,
    const float* __restrict__ W_post1, const float* __restrict__ b_post1,
    const float* __restrict__ W_post2, const float* __restrict__ b_post2,
    const float* __restrict__ W_node1, const float* __restrict__ b_node1,
    float* __restrict__ nh_out, int N, int nIter)
{
  __shared__ float sWp1[32 * 64];
  __shared__ float sWp2[64 * 32];
  __shared__ float sW1[NODEIN_DIM * 128];
  __shared__ float sb1[128];
  __shared__ float sbp1[64];
  __shared__ float sbp2[32];
  __shared__ float nin[4][NODEIN_DIM];
  __shared__ float tmp1[4][32];
  __shared__ float tmp2[4][64];

  const int tid = threadIdx.x;
  for (int k = tid; k < 32 * 64; k += 256) sWp1[k] = W_post1[k];
  for (int k = tid; k < 64 * 32; k += 256) sWp2[k] = W_post2[k];
  for (int k = tid; k < NODEIN_DIM * 128; k += 256) sW1[k] = W_node1[k];
  for (int k = tid; k < 128; k += 256) sb1[k] = b_node1[k];
  for (int k = tid; k < 64; k += 256) sbp1[k] = b_post1[k];
  for (int k = tid; k < 32; k += 256) sbp2[k] = b_post2[k];
  __syncthreads();

  const int lane = tid & 63;
  const int w = tid >> 6;
  const int gw = blockIdx.x * 4 + w;
  const int stride = gridDim.x * 4;

  for (int it = 0; it < nIter; ++it) {
    const int n = gw + it * stride;
    const bool active = (n < N);
    if (active) {
      if (lane < 32) {
        const float inv = 1.0f / fmaxf(counts[n], 1.0f);
        const float c0 = comb_sum[(size_t)n * 96 + lane * 3 + 0] * inv;
        const float c1 = comb_sum[(size_t)n * 96 + lane * 3 + 1] * inv;
        const float c2 = comb_sum[(size_t)n * 96 + lane * 3 + 2] * inv;
        tmp1[w][lane] = c0 * c0 + c1 * c1 + c2 * c2;
      }
      nin[w][lane] = h[n * DA + lane];
      nin[w][64 + lane] = h_i_sem[(size_t)n * 128 + lane];
      nin[w][128 + lane] = h_i_sem[(size_t)n * 128 + 64 + lane];
    }
    __syncthreads();
    if (active) {
      float acc = sbp1[lane];
      #pragma unroll
      for (int k = 0; k < 32; ++k) acc += tmp1[w][k] * sWp1[k * 64 + lane];
      tmp2[w][lane] = siluf(acc);
    }
    __syncthreads();
    if (active && lane < 32) {
      float acc = sbp2[lane];
      #pragma unroll 8
      for (int k = 0; k < 64; ++k) acc += tmp2[w][k] * sWp2[k * 32 + lane];
      nin[w][192 + lane] = siluf(acc);
    }
    __syncthreads();
    if (active) {
      float acc0 = sb1[lane];
      float acc1 = sb1[64 + lane];
      #pragma unroll 4
      for (int k = 0; k < NODEIN_DIM; ++k) {
        const float e = nin[w][k];
        acc0 += e * sW1[k * 128 + lane];
        acc1 += e * sW1[k * 128 + 64 + lane];
      }
      nh_out[(size_t)n * 128 + lane] = siluf(acc0);
      nh_out[(size_t)n * 128 + 64 + lane] = siluf(acc1);
    }
    __syncthreads();
  }
}

// ---------------------------------------------------------------------------
// Pass C2: h_upd, gate, v_upd, x_upd -> d_out
// ---------------------------------------------------------------------------
__global__ __launch_bounds__(256) void node_pass_c2(
    const float* __restrict__ h, const float* __restrict__ x,
    const float* __restrict__ v, const float* __restrict__ nh,
    const float* __restrict__ dv_sum, const float* __restrict__ counts,
    const float* __restrict__ W_node2, const float* __restrict__ b_node2,
    const float* __restrict__ W_vel1, const float* __restrict__ b_vel1,
    const float* __restrict__ W_vel2,
    float* __restrict__ out, int N, int nIter)
{
  __shared__ float sW2[128 * 64];
  __shared__ float sWv1[64 * 32];
  __shared__ float sb2[64];
  __shared__ float sbv1[32];
  __shared__ float sWv2[32];
  __shared__ float snh[4][128];
  __shared__ float shu[4][64];

  const int tid = threadIdx.x;
  for (int k = tid; k < 128 * 64; k += 256) sW2[k] = W_node2[k];
  for (int k = tid; k < 64 * 32; k += 256) sWv1[k] = W_vel1[k];
  for (int k = tid; k < 64; k += 256) sb2[k] = b_node2[k];
  for (int k = tid; k < 32; k += 256) sbv1[k] = b_vel1[k];
  for (int k = tid; k < 32; k += 256) sWv2[k] = W_vel2[k];
  __syncthreads();

  const int lane = tid & 63;
  const int w = tid >> 6;
  const int gw = blockIdx.x * 4 + w;
  const int stride = gridDim.x * 4;

  for (int it = 0; it < nIter; ++it) {
    const int n = gw + it * stride;
    const bool active = (n < N);
    if (active) {
      snh[w][lane] = nh[(size_t)n * 128 + lane];
      snh[w][64 + lane] = nh[(size_t)n * 128 + 64 + lane];
    }
    __syncthreads();
    if (active) {
      float acc = sb2[lane];
      #pragma unroll 8
      for (int k = 0; k < 128; ++k) acc += snh[w][k] * sW2[k * 64 + lane];
      const float hu = h[n * DA + lane] + siluf(acc);
      out[(size_t)n * DA + lane] = hu;
      shu[w][lane] = hu;
    }
    __syncthreads();
    if (active) {
      float p = 0.f;
      if (lane < 32) {
        float acc = sbv1[lane];
        #pragma unroll 8
        for (int k = 0; k < 64; ++k) acc += shu[w][k] * sWv1[k * 32 + lane];
        p = siluf(acc) * sWv2[lane];
      }
      p += __shfl_xor(p, 16);
      p += __shfl_xor(p, 8);
      p += __shfl_xor(p, 4);
      p += __shfl_xor(p, 2);
      p += __shfl_xor(p, 1);
      const float s = __shfl(p, 0);
      const float gate = 2.0f / (1.0f + __expf(-s));
      if (lane < 3) {
        const float cnt = fmaxf(counts[n], 1.0f);
        const float dvx = dv_sum[n * 3 + lane] / cnt;
        const float vu = gate * v[n * 3 + lane] + dvx;
        out[(size_t)N * 64 + n * 3 + lane] = x[n * 3 + lane] + vu;
        out[(size_t)N * 64 + (size_t)N * 3 + n * 3 + lane] = vu;
      }
    }
    __syncthreads();
  }
}

// ---------------------------------------------------------------------------
extern "C" void kernel_launch(void* const* d_in, const int* in_sizes, int n_in,
                              void* d_out, int out_size, void* d_ws, size_t ws_size,
                              hipStream_t stream) {
  const float* h   = (const float*)d_in[0];
  const float* x   = (const float*)d_in[1];
  const float* v   = (const float*)d_in[2];
  const int* idx_i = (const int*)d_in[3];
  const int* idx_j = (const int*)d_in[4];
  const float* W_edge_in  = (const float*)d_in[5];
  const float* b_edge_in  = (const float*)d_in[6];
  const float* W_edge_h   = (const float*)d_in[7];
  const float* b_edge_h   = (const float*)d_in[8];
  const float* W_edge_out = (const float*)d_in[9];
  const float* b_edge_out = (const float*)d_in[10];
  const float* W_att      = (const float*)d_in[11];
  const float* b_att      = (const float*)d_in[12];
  const float* W_x_mix    = (const float*)d_in[13];
  const float* W_node1    = (const float*)d_in[14];
  const float* b_node1    = (const float*)d_in[15];
  const float* W_node2    = (const float*)d_in[16];
  const float* b_node2    = (const float*)d_in[17];
  const float* W_post1    = (const float*)d_in[18];
  const float* b_post1    = (const float*)d_in[19];
  const float* W_post2    = (const float*)d_in[20];
  const float* b_post2    = (const float*)d_in[21];
  const float* W_vel1     = (const float*)d_in[22];
  const float* b_vel1     = (const float*)d_in[23];
  const float* W_vel2     = (const float*)d_in[24];
  const float* w_v_mix    = (const float*)d_in[25];

  const int E = in_sizes[3];
  const int N = in_sizes[0] / DA;

  // Workspace (floats). Total ~22.6M floats = ~90 MB. All segment sizes
  // are multiples of 4 floats (16B alignment preserved).
  float* ws = (float*)d_ws;
  size_t off = 0;
  float* denom    = ws + off; off += (size_t)N * 4;     // zeroed
  int*   deg      = (int*)(ws + off); off += (size_t)N; // zeroed
  const size_t zeroBytes = off * sizeof(float);
  float* counts   = ws + off; off += (size_t)N;
  int*   rowstart = (int*)(ws + off); off += (size_t)N + 4;
  int*   cursor   = (int*)(ws + off); off += (size_t)N;
  int*   perm     = (int*)(ws + off); off += (size_t)E;
  float* pE       = ws + off; off += (size_t)E;
  float* expl     = ws + off; off += (size_t)E * 4;
  float* dirb     = ws + off; off += (size_t)E * 3;
  float* h_i_sem  = ws + off; off += (size_t)N * 128;
  float* comb_sum = ws + off; off += (size_t)N * 96;
  float* dv_sum   = ws + off; off += (size_t)N * 4;
  float* hbfR     = ws + off; off += (size_t)N * 32;    // h_bf bf16 [N,64]
  float* fltR     = ws + off; off += (size_t)E * 16;    // Filt / mixE / nh
  float* hebR     = ws + off; off += (size_t)E * 16;    // heb bf16 [E,32]

  ushort_t* h_bf = (ushort_t*)hbfR;
  ushort_t* Filt = (ushort_t*)fltR;
  ushort_t* heb  = (ushort_t*)hebR;
  ushort_t* mixE = (ushort_t*)fltR;  // aliases Filt (dead after edge_f2)
  float* nh = fltR;                  // aliases mixE (dead after node_reduce)

  hipMemsetAsync(d_ws, 0, zeroBytes, stream);

  {
    const int n4 = (N * 64) / 4;
    cast_h<<<(n4 + 255) / 256, 256, 0, stream>>>(h, h_bf, n4);
  }
  edge_f1<<<1024, 256, 0, stream>>>(h_bf, x, idx_i, idx_j, W_edge_in,
                                    b_edge_in, Filt, dirb, deg, E);
  scan_csr<<<1, 256, 0, stream>>>(deg, rowstart, cursor, counts, N);
  bucket_edges<<<512, 256, 0, stream>>>(idx_i, cursor, perm, E);
  edge_f2<<<1024, 256, 0, stream>>>(h_bf, idx_i, idx_j, Filt, W_edge_h,
                                    b_edge_h, W_edge_out, b_edge_out, heb, E);
  att_kernel<<<1024, 256, 0, stream>>>(heb, idx_i, W_att, b_att, expl, denom, E);
  mix_kernel<<<1024, 256, 0, stream>>>(heb, idx_i, expl, denom, W_x_mix,
                                       w_v_mix, mixE, pE, E);
  node_reduce<<<2048, 256, 0, stream>>>(rowstart, perm, heb, mixE, expl, denom,
                                        dirb, pE, h_i_sem, comb_sum, dv_sum, N);
  {
    const int grid = 512;
    const int nIter = (N + grid * 4 - 1) / (grid * 4);
    node_pass_c1<<<grid, 256, 0, stream>>>(
        h, h_i_sem, comb_sum, counts, W_post1, b_post1, W_post2, b_post2,
        W_node1, b_node1, nh, N, nIter);
  }
  {
    const int grid = 1024;
    const int nIter = (N + grid * 4 - 1) / (grid * 4);
    node_pass_c2<<<grid, 256, 0, stream>>>(
        h, x, v, nh, dv_sum, counts, W_node2, b_node2, W_vel1, b_vel1, W_vel2,
        (float*)d_out, N, nIter);
  }
}

// Round 5
// 783.905 us; speedup vs baseline: 3.4873x; 1.3876x over previous
//
#include <hip/hip_runtime.h>
#include <math.h>

// Problem dims (fixed by reference)
#define DA 64    // A
#define NODEIN_DIM 224 // A + H*EB + S

#define EPSC 1e-8f

typedef short v8s __attribute__((ext_vector_type(8)));
typedef float v4f __attribute__((ext_vector_type(4)));
typedef unsigned short ushort_t;

__device__ __forceinline__ float siluf(float v) { return v / (1.0f + __expf(-v)); }

__device__ __forceinline__ void atomAddF(float* p, float v) {
#if defined(__HIP_DEVICE_COMPILE__)
  unsafeAtomicAdd(p, v);
#else
  atomicAdd(p, v);
#endif
}

__device__ __forceinline__ unsigned short f2bfu(float f) {
  union { float f; unsigned u; } v; v.f = f;
  unsigned r = v.u + 0x7fffu + ((v.u >> 16) & 1u);
  return (unsigned short)(r >> 16);
}
__device__ __forceinline__ short f2bfs(float f) { return (short)f2bfu(f); }
__device__ __forceinline__ float bf2f(ushort_t s) {
  union { unsigned u; float f; } v; v.u = ((unsigned)s) << 16; return v.f;
}
__device__ __forceinline__ float bflo(unsigned u) {
  union { unsigned u; float f; } v; v.u = u << 16; return v.f;
}
__device__ __forceinline__ float bfhi(unsigned u) {
  union { unsigned u; float f; } v; v.u = u & 0xffff0000u; return v.f;
}

#define MU0 0.60653065971263342f
#define DMU ((1.0f - 0.60653065971263342f) / 19.0f)
#define BETA ((float)(1.0 / (0.039346934028736658 * 0.039346934028736658)))

// ---------------------------------------------------------------------------
// cast_h: h fp32 -> bf16 copy
// ---------------------------------------------------------------------------
__global__ __launch_bounds__(256) void cast_h(
    const float* __restrict__ hsrc, ushort_t* __restrict__ hb, int n4)
{
  const int i = blockIdx.x * blockDim.x + threadIdx.x;
  if (i < n4) {
    const float4 fv = ((const float4*)hsrc)[i];
    ushort4 o;
    o.x = f2bfu(fv.x); o.y = f2bfu(fv.y); o.z = f2bfu(fv.z); o.w = f2bfu(fv.w);
    ((ushort4*)hb)[i] = o;
  }
}

// ---------------------------------------------------------------------------
// F1: gather + geometry + M1 ([E,128] x W_in[128,20]) + RBF epilogue.
// ---------------------------------------------------------------------------
__global__ __launch_bounds__(256) void edge_f1(
    const ushort_t* __restrict__ h_bf, const float* __restrict__ x,
    const int* __restrict__ idx_i, const int* __restrict__ idx_j,
    const float* __restrict__ W_in, const float* __restrict__ b_in,
    ushort_t* __restrict__ Filt, float* __restrict__ dirb,
    int* __restrict__ deg, int E)
{
  const int tid = blockIdx.x * blockDim.x + threadIdx.x;
  const int wid = tid >> 6;
  const int lane = threadIdx.x & 63;
  const int nw = (gridDim.x * blockDim.x) >> 6;
  const int l15 = lane & 15;
  const int q = lane >> 4;

  v8s bfr[4][2];
  #pragma unroll
  for (int kc = 0; kc < 4; ++kc)
    #pragma unroll
    for (int nt = 0; nt < 2; ++nt)
      #pragma unroll
      for (int j = 0; j < 8; ++j) {
        const int k = kc * 32 + q * 8 + j;
        const int col = nt * 16 + l15;
        bfr[kc][nt][j] = (col < 20) ? f2bfs(W_in[k * 20 + col]) : (short)0;
      }
  float bin[2], mu[2];
  #pragma unroll
  for (int nt = 0; nt < 2; ++nt) {
    const int col = nt * 16 + l15;
    bin[nt] = (col < 20) ? b_in[col] : 0.0f;
    mu[nt] = MU0 + (float)col * DMU;
  }

  const int ntiles = (E + 15) >> 4;
  for (int t = wid; t < ntiles; t += nw) {
    const int row = t * 16 + l15;
    const int rowL = (row < E) ? row : (E - 1);
    const int ii = idx_i[rowL];
    const int jj = idx_j[rowL];

    v8s afr[4];
    afr[0] = *(const v8s*)(h_bf + (size_t)ii * 64 + q * 8);
    afr[1] = *(const v8s*)(h_bf + (size_t)ii * 64 + 32 + q * 8);
    afr[2] = *(const v8s*)(h_bf + (size_t)jj * 64 + q * 8);
    afr[3] = *(const v8s*)(h_bf + (size_t)jj * 64 + 32 + q * 8);

    float dval = 0.0f;
    if (lane < 16 && row < E) {
      const float rx = x[jj * 3 + 0] - x[ii * 3 + 0];
      const float ry = x[jj * 3 + 1] - x[ii * 3 + 1];
      const float rz = x[jj * 3 + 2] - x[ii * 3 + 2];
      const float d = sqrtf(rx * rx + ry * ry + rz * rz + EPSC);
      dval = d;
      const float inv = 1.0f / (d + EPSC);
      dirb[row * 3 + 0] = rx * inv;
      dirb[row * 3 + 1] = ry * inv;
      dirb[row * 3 + 2] = rz * inv;
      atomicAdd(&deg[ii], 1);
    }

    v4f acc[2];
    #pragma unroll
    for (int nt = 0; nt < 2; ++nt) {
      v4f a = {0.f, 0.f, 0.f, 0.f};
      #pragma unroll
      for (int kc = 0; kc < 4; ++kc)
        a = __builtin_amdgcn_mfma_f32_16x16x32_bf16(afr[kc], bfr[kc][nt], a, 0, 0, 0);
      acc[nt] = a;
    }

    const int rowb = t * 16 + q * 4;
    float dr[4], edr[4];
    #pragma unroll
    for (int r = 0; r < 4; ++r) {
      dr[r] = __shfl(dval, q * 4 + r);
      edr[r] = __expf(-dr[r]);
    }
    #pragma unroll
    for (int nt = 0; nt < 2; ++nt) {
      const int col = nt * 16 + l15;
      #pragma unroll
      for (int r = 0; r < 4; ++r) {
        ushort_t ov;
        if (col < 20) {
          const float tt = edr[r] - mu[nt];
          ov = f2bfu((acc[nt][r] + bin[nt]) * __expf(-BETA * tt * tt));
        } else if (col == 20) {
          ov = f2bfu(dr[r]);
        } else {
          ov = 0;
        }
        if (rowb + r < E) Filt[(size_t)(rowb + r) * 32 + col] = ov;
      }
    }
  }
}

// ---------------------------------------------------------------------------
// F2: M2 ([E,160] x W_h, silu) + LDS transpose + M3 -> heb[E,32] bf16
// ---------------------------------------------------------------------------
#define THS 72
__global__ __launch_bounds__(256) void edge_f2(
    const ushort_t* __restrict__ h_bf,
    const int* __restrict__ idx_i, const int* __restrict__ idx_j,
    const ushort_t* __restrict__ Filt,
    const float* __restrict__ W_h, const float* __restrict__ b_h,
    const float* __restrict__ W_out, const float* __restrict__ b_out,
    ushort_t* __restrict__ heb, int E)
{
  __shared__ ushort_t tH[4][16 * THS];

  const int tid = blockIdx.x * blockDim.x + threadIdx.x;
  const int wid = tid >> 6;
  const int lane = threadIdx.x & 63;
  const int w = threadIdx.x >> 6;
  const int nw = (gridDim.x * blockDim.x) >> 6;
  const int l15 = lane & 15;
  const int q = lane >> 4;

  v8s bfr2[5][4];
  #pragma unroll
  for (int kc = 0; kc < 5; ++kc)
    #pragma unroll
    for (int nt = 0; nt < 4; ++nt)
      #pragma unroll
      for (int j = 0; j < 8; ++j) {
        const int k = kc * 32 + q * 8 + j;
        const int col = nt * 16 + l15;
        bfr2[kc][nt][j] = (k < 149) ? f2bfs(W_h[k * 64 + col]) : (short)0;
      }
  v8s bfr3[2][2];
  #pragma unroll
  for (int kc = 0; kc < 2; ++kc)
    #pragma unroll
    for (int nt = 0; nt < 2; ++nt)
      #pragma unroll
      for (int j = 0; j < 8; ++j) {
        const int k = kc * 32 + q * 8 + j;
        const int col = nt * 16 + l15;
        bfr3[kc][nt][j] = f2bfs(W_out[k * 32 + col]);
      }
  float bias2[4];
  #pragma unroll
  for (int nt = 0; nt < 4; ++nt) bias2[nt] = b_h[nt * 16 + l15];
  float bias3[2];
  #pragma unroll
  for (int nt = 0; nt < 2; ++nt) bias3[nt] = b_out[nt * 16 + l15];

  const int ntiles = (E + 15) >> 4;
  for (int t = wid; t < ntiles; t += nw) {
    const int row = t * 16 + l15;
    const int rowL = (row < E) ? row : (E - 1);
    const int ii = idx_i[rowL];
    const int jj = idx_j[rowL];

    v8s afr[5];
    afr[0] = *(const v8s*)(h_bf + (size_t)ii * 64 + q * 8);
    afr[1] = *(const v8s*)(h_bf + (size_t)ii * 64 + 32 + q * 8);
    afr[2] = *(const v8s*)(h_bf + (size_t)jj * 64 + q * 8);
    afr[3] = *(const v8s*)(h_bf + (size_t)jj * 64 + 32 + q * 8);
    afr[4] = *(const v8s*)(Filt + (size_t)rowL * 32 + q * 8);

    v4f acc2[4];
    #pragma unroll
    for (int nt = 0; nt < 4; ++nt) {
      v4f a = {0.f, 0.f, 0.f, 0.f};
      #pragma unroll
      for (int kc = 0; kc < 5; ++kc)
        a = __builtin_amdgcn_mfma_f32_16x16x32_bf16(afr[kc], bfr2[kc][nt], a, 0, 0, 0);
      acc2[nt] = a;
    }

    #pragma unroll
    for (int nt = 0; nt < 4; ++nt) {
      #pragma unroll
      for (int r = 0; r < 4; ++r)
        tH[w][(q * 4 + r) * THS + nt * 16 + l15] =
            f2bfu(siluf(acc2[nt][r] + bias2[nt]));
    }
    __builtin_amdgcn_wave_barrier();

    v8s af3[2];
    af3[0] = *(const v8s*)&tH[w][l15 * THS + q * 8];
    af3[1] = *(const v8s*)&tH[w][l15 * THS + 32 + q * 8];

    v4f acc3[2];
    #pragma unroll
    for (int nt = 0; nt < 2; ++nt) {
      v4f a = {0.f, 0.f, 0.f, 0.f};
      #pragma unroll
      for (int kc = 0; kc < 2; ++kc)
        a = __builtin_amdgcn_mfma_f32_16x16x32_bf16(af3[kc], bfr3[kc][nt], a, 0, 0, 0);
      acc3[nt] = a;
    }

    const int rowb = t * 16 + q * 4;
    #pragma unroll
    for (int nt = 0; nt < 2; ++nt) {
      const int col = nt * 16 + l15;
      #pragma unroll
      for (int r = 0; r < 4; ++r)
        if (rowb + r < E)
          heb[(size_t)(rowb + r) * 32 + col] = f2bfu(acc3[nt][r] + bias3[nt]);
    }
  }
}

// ---------------------------------------------------------------------------
// Att: per-edge celu logits -> exp, denom atomics
// ---------------------------------------------------------------------------
__global__ __launch_bounds__(256) void att_kernel(
    const ushort_t* __restrict__ heb, const int* __restrict__ idx_i,
    const float* __restrict__ W_att, const float* __restrict__ b_att,
    float* __restrict__ expl, float* __restrict__ denom, int E)
{
  __shared__ float sWa[128];
  __shared__ float sba[4];
  if (threadIdx.x < 128) sWa[threadIdx.x] = W_att[threadIdx.x];
  if (threadIdx.x < 4) sba[threadIdx.x] = b_att[threadIdx.x];
  __syncthreads();
  const int stride = gridDim.x * blockDim.x;
  for (int e = blockIdx.x * blockDim.x + threadIdx.x; e < E; e += stride) {
    float acc[4] = {sba[0], sba[1], sba[2], sba[3]};
    const int4* hv = (const int4*)(heb + (size_t)e * 32);
    #pragma unroll
    for (int blk = 0; blk < 4; ++blk) {
      const int4 pk = hv[blk];
      const unsigned uu[4] = {(unsigned)pk.x, (unsigned)pk.y,
                              (unsigned)pk.z, (unsigned)pk.w};
      #pragma unroll
      for (int u = 0; u < 4; ++u) {
        const int c = blk * 8 + u * 2;
        const float c0 = bflo(uu[u]);
        const float c1 = bfhi(uu[u]);
        #pragma unroll
        for (int tt = 0; tt < 4; ++tt)
          acc[tt] += c0 * sWa[c * 4 + tt] + c1 * sWa[(c + 1) * 4 + tt];
      }
    }
    const int ii = idx_i[e];
    float ev[4];
    #pragma unroll
    for (int tt = 0; tt < 4; ++tt) {
      const float l = (acc[tt] > 0.f) ? acc[tt]
                                      : 2.0f * (__expf(0.5f * acc[tt]) - 1.0f);
      ev[tt] = __expf(l);
    }
    float4 evv = {ev[0], ev[1], ev[2], ev[3]};
    *(float4*)(expl + (size_t)e * 4) = evv;
    #pragma unroll
    for (int tt = 0; tt < 4; ++tt) atomAddF(&denom[ii * 4 + tt], ev[tt]);
  }
}

// ---------------------------------------------------------------------------
// scan_csr: exclusive prefix-sum of deg -> rowstart, cursor, counts (float)
// ---------------------------------------------------------------------------
__global__ __launch_bounds__(256) void scan_csr(
    const int* __restrict__ deg, int* __restrict__ rowstart,
    int* __restrict__ cursor, float* __restrict__ counts, int N)
{
  __shared__ int partial[256];
  __shared__ int base[256];
  const int t = threadIdx.x;
  const int chunk = (N + 255) / 256;
  const int lo = t * chunk;
  const int hi = (lo + chunk < N) ? (lo + chunk) : N;
  int s = 0;
  for (int i = lo; i < hi; ++i) s += deg[i];
  partial[t] = s;
  __syncthreads();
  if (t == 0) {
    int acc = 0;
    for (int i = 0; i < 256; ++i) { base[i] = acc; acc += partial[i]; }
  }
  __syncthreads();
  int acc = base[t];
  for (int i = lo; i < hi; ++i) {
    rowstart[i] = acc;
    cursor[i] = acc;
    counts[i] = (float)deg[i];
    acc += deg[i];
  }
  if (t == 255) rowstart[N] = acc;
}

// ---------------------------------------------------------------------------
// bucket_edges: perm[pos] = e, pos from cursor atomics
// ---------------------------------------------------------------------------
__global__ __launch_bounds__(256) void bucket_edges(
    const int* __restrict__ idx_i, int* __restrict__ cursor,
    int* __restrict__ perm, int E)
{
  const int stride = gridDim.x * blockDim.x;
  for (int e = blockIdx.x * blockDim.x + threadIdx.x; e < E; e += stride) {
    const int pos = atomicAdd(&cursor[idx_i[e]], 1);
    perm[pos] = e;
  }
}

// ---------------------------------------------------------------------------
// mix_kernel: per-edge A = att (x) he  ->  MFMA [E,128] x W_x_mix[128,32]
// ---------------------------------------------------------------------------
__global__ __launch_bounds__(256) void mix_kernel(
    const ushort_t* __restrict__ heb, const int* __restrict__ idx_i,
    const float* __restrict__ expl, const float* __restrict__ denom,
    const float* __restrict__ W_xmix, const float* __restrict__ w_vmix,
    ushort_t* __restrict__ mixE, float* __restrict__ pE, int E)
{
  const int tid = blockIdx.x * blockDim.x + threadIdx.x;
  const int wid = tid >> 6;
  const int lane = threadIdx.x & 63;
  const int nw = (gridDim.x * blockDim.x) >> 6;
  const int l15 = lane & 15;
  const int q = lane >> 4;

  v8s bfr[4][2];
  #pragma unroll
  for (int kc = 0; kc < 4; ++kc)
    #pragma unroll
    for (int nt = 0; nt < 2; ++nt)
      #pragma unroll
      for (int j = 0; j < 8; ++j) {
        const int k = kc * 32 + q * 8 + j;
        const int col = nt * 16 + l15;
        bfr[kc][nt][j] = f2bfs(W_xmix[k * 32 + col]);
      }
  float wv[2];
  wv[0] = w_vmix[l15];
  wv[1] = w_vmix[16 + l15];

  const int ntiles = (E + 15) >> 4;
  for (int t = wid; t < ntiles; t += nw) {
    const int row = t * 16 + l15;
    const int rowL = (row < E) ? row : (E - 1);
    const int ii = idx_i[rowL];
    float att[4];
    #pragma unroll
    for (int hh = 0; hh < 4; ++hh)
      att[hh] = expl[(size_t)rowL * 4 + hh] / (denom[ii * 4 + hh] + EPSC);

    const v8s hech = *(const v8s*)(heb + (size_t)rowL * 32 + q * 8);
    float hef[8];
    #pragma unroll
    for (int j = 0; j < 8; ++j) hef[j] = bf2f((ushort_t)hech[j]);

    v8s afr[4];
    #pragma unroll
    for (int kc = 0; kc < 4; ++kc)
      #pragma unroll
      for (int j = 0; j < 8; ++j)
        afr[kc][j] = f2bfs(att[kc] * hef[j]);

    v4f acc[2];
    #pragma unroll
    for (int nt = 0; nt < 2; ++nt) {
      v4f a = {0.f, 0.f, 0.f, 0.f};
      #pragma unroll
      for (int kc = 0; kc < 4; ++kc)
        a = __builtin_amdgcn_mfma_f32_16x16x32_bf16(afr[kc], bfr[kc][nt], a, 0, 0, 0);
      acc[nt] = a;
    }

    const int rowb = t * 16 + q * 4;
    float pr[4];
    #pragma unroll
    for (int r = 0; r < 4; ++r) {
      const float m0 = tanhf(acc[0][r]);
      const float m1 = tanhf(acc[1][r]);
      if (rowb + r < E) {
        mixE[(size_t)(rowb + r) * 32 + l15] = f2bfu(m0);
        mixE[(size_t)(rowb + r) * 32 + 16 + l15] = f2bfu(m1);
      }
      pr[r] = m0 * wv[0] + m1 * wv[1];
    }
    #pragma unroll
    for (int r = 0; r < 4; ++r) {
      pr[r] += __shfl_xor(pr[r], 1);
      pr[r] += __shfl_xor(pr[r], 2);
      pr[r] += __shfl_xor(pr[r], 4);
      pr[r] += __shfl_xor(pr[r], 8);
      if (l15 == 0 && rowb + r < E) pE[rowb + r] = pr[r];
    }
  }
}

// ---------------------------------------------------------------------------
// node_reduce: wave per node, CSR gather-reduce.  h_i_sem now bf16.
// ---------------------------------------------------------------------------
__global__ __launch_bounds__(256) void node_reduce(
    const int* __restrict__ rowstart, const int* __restrict__ perm,
    const ushort_t* __restrict__ heb, const ushort_t* __restrict__ mixE,
    const float* __restrict__ expl, const float* __restrict__ denom,
    const float* __restrict__ dirb, const float* __restrict__ pE,
    ushort_t* __restrict__ hsem, float* __restrict__ comb_sum,
    float* __restrict__ dv_sum, int N)
{
  const int tid = blockIdx.x * blockDim.x + threadIdx.x;
  const int wid = tid >> 6;
  const int lane = threadIdx.x & 63;
  const int nw = (gridDim.x * blockDim.x) >> 6;
  const int hh = lane >> 5;
  const int eb = lane & 31;

  for (int n = wid; n < N; n += nw) {
    const int s = rowstart[n];
    const int epd = rowstart[n + 1];
    float semA = 0.f, semB = 0.f;
    float cx = 0.f, cy = 0.f, cz = 0.f;
    float dvx = 0.f, dvy = 0.f, dvz = 0.f;
    for (int k = s; k < epd; ++k) {
      const int e = perm[k];
      const float he = bf2f(heb[(size_t)e * 32 + eb]);
      const float ea = expl[(size_t)e * 4 + hh];
      const float ec = expl[(size_t)e * 4 + 2 + hh];
      semA += ea * he;
      semB += ec * he;
      const float dx = dirb[e * 3 + 0];
      const float dy = dirb[e * 3 + 1];
      const float dz = dirb[e * 3 + 2];
      if (lane < 32) {
        const float m = bf2f(mixE[(size_t)e * 32 + lane]);
        cx += dx * m; cy += dy * m; cz += dz * m;
      }
      if (lane == 0) {
        const float pe = pE[e];
        dvx += dx * pe; dvy += dy * pe; dvz += dz * pe;
      }
    }
    const float dA = denom[n * 4 + hh] + EPSC;
    const float dB = denom[n * 4 + 2 + hh] + EPSC;
    hsem[(size_t)n * 128 + lane] = f2bfu(semA / dA);
    hsem[(size_t)n * 128 + 64 + lane] = f2bfu(semB / dB);
    if (lane < 32) {
      comb_sum[(size_t)n * 96 + lane * 3 + 0] = cx;
      comb_sum[(size_t)n * 96 + lane * 3 + 1] = cy;
      comb_sum[(size_t)n * 96 + lane * 3 + 2] = cz;
    }
    if (lane == 0) {
      dv_sum[n * 3 + 0] = dvx;
      dv_sum[n * 3 + 1] = dvy;
      dv_sum[n * 3 + 2] = dvz;
    }
  }
}

// ---------------------------------------------------------------------------
// C1 (MFMA): spatial MLP (post1/post2) + node1, wave per 16-node tile.
// W_node1 staged bf16 col-major in LDS (ds_read_b128 B-frags).
// ---------------------------------------------------------------------------
#define W1S 232  // col stride in ushorts (464 B, 16B-aligned)
__global__ __launch_bounds__(256) void node_c1_mfma(
    const ushort_t* __restrict__ h_bf, const ushort_t* __restrict__ hsem,
    const float* __restrict__ comb_sum, const float* __restrict__ counts,
    const float* __restrict__ W_post1, const float* __restrict__ b_post1,
    const float* __restrict__ W_post2, const float* __restrict__ b_post2,
    const float* __restrict__ W_node1, const float* __restrict__ b_node1,
    float* __restrict__ nh_out, int N)
{
  __shared__ ushort_t sW1t[128 * W1S];   // 58 KB: col-major bf16 W_node1
  __shared__ ushort_t tp[4][16 * THS];   // 9 KB: per-wave transpose tile

  const int tid = threadIdx.x;
  for (int idx = tid; idx < 224 * 128; idx += 256) {
    const int k = idx >> 7;
    const int c = idx & 127;
    sW1t[c * W1S + k] = f2bfu(W_node1[idx]);
  }
  __syncthreads();

  const int lane = tid & 63;
  const int w = tid >> 6;
  const int l15 = lane & 15;
  const int q = lane >> 4;

  // small-B fragments in registers
  v8s bp1[4];
  #pragma unroll
  for (int nt = 0; nt < 4; ++nt)
    #pragma unroll
    for (int j = 0; j < 8; ++j)
      bp1[nt][j] = f2bfs(W_post1[(q * 8 + j) * 64 + nt * 16 + l15]);
  v8s bp2[2][2];
  #pragma unroll
  for (int kc = 0; kc < 2; ++kc)
    #pragma unroll
    for (int nt = 0; nt < 2; ++nt)
      #pragma unroll
      for (int j = 0; j < 8; ++j)
        bp2[kc][nt][j] = f2bfs(W_post2[(kc * 32 + q * 8 + j) * 32 + nt * 16 + l15]);
  float bb1[4];
  #pragma unroll
  for (int nt = 0; nt < 4; ++nt) bb1[nt] = b_post1[nt * 16 + l15];
  float bb2[2];
  #pragma unroll
  for (int nt = 0; nt < 2; ++nt) bb2[nt] = b_post2[nt * 16 + l15];
  float b1[8];
  #pragma unroll
  for (int nt = 0; nt < 8; ++nt) b1[nt] = b_node1[nt * 16 + l15];

  const int gw = blockIdx.x * 4 + w;
  const int nwv = gridDim.x * 4;
  const int ntiles = (N + 15) >> 4;

  for (int t = gw; t < ntiles; t += nwv) {
    const int row = t * 16 + l15;
    const int rowL = (row < N) ? row : (N - 1);

    // norm2 A-fragment: k = q*8+j spatial channel
    const float inv = 1.0f / fmaxf(counts[rowL], 1.0f);
    const float4* cs = (const float4*)(comb_sum + (size_t)rowL * 96 + q * 24);
    float cf[24];
    #pragma unroll
    for (int b = 0; b < 6; ++b) {
      const float4 cv = cs[b];
      cf[b * 4 + 0] = cv.x; cf[b * 4 + 1] = cv.y;
      cf[b * 4 + 2] = cv.z; cf[b * 4 + 3] = cv.w;
    }
    v8s a1;
    #pragma unroll
    for (int j = 0; j < 8; ++j) {
      const float vx = cf[j * 3 + 0] * inv;
      const float vy = cf[j * 3 + 1] * inv;
      const float vz = cf[j * 3 + 2] * inv;
      a1[j] = f2bfs(vx * vx + vy * vy + vz * vz);
    }

    // post1: [16,32] x [32,64]
    v4f p1[4];
    #pragma unroll
    for (int nt = 0; nt < 4; ++nt) {
      v4f a = {0.f, 0.f, 0.f, 0.f};
      p1[nt] = __builtin_amdgcn_mfma_f32_16x16x32_bf16(a1, bp1[nt], a, 0, 0, 0);
    }
    #pragma unroll
    for (int nt = 0; nt < 4; ++nt)
      #pragma unroll
      for (int r = 0; r < 4; ++r)
        tp[w][(q * 4 + r) * THS + nt * 16 + l15] =
            f2bfu(siluf(p1[nt][r] + bb1[nt]));
    __builtin_amdgcn_wave_barrier();

    v8s a2[2];
    a2[0] = *(const v8s*)&tp[w][l15 * THS + q * 8];
    a2[1] = *(const v8s*)&tp[w][l15 * THS + 32 + q * 8];

    // post2: [16,64] x [64,32]
    v4f p2[2];
    #pragma unroll
    for (int nt = 0; nt < 2; ++nt) {
      v4f a = {0.f, 0.f, 0.f, 0.f};
      #pragma unroll
      for (int kc = 0; kc < 2; ++kc)
        a = __builtin_amdgcn_mfma_f32_16x16x32_bf16(a2[kc], bp2[kc][nt], a, 0, 0, 0);
      p2[nt] = a;
    }
    __builtin_amdgcn_wave_barrier();
    #pragma unroll
    for (int nt = 0; nt < 2; ++nt)
      #pragma unroll
      for (int r = 0; r < 4; ++r)
        tp[w][(q * 4 + r) * THS + nt * 16 + l15] =
            f2bfu(siluf(p2[nt][r] + bb2[nt]));
    __builtin_amdgcn_wave_barrier();

    // node1 A-fragments
    v8s af[7];
    af[0] = *(const v8s*)(h_bf + (size_t)rowL * 64 + q * 8);
    af[1] = *(const v8s*)(h_bf + (size_t)rowL * 64 + 32 + q * 8);
    #pragma unroll
    for (int kc = 0; kc < 4; ++kc)
      af[2 + kc] = *(const v8s*)(hsem + (size_t)rowL * 128 + kc * 32 + q * 8);
    af[6] = *(const v8s*)&tp[w][l15 * THS + q * 8];

    v4f acc[8];
    #pragma unroll
    for (int nt = 0; nt < 8; ++nt) acc[nt] = (v4f){0.f, 0.f, 0.f, 0.f};
    #pragma unroll
    for (int kc = 0; kc < 7; ++kc) {
      #pragma unroll
      for (int nt = 0; nt < 8; ++nt) {
        const v8s bfrag =
            *(const v8s*)&sW1t[(nt * 16 + l15) * W1S + kc * 32 + q * 8];
        acc[nt] = __builtin_amdgcn_mfma_f32_16x16x32_bf16(af[kc], bfrag, acc[nt], 0, 0, 0);
      }
    }

    const int rowb = t * 16 + q * 4;
    #pragma unroll
    for (int nt = 0; nt < 8; ++nt) {
      #pragma unroll
      for (int r = 0; r < 4; ++r)
        if (rowb + r < N)
          nh_out[(size_t)(rowb + r) * 128 + nt * 16 + l15] =
              siluf(acc[nt][r] + b1[nt]);
    }
  }
}

// ---------------------------------------------------------------------------
// Pass C2: h_upd, gate, v_upd, x_upd -> d_out
// ---------------------------------------------------------------------------
__global__ __launch_bounds__(256) void node_pass_c2(
    const float* __restrict__ h, const float* __restrict__ x,
    const float* __restrict__ v, const float* __restrict__ nh,
    const float* __restrict__ dv_sum, const float* __restrict__ counts,
    const float* __restrict__ W_node2, const float* __restrict__ b_node2,
    const float* __restrict__ W_vel1, const float* __restrict__ b_vel1,
    const float* __restrict__ W_vel2,
    float* __restrict__ out, int N, int nIter)
{
  __shared__ float sW2[128 * 64];
  __shared__ float sWv1[64 * 32];
  __shared__ float sb2[64];
  __shared__ float sbv1[32];
  __shared__ float sWv2[32];
  __shared__ float snh[4][128];
  __shared__ float shu[4][64];

  const int tid = threadIdx.x;
  for (int k = tid; k < 128 * 64; k += 256) sW2[k] = W_node2[k];
  for (int k = tid; k < 64 * 32; k += 256) sWv1[k] = W_vel1[k];
  for (int k = tid; k < 64; k += 256) sb2[k] = b_node2[k];
  for (int k = tid; k < 32; k += 256) sbv1[k] = b_vel1[k];
  for (int k = tid; k < 32; k += 256) sWv2[k] = W_vel2[k];
  __syncthreads();

  const int lane = tid & 63;
  const int w = tid >> 6;
  const int gw = blockIdx.x * 4 + w;
  const int stride = gridDim.x * 4;

  for (int it = 0; it < nIter; ++it) {
    const int n = gw + it * stride;
    const bool active = (n < N);
    if (active) {
      snh[w][lane] = nh[(size_t)n * 128 + lane];
      snh[w][64 + lane] = nh[(size_t)n * 128 + 64 + lane];
    }
    __syncthreads();
    if (active) {
      float acc = sb2[lane];
      #pragma unroll 8
      for (int k = 0; k < 128; ++k) acc += snh[w][k] * sW2[k * 64 + lane];
      const float hu = h[n * DA + lane] + siluf(acc);
      out[(size_t)n * DA + lane] = hu;
      shu[w][lane] = hu;
    }
    __syncthreads();
    if (active) {
      float p = 0.f;
      if (lane < 32) {
        float acc = sbv1[lane];
        #pragma unroll 8
        for (int k = 0; k < 64; ++k) acc += shu[w][k] * sWv1[k * 32 + lane];
        p = siluf(acc) * sWv2[lane];
      }
      p += __shfl_xor(p, 16);
      p += __shfl_xor(p, 8);
      p += __shfl_xor(p, 4);
      p += __shfl_xor(p, 2);
      p += __shfl_xor(p, 1);
      const float s = __shfl(p, 0);
      const float gate = 2.0f / (1.0f + __expf(-s));
      if (lane < 3) {
        const float cnt = fmaxf(counts[n], 1.0f);
        const float dvx = dv_sum[n * 3 + lane] / cnt;
        const float vu = gate * v[n * 3 + lane] + dvx;
        out[(size_t)N * 64 + n * 3 + lane] = x[n * 3 + lane] + vu;
        out[(size_t)N * 64 + (size_t)N * 3 + n * 3 + lane] = vu;
      }
    }
    __syncthreads();
  }
}

// ---------------------------------------------------------------------------
extern "C" void kernel_launch(void* const* d_in, const int* in_sizes, int n_in,
                              void* d_out, int out_size, void* d_ws, size_t ws_size,
                              hipStream_t stream) {
  const float* h   = (const float*)d_in[0];
  const float* x   = (const float*)d_in[1];
  const float* v   = (const float*)d_in[2];
  const int* idx_i = (const int*)d_in[3];
  const int* idx_j = (const int*)d_in[4];
  const float* W_edge_in  = (const float*)d_in[5];
  const float* b_edge_in  = (const float*)d_in[6];
  const float* W_edge_h   = (const float*)d_in[7];
  const float* b_edge_h   = (const float*)d_in[8];
  const float* W_edge_out = (const float*)d_in[9];
  const float* b_edge_out = (const float*)d_in[10];
  const float* W_att      = (const float*)d_in[11];
  const float* b_att      = (const float*)d_in[12];
  const float* W_x_mix    = (const float*)d_in[13];
  const float* W_node1    = (const float*)d_in[14];
  const float* b_node1    = (const float*)d_in[15];
  const float* W_node2    = (const float*)d_in[16];
  const float* b_node2    = (const float*)d_in[17];
  const float* W_post1    = (const float*)d_in[18];
  const float* b_post1    = (const float*)d_in[19];
  const float* W_post2    = (const float*)d_in[20];
  const float* b_post2    = (const float*)d_in[21];
  const float* W_vel1     = (const float*)d_in[22];
  const float* b_vel1     = (const float*)d_in[23];
  const float* W_vel2     = (const float*)d_in[24];
  const float* w_v_mix    = (const float*)d_in[25];

  const int E = in_sizes[3];
  const int N = in_sizes[0] / DA;

  float* ws = (float*)d_ws;
  size_t off = 0;
  float* denom    = ws + off; off += (size_t)N * 4;     // zeroed
  int*   deg      = (int*)(ws + off); off += (size_t)N; // zeroed
  const size_t zeroBytes = off * sizeof(float);
  float* counts   = ws + off; off += (size_t)N;
  int*   rowstart = (int*)(ws + off); off += (size_t)N + 4;
  int*   cursor   = (int*)(ws + off); off += (size_t)N;
  int*   perm     = (int*)(ws + off); off += (size_t)E;
  float* pE       = ws + off; off += (size_t)E;
  float* expl     = ws + off; off += (size_t)E * 4;
  float* dirb     = ws + off; off += (size_t)E * 3;
  float* hsemR    = ws + off; off += (size_t)N * 64;    // hsem bf16 [N,128]
  float* comb_sum = ws + off; off += (size_t)N * 96;
  float* dv_sum   = ws + off; off += (size_t)N * 4;
  float* hbfR     = ws + off; off += (size_t)N * 32;    // h_bf bf16 [N,64]
  float* fltR     = ws + off; off += (size_t)E * 16;    // Filt / mixE / nh
  float* hebR     = ws + off; off += (size_t)E * 16;    // heb bf16 [E,32]

  ushort_t* h_bf = (ushort_t*)hbfR;
  ushort_t* hsem = (ushort_t*)hsemR;
  ushort_t* Filt = (ushort_t*)fltR;
  ushort_t* heb  = (ushort_t*)hebR;
  ushort_t* mixE = (ushort_t*)fltR;  // aliases Filt (dead after edge_f2)
  float* nh = fltR;                  // aliases mixE (dead after node_reduce)

  hipMemsetAsync(d_ws, 0, zeroBytes, stream);

  {
    const int n4 = (N * 64) / 4;
    cast_h<<<(n4 + 255) / 256, 256, 0, stream>>>(h, h_bf, n4);
  }
  edge_f1<<<1024, 256, 0, stream>>>(h_bf, x, idx_i, idx_j, W_edge_in,
                                    b_edge_in, Filt, dirb, deg, E);
  scan_csr<<<1, 256, 0, stream>>>(deg, rowstart, cursor, counts, N);
  bucket_edges<<<512, 256, 0, stream>>>(idx_i, cursor, perm, E);
  edge_f2<<<1024, 256, 0, stream>>>(h_bf, idx_i, idx_j, Filt, W_edge_h,
                                    b_edge_h, W_edge_out, b_edge_out, heb, E);
  att_kernel<<<1024, 256, 0, stream>>>(heb, idx_i, W_att, b_att, expl, denom, E);
  mix_kernel<<<1024, 256, 0, stream>>>(heb, idx_i, expl, denom, W_x_mix,
                                       w_v_mix, mixE, pE, E);
  node_reduce<<<2048, 256, 0, stream>>>(rowstart, perm, heb, mixE, expl, denom,
                                        dirb, pE, hsem, comb_sum, dv_sum, N);
  node_c1_mfma<<<512, 256, 0, stream>>>(
      h_bf, hsem, comb_sum, counts, W_post1, b_post1, W_post2, b_post2,
      W_node1, b_node1, nh, N);
  {
    const int grid = 1024;
    const int nIter = (N + grid * 4 - 1) / (grid * 4);
    node_pass_c2<<<grid, 256, 0, stream>>>(
        h, x, v, nh, dv_sum, counts, W_node2, b_node2, W_vel1, b_vel1, W_vel2,
        (float*)d_out, N, nIter);
  }
}

// Round 6
// 664.087 us; speedup vs baseline: 4.1165x; 1.1804x over previous
//
#include <hip/hip_runtime.h>
#include <math.h>

// Problem dims (fixed by reference)
#define DA 64    // A
#define NODEIN_DIM 224 // A + H*EB + S

#define EPSC 1e-8f

typedef short v8s __attribute__((ext_vector_type(8)));
typedef float v4f __attribute__((ext_vector_type(4)));
typedef unsigned short ushort_t;

__device__ __forceinline__ float siluf(float v) { return v / (1.0f + __expf(-v)); }

__device__ __forceinline__ void atomAddF(float* p, float v) {
#if defined(__HIP_DEVICE_COMPILE__)
  unsafeAtomicAdd(p, v);
#else
  atomicAdd(p, v);
#endif
}

__device__ __forceinline__ unsigned short f2bfu(float f) {
  union { float f; unsigned u; } v; v.f = f;
  unsigned r = v.u + 0x7fffu + ((v.u >> 16) & 1u);
  return (unsigned short)(r >> 16);
}
__device__ __forceinline__ short f2bfs(float f) { return (short)f2bfu(f); }
__device__ __forceinline__ float bf2f(ushort_t s) {
  union { unsigned u; float f; } v; v.u = ((unsigned)s) << 16; return v.f;
}
__device__ __forceinline__ float bflo(unsigned u) {
  union { unsigned u; float f; } v; v.u = u << 16; return v.f;
}
__device__ __forceinline__ float bfhi(unsigned u) {
  union { unsigned u; float f; } v; v.u = u & 0xffff0000u; return v.f;
}

#define MU0 0.60653065971263342f
#define DMU ((1.0f - 0.60653065971263342f) / 19.0f)
#define BETA ((float)(1.0 / (0.039346934028736658 * 0.039346934028736658)))

// ---------------------------------------------------------------------------
// cast_h: h fp32 -> bf16 copy
// ---------------------------------------------------------------------------
__global__ __launch_bounds__(256) void cast_h(
    const float* __restrict__ hsrc, ushort_t* __restrict__ hb, int n4)
{
  const int i = blockIdx.x * blockDim.x + threadIdx.x;
  if (i < n4) {
    const float4 fv = ((const float4*)hsrc)[i];
    ushort4 o;
    o.x = f2bfu(fv.x); o.y = f2bfu(fv.y); o.z = f2bfu(fv.z); o.w = f2bfu(fv.w);
    ((ushort4*)hb)[i] = o;
  }
}

// ---------------------------------------------------------------------------
// F1: gather + geometry + M1 ([E,128] x W_in[128,20]) + RBF epilogue.
// ---------------------------------------------------------------------------
__global__ __launch_bounds__(256) void edge_f1(
    const ushort_t* __restrict__ h_bf, const float* __restrict__ x,
    const int* __restrict__ idx_i, const int* __restrict__ idx_j,
    const float* __restrict__ W_in, const float* __restrict__ b_in,
    ushort_t* __restrict__ Filt, float* __restrict__ dirb,
    int* __restrict__ deg, int E)
{
  const int tid = blockIdx.x * blockDim.x + threadIdx.x;
  const int wid = tid >> 6;
  const int lane = threadIdx.x & 63;
  const int nw = (gridDim.x * blockDim.x) >> 6;
  const int l15 = lane & 15;
  const int q = lane >> 4;

  v8s bfr[4][2];
  #pragma unroll
  for (int kc = 0; kc < 4; ++kc)
    #pragma unroll
    for (int nt = 0; nt < 2; ++nt)
      #pragma unroll
      for (int j = 0; j < 8; ++j) {
        const int k = kc * 32 + q * 8 + j;
        const int col = nt * 16 + l15;
        bfr[kc][nt][j] = (col < 20) ? f2bfs(W_in[k * 20 + col]) : (short)0;
      }
  float bin[2], mu[2];
  #pragma unroll
  for (int nt = 0; nt < 2; ++nt) {
    const int col = nt * 16 + l15;
    bin[nt] = (col < 20) ? b_in[col] : 0.0f;
    mu[nt] = MU0 + (float)col * DMU;
  }

  const int ntiles = (E + 15) >> 4;
  for (int t = wid; t < ntiles; t += nw) {
    const int row = t * 16 + l15;
    const int rowL = (row < E) ? row : (E - 1);
    const int ii = idx_i[rowL];
    const int jj = idx_j[rowL];

    v8s afr[4];
    afr[0] = *(const v8s*)(h_bf + (size_t)ii * 64 + q * 8);
    afr[1] = *(const v8s*)(h_bf + (size_t)ii * 64 + 32 + q * 8);
    afr[2] = *(const v8s*)(h_bf + (size_t)jj * 64 + q * 8);
    afr[3] = *(const v8s*)(h_bf + (size_t)jj * 64 + 32 + q * 8);

    float dval = 0.0f;
    if (lane < 16 && row < E) {
      const float rx = x[jj * 3 + 0] - x[ii * 3 + 0];
      const float ry = x[jj * 3 + 1] - x[ii * 3 + 1];
      const float rz = x[jj * 3 + 2] - x[ii * 3 + 2];
      const float d = sqrtf(rx * rx + ry * ry + rz * rz + EPSC);
      dval = d;
      const float inv = 1.0f / (d + EPSC);
      dirb[row * 3 + 0] = rx * inv;
      dirb[row * 3 + 1] = ry * inv;
      dirb[row * 3 + 2] = rz * inv;
      atomicAdd(&deg[ii], 1);
    }

    v4f acc[2];
    #pragma unroll
    for (int nt = 0; nt < 2; ++nt) {
      v4f a = {0.f, 0.f, 0.f, 0.f};
      #pragma unroll
      for (int kc = 0; kc < 4; ++kc)
        a = __builtin_amdgcn_mfma_f32_16x16x32_bf16(afr[kc], bfr[kc][nt], a, 0, 0, 0);
      acc[nt] = a;
    }

    const int rowb = t * 16 + q * 4;
    float dr[4], edr[4];
    #pragma unroll
    for (int r = 0; r < 4; ++r) {
      dr[r] = __shfl(dval, q * 4 + r);
      edr[r] = __expf(-dr[r]);
    }
    #pragma unroll
    for (int nt = 0; nt < 2; ++nt) {
      const int col = nt * 16 + l15;
      #pragma unroll
      for (int r = 0; r < 4; ++r) {
        ushort_t ov;
        if (col < 20) {
          const float tt = edr[r] - mu[nt];
          ov = f2bfu((acc[nt][r] + bin[nt]) * __expf(-BETA * tt * tt));
        } else if (col == 20) {
          ov = f2bfu(dr[r]);
        } else {
          ov = 0;
        }
        if (rowb + r < E) Filt[(size_t)(rowb + r) * 32 + col] = ov;
      }
    }
  }
}

// ---------------------------------------------------------------------------
// F2: M2 ([E,160] x W_h, silu) + LDS transpose + M3 -> heb[E,32] bf16
// ---------------------------------------------------------------------------
#define THS 72
__global__ __launch_bounds__(256) void edge_f2(
    const ushort_t* __restrict__ h_bf,
    const int* __restrict__ idx_i, const int* __restrict__ idx_j,
    const ushort_t* __restrict__ Filt,
    const float* __restrict__ W_h, const float* __restrict__ b_h,
    const float* __restrict__ W_out, const float* __restrict__ b_out,
    ushort_t* __restrict__ heb, int E)
{
  __shared__ ushort_t tH[4][16 * THS];

  const int tid = blockIdx.x * blockDim.x + threadIdx.x;
  const int wid = tid >> 6;
  const int lane = threadIdx.x & 63;
  const int w = threadIdx.x >> 6;
  const int nw = (gridDim.x * blockDim.x) >> 6;
  const int l15 = lane & 15;
  const int q = lane >> 4;

  v8s bfr2[5][4];
  #pragma unroll
  for (int kc = 0; kc < 5; ++kc)
    #pragma unroll
    for (int nt = 0; nt < 4; ++nt)
      #pragma unroll
      for (int j = 0; j < 8; ++j) {
        const int k = kc * 32 + q * 8 + j;
        const int col = nt * 16 + l15;
        bfr2[kc][nt][j] = (k < 149) ? f2bfs(W_h[k * 64 + col]) : (short)0;
      }
  v8s bfr3[2][2];
  #pragma unroll
  for (int kc = 0; kc < 2; ++kc)
    #pragma unroll
    for (int nt = 0; nt < 2; ++nt)
      #pragma unroll
      for (int j = 0; j < 8; ++j) {
        const int k = kc * 32 + q * 8 + j;
        const int col = nt * 16 + l15;
        bfr3[kc][nt][j] = f2bfs(W_out[k * 32 + col]);
      }
  float bias2[4];
  #pragma unroll
  for (int nt = 0; nt < 4; ++nt) bias2[nt] = b_h[nt * 16 + l15];
  float bias3[2];
  #pragma unroll
  for (int nt = 0; nt < 2; ++nt) bias3[nt] = b_out[nt * 16 + l15];

  const int ntiles = (E + 15) >> 4;
  for (int t = wid; t < ntiles; t += nw) {
    const int row = t * 16 + l15;
    const int rowL = (row < E) ? row : (E - 1);
    const int ii = idx_i[rowL];
    const int jj = idx_j[rowL];

    v8s afr[5];
    afr[0] = *(const v8s*)(h_bf + (size_t)ii * 64 + q * 8);
    afr[1] = *(const v8s*)(h_bf + (size_t)ii * 64 + 32 + q * 8);
    afr[2] = *(const v8s*)(h_bf + (size_t)jj * 64 + q * 8);
    afr[3] = *(const v8s*)(h_bf + (size_t)jj * 64 + 32 + q * 8);
    afr[4] = *(const v8s*)(Filt + (size_t)rowL * 32 + q * 8);

    v4f acc2[4];
    #pragma unroll
    for (int nt = 0; nt < 4; ++nt) {
      v4f a = {0.f, 0.f, 0.f, 0.f};
      #pragma unroll
      for (int kc = 0; kc < 5; ++kc)
        a = __builtin_amdgcn_mfma_f32_16x16x32_bf16(afr[kc], bfr2[kc][nt], a, 0, 0, 0);
      acc2[nt] = a;
    }

    #pragma unroll
    for (int nt = 0; nt < 4; ++nt) {
      #pragma unroll
      for (int r = 0; r < 4; ++r)
        tH[w][(q * 4 + r) * THS + nt * 16 + l15] =
            f2bfu(siluf(acc2[nt][r] + bias2[nt]));
    }
    __builtin_amdgcn_wave_barrier();

    v8s af3[2];
    af3[0] = *(const v8s*)&tH[w][l15 * THS + q * 8];
    af3[1] = *(const v8s*)&tH[w][l15 * THS + 32 + q * 8];

    v4f acc3[2];
    #pragma unroll
    for (int nt = 0; nt < 2; ++nt) {
      v4f a = {0.f, 0.f, 0.f, 0.f};
      #pragma unroll
      for (int kc = 0; kc < 2; ++kc)
        a = __builtin_amdgcn_mfma_f32_16x16x32_bf16(af3[kc], bfr3[kc][nt], a, 0, 0, 0);
      acc3[nt] = a;
    }

    const int rowb = t * 16 + q * 4;
    #pragma unroll
    for (int nt = 0; nt < 2; ++nt) {
      const int col = nt * 16 + l15;
      #pragma unroll
      for (int r = 0; r < 4; ++r)
        if (rowb + r < E)
          heb[(size_t)(rowb + r) * 32 + col] = f2bfu(acc3[nt][r] + bias3[nt]);
    }
  }
}

// ---------------------------------------------------------------------------
// Att: per-edge celu logits -> exp, denom atomics
// ---------------------------------------------------------------------------
__global__ __launch_bounds__(256) void att_kernel(
    const ushort_t* __restrict__ heb, const int* __restrict__ idx_i,
    const float* __restrict__ W_att, const float* __restrict__ b_att,
    float* __restrict__ expl, float* __restrict__ denom, int E)
{
  __shared__ float sWa[128];
  __shared__ float sba[4];
  if (threadIdx.x < 128) sWa[threadIdx.x] = W_att[threadIdx.x];
  if (threadIdx.x < 4) sba[threadIdx.x] = b_att[threadIdx.x];
  __syncthreads();
  const int stride = gridDim.x * blockDim.x;
  for (int e = blockIdx.x * blockDim.x + threadIdx.x; e < E; e += stride) {
    float acc[4] = {sba[0], sba[1], sba[2], sba[3]};
    const int4* hv = (const int4*)(heb + (size_t)e * 32);
    #pragma unroll
    for (int blk = 0; blk < 4; ++blk) {
      const int4 pk = hv[blk];
      const unsigned uu[4] = {(unsigned)pk.x, (unsigned)pk.y,
                              (unsigned)pk.z, (unsigned)pk.w};
      #pragma unroll
      for (int u = 0; u < 4; ++u) {
        const int c = blk * 8 + u * 2;
        const float c0 = bflo(uu[u]);
        const float c1 = bfhi(uu[u]);
        #pragma unroll
        for (int tt = 0; tt < 4; ++tt)
          acc[tt] += c0 * sWa[c * 4 + tt] + c1 * sWa[(c + 1) * 4 + tt];
      }
    }
    const int ii = idx_i[e];
    float ev[4];
    #pragma unroll
    for (int tt = 0; tt < 4; ++tt) {
      const float l = (acc[tt] > 0.f) ? acc[tt]
                                      : 2.0f * (__expf(0.5f * acc[tt]) - 1.0f);
      ev[tt] = __expf(l);
    }
    float4 evv = {ev[0], ev[1], ev[2], ev[3]};
    *(float4*)(expl + (size_t)e * 4) = evv;
    #pragma unroll
    for (int tt = 0; tt < 4; ++tt) atomAddF(&denom[ii * 4 + tt], ev[tt]);
  }
}

// ---------------------------------------------------------------------------
// Parallel CSR scan (replaces single-block scan_csr, which was 150 us at
// 0.05% occupancy).  SCAN_T threads each own a contiguous <=SCAN_C node
// chunk.
// ---------------------------------------------------------------------------
#define SCAN_B 64    // blocks for phases 1 & 3
#define SCAN_T (SCAN_B * 256)

__global__ __launch_bounds__(256) void deg_tsum(
    const int* __restrict__ deg, int* __restrict__ tsum, int N, int C)
{
  const int g = blockIdx.x * blockDim.x + threadIdx.x;
  const int lo = g * C;
  const int hi = (lo + C < N) ? (lo + C) : N;
  int s = 0;
  for (int i = lo; i < hi; ++i) s += deg[i];
  tsum[g] = s;
}

__global__ __launch_bounds__(256) void scan_tsum(int* __restrict__ tsum)
{
  __shared__ int ps[256];
  const int t = threadIdx.x;
  const int per = SCAN_T / 256;  // 64
  const int lo = t * per;
  int s = 0;
  for (int i = 0; i < per; ++i) s += tsum[lo + i];
  ps[t] = s;
  __syncthreads();
  if (t == 0) {
    int a = 0;
    for (int i = 0; i < 256; ++i) { const int v = ps[i]; ps[i] = a; a += v; }
  }
  __syncthreads();
  int acc = ps[t];
  for (int i = 0; i < per; ++i) {
    const int v = tsum[lo + i];
    tsum[lo + i] = acc;
    acc += v;
  }
}

__global__ __launch_bounds__(256) void write_csr(
    const int* __restrict__ deg, const int* __restrict__ tpre,
    int* __restrict__ rowstart, int* __restrict__ cursor,
    float* __restrict__ counts, int N, int C)
{
  const int g = blockIdx.x * blockDim.x + threadIdx.x;
  const int lo = g * C;
  const int hi = (lo + C < N) ? (lo + C) : N;
  int acc = tpre[g];
  for (int i = lo; i < hi; ++i) {
    const int d = deg[i];
    rowstart[i] = acc;
    cursor[i] = acc;
    counts[i] = (float)d;
    acc += d;
  }
  if (hi == N) rowstart[N] = acc;  // tail threads all hold the grand total
}

// ---------------------------------------------------------------------------
// bucket_edges: perm[pos] = e, pos from cursor atomics
// ---------------------------------------------------------------------------
__global__ __launch_bounds__(256) void bucket_edges(
    const int* __restrict__ idx_i, int* __restrict__ cursor,
    int* __restrict__ perm, int E)
{
  const int stride = gridDim.x * blockDim.x;
  for (int e = blockIdx.x * blockDim.x + threadIdx.x; e < E; e += stride) {
    const int pos = atomicAdd(&cursor[idx_i[e]], 1);
    perm[pos] = e;
  }
}

// ---------------------------------------------------------------------------
// mix_kernel: per-edge A = att (x) he  ->  MFMA [E,128] x W_x_mix[128,32]
// ---------------------------------------------------------------------------
__global__ __launch_bounds__(256) void mix_kernel(
    const ushort_t* __restrict__ heb, const int* __restrict__ idx_i,
    const float* __restrict__ expl, const float* __restrict__ denom,
    const float* __restrict__ W_xmix, const float* __restrict__ w_vmix,
    ushort_t* __restrict__ mixE, float* __restrict__ pE, int E)
{
  const int tid = blockIdx.x * blockDim.x + threadIdx.x;
  const int wid = tid >> 6;
  const int lane = threadIdx.x & 63;
  const int nw = (gridDim.x * blockDim.x) >> 6;
  const int l15 = lane & 15;
  const int q = lane >> 4;

  v8s bfr[4][2];
  #pragma unroll
  for (int kc = 0; kc < 4; ++kc)
    #pragma unroll
    for (int nt = 0; nt < 2; ++nt)
      #pragma unroll
      for (int j = 0; j < 8; ++j) {
        const int k = kc * 32 + q * 8 + j;
        const int col = nt * 16 + l15;
        bfr[kc][nt][j] = f2bfs(W_xmix[k * 32 + col]);
      }
  float wv[2];
  wv[0] = w_vmix[l15];
  wv[1] = w_vmix[16 + l15];

  const int ntiles = (E + 15) >> 4;
  for (int t = wid; t < ntiles; t += nw) {
    const int row = t * 16 + l15;
    const int rowL = (row < E) ? row : (E - 1);
    const int ii = idx_i[rowL];
    float att[4];
    #pragma unroll
    for (int hh = 0; hh < 4; ++hh)
      att[hh] = expl[(size_t)rowL * 4 + hh] / (denom[ii * 4 + hh] + EPSC);

    const v8s hech = *(const v8s*)(heb + (size_t)rowL * 32 + q * 8);
    float hef[8];
    #pragma unroll
    for (int j = 0; j < 8; ++j) hef[j] = bf2f((ushort_t)hech[j]);

    v8s afr[4];
    #pragma unroll
    for (int kc = 0; kc < 4; ++kc)
      #pragma unroll
      for (int j = 0; j < 8; ++j)
        afr[kc][j] = f2bfs(att[kc] * hef[j]);

    v4f acc[2];
    #pragma unroll
    for (int nt = 0; nt < 2; ++nt) {
      v4f a = {0.f, 0.f, 0.f, 0.f};
      #pragma unroll
      for (int kc = 0; kc < 4; ++kc)
        a = __builtin_amdgcn_mfma_f32_16x16x32_bf16(afr[kc], bfr[kc][nt], a, 0, 0, 0);
      acc[nt] = a;
    }

    const int rowb = t * 16 + q * 4;
    float pr[4];
    #pragma unroll
    for (int r = 0; r < 4; ++r) {
      const float m0 = tanhf(acc[0][r]);
      const float m1 = tanhf(acc[1][r]);
      if (rowb + r < E) {
        mixE[(size_t)(rowb + r) * 32 + l15] = f2bfu(m0);
        mixE[(size_t)(rowb + r) * 32 + 16 + l15] = f2bfu(m1);
      }
      pr[r] = m0 * wv[0] + m1 * wv[1];
    }
    #pragma unroll
    for (int r = 0; r < 4; ++r) {
      pr[r] += __shfl_xor(pr[r], 1);
      pr[r] += __shfl_xor(pr[r], 2);
      pr[r] += __shfl_xor(pr[r], 4);
      pr[r] += __shfl_xor(pr[r], 8);
      if (l15 == 0 && rowb + r < E) pE[rowb + r] = pr[r];
    }
  }
}

// ---------------------------------------------------------------------------
// node_reduce: wave per node, CSR gather-reduce.
// ---------------------------------------------------------------------------
__global__ __launch_bounds__(256) void node_reduce(
    const int* __restrict__ rowstart, const int* __restrict__ perm,
    const ushort_t* __restrict__ heb, const ushort_t* __restrict__ mixE,
    const float* __restrict__ expl, const float* __restrict__ denom,
    const float* __restrict__ dirb, const float* __restrict__ pE,
    ushort_t* __restrict__ hsem, float* __restrict__ comb_sum,
    float* __restrict__ dv_sum, int N)
{
  const int tid = blockIdx.x * blockDim.x + threadIdx.x;
  const int wid = tid >> 6;
  const int lane = threadIdx.x & 63;
  const int nw = (gridDim.x * blockDim.x) >> 6;
  const int hh = lane >> 5;
  const int eb = lane & 31;

  for (int n = wid; n < N; n += nw) {
    const int s = rowstart[n];
    const int epd = rowstart[n + 1];
    float semA = 0.f, semB = 0.f;
    float cx = 0.f, cy = 0.f, cz = 0.f;
    float dvx = 0.f, dvy = 0.f, dvz = 0.f;
    for (int k = s; k < epd; ++k) {
      const int e = perm[k];
      const float he = bf2f(heb[(size_t)e * 32 + eb]);
      const float ea = expl[(size_t)e * 4 + hh];
      const float ec = expl[(size_t)e * 4 + 2 + hh];
      semA += ea * he;
      semB += ec * he;
      const float dx = dirb[e * 3 + 0];
      const float dy = dirb[e * 3 + 1];
      const float dz = dirb[e * 3 + 2];
      if (lane < 32) {
        const float m = bf2f(mixE[(size_t)e * 32 + lane]);
        cx += dx * m; cy += dy * m; cz += dz * m;
      }
      if (lane == 0) {
        const float pe = pE[e];
        dvx += dx * pe; dvy += dy * pe; dvz += dz * pe;
      }
    }
    const float dA = denom[n * 4 + hh] + EPSC;
    const float dB = denom[n * 4 + 2 + hh] + EPSC;
    hsem[(size_t)n * 128 + lane] = f2bfu(semA / dA);
    hsem[(size_t)n * 128 + 64 + lane] = f2bfu(semB / dB);
    if (lane < 32) {
      comb_sum[(size_t)n * 96 + lane * 3 + 0] = cx;
      comb_sum[(size_t)n * 96 + lane * 3 + 1] = cy;
      comb_sum[(size_t)n * 96 + lane * 3 + 2] = cz;
    }
    if (lane == 0) {
      dv_sum[n * 3 + 0] = dvx;
      dv_sum[n * 3 + 1] = dvy;
      dv_sum[n * 3 + 2] = dvz;
    }
  }
}

// ---------------------------------------------------------------------------
// C1 (MFMA): spatial MLP (post1/post2) + node1, wave per 16-node tile.
// ---------------------------------------------------------------------------
#define W1S 232  // col stride in ushorts (464 B, 16B-aligned)
__global__ __launch_bounds__(256) void node_c1_mfma(
    const ushort_t* __restrict__ h_bf, const ushort_t* __restrict__ hsem,
    const float* __restrict__ comb_sum, const float* __restrict__ counts,
    const float* __restrict__ W_post1, const float* __restrict__ b_post1,
    const float* __restrict__ W_post2, const float* __restrict__ b_post2,
    const float* __restrict__ W_node1, const float* __restrict__ b_node1,
    float* __restrict__ nh_out, int N)
{
  __shared__ ushort_t sW1t[128 * W1S];
  __shared__ ushort_t tp[4][16 * THS];

  const int tid = threadIdx.x;
  for (int idx = tid; idx < 224 * 128; idx += 256) {
    const int k = idx >> 7;
    const int c = idx & 127;
    sW1t[c * W1S + k] = f2bfu(W_node1[idx]);
  }
  __syncthreads();

  const int lane = tid & 63;
  const int w = tid >> 6;
  const int l15 = lane & 15;
  const int q = lane >> 4;

  v8s bp1[4];
  #pragma unroll
  for (int nt = 0; nt < 4; ++nt)
    #pragma unroll
    for (int j = 0; j < 8; ++j)
      bp1[nt][j] = f2bfs(W_post1[(q * 8 + j) * 64 + nt * 16 + l15]);
  v8s bp2[2][2];
  #pragma unroll
  for (int kc = 0; kc < 2; ++kc)
    #pragma unroll
    for (int nt = 0; nt < 2; ++nt)
      #pragma unroll
      for (int j = 0; j < 8; ++j)
        bp2[kc][nt][j] = f2bfs(W_post2[(kc * 32 + q * 8 + j) * 32 + nt * 16 + l15]);
  float bb1[4];
  #pragma unroll
  for (int nt = 0; nt < 4; ++nt) bb1[nt] = b_post1[nt * 16 + l15];
  float bb2[2];
  #pragma unroll
  for (int nt = 0; nt < 2; ++nt) bb2[nt] = b_post2[nt * 16 + l15];
  float b1[8];
  #pragma unroll
  for (int nt = 0; nt < 8; ++nt) b1[nt] = b_node1[nt * 16 + l15];

  const int gw = blockIdx.x * 4 + w;
  const int nwv = gridDim.x * 4;
  const int ntiles = (N + 15) >> 4;

  for (int t = gw; t < ntiles; t += nwv) {
    const int row = t * 16 + l15;
    const int rowL = (row < N) ? row : (N - 1);

    const float inv = 1.0f / fmaxf(counts[rowL], 1.0f);
    const float4* cs = (const float4*)(comb_sum + (size_t)rowL * 96 + q * 24);
    float cf[24];
    #pragma unroll
    for (int b = 0; b < 6; ++b) {
      const float4 cv = cs[b];
      cf[b * 4 + 0] = cv.x; cf[b * 4 + 1] = cv.y;
      cf[b * 4 + 2] = cv.z; cf[b * 4 + 3] = cv.w;
    }
    v8s a1;
    #pragma unroll
    for (int j = 0; j < 8; ++j) {
      const float vx = cf[j * 3 + 0] * inv;
      const float vy = cf[j * 3 + 1] * inv;
      const float vz = cf[j * 3 + 2] * inv;
      a1[j] = f2bfs(vx * vx + vy * vy + vz * vz);
    }

    v4f p1[4];
    #pragma unroll
    for (int nt = 0; nt < 4; ++nt) {
      v4f a = {0.f, 0.f, 0.f, 0.f};
      p1[nt] = __builtin_amdgcn_mfma_f32_16x16x32_bf16(a1, bp1[nt], a, 0, 0, 0);
    }
    #pragma unroll
    for (int nt = 0; nt < 4; ++nt)
      #pragma unroll
      for (int r = 0; r < 4; ++r)
        tp[w][(q * 4 + r) * THS + nt * 16 + l15] =
            f2bfu(siluf(p1[nt][r] + bb1[nt]));
    __builtin_amdgcn_wave_barrier();

    v8s a2[2];
    a2[0] = *(const v8s*)&tp[w][l15 * THS + q * 8];
    a2[1] = *(const v8s*)&tp[w][l15 * THS + 32 + q * 8];

    v4f p2[2];
    #pragma unroll
    for (int nt = 0; nt < 2; ++nt) {
      v4f a = {0.f, 0.f, 0.f, 0.f};
      #pragma unroll
      for (int kc = 0; kc < 2; ++kc)
        a = __builtin_amdgcn_mfma_f32_16x16x32_bf16(a2[kc], bp2[kc][nt], a, 0, 0, 0);
      p2[nt] = a;
    }
    __builtin_amdgcn_wave_barrier();
    #pragma unroll
    for (int nt = 0; nt < 2; ++nt)
      #pragma unroll
      for (int r = 0; r < 4; ++r)
        tp[w][(q * 4 + r) * THS + nt * 16 + l15] =
            f2bfu(siluf(p2[nt][r] + bb2[nt]));
    __builtin_amdgcn_wave_barrier();

    v8s af[7];
    af[0] = *(const v8s*)(h_bf + (size_t)rowL * 64 + q * 8);
    af[1] = *(const v8s*)(h_bf + (size_t)rowL * 64 + 32 + q * 8);
    #pragma unroll
    for (int kc = 0; kc < 4; ++kc)
      af[2 + kc] = *(const v8s*)(hsem + (size_t)rowL * 128 + kc * 32 + q * 8);
    af[6] = *(const v8s*)&tp[w][l15 * THS + q * 8];

    v4f acc[8];
    #pragma unroll
    for (int nt = 0; nt < 8; ++nt) acc[nt] = (v4f){0.f, 0.f, 0.f, 0.f};
    #pragma unroll
    for (int kc = 0; kc < 7; ++kc) {
      #pragma unroll
      for (int nt = 0; nt < 8; ++nt) {
        const v8s bfrag =
            *(const v8s*)&sW1t[(nt * 16 + l15) * W1S + kc * 32 + q * 8];
        acc[nt] = __builtin_amdgcn_mfma_f32_16x16x32_bf16(af[kc], bfrag, acc[nt], 0, 0, 0);
      }
    }

    const int rowb = t * 16 + q * 4;
    #pragma unroll
    for (int nt = 0; nt < 8; ++nt) {
      #pragma unroll
      for (int r = 0; r < 4; ++r)
        if (rowb + r < N)
          nh_out[(size_t)(rowb + r) * 128 + nt * 16 + l15] =
              siluf(acc[nt][r] + b1[nt]);
    }
  }
}

// ---------------------------------------------------------------------------
// Pass C2: h_upd, gate, v_upd, x_upd -> d_out
// ---------------------------------------------------------------------------
__global__ __launch_bounds__(256) void node_pass_c2(
    const float* __restrict__ h, const float* __restrict__ x,
    const float* __restrict__ v, const float* __restrict__ nh,
    const float* __restrict__ dv_sum, const float* __restrict__ counts,
    const float* __restrict__ W_node2, const float* __restrict__ b_node2,
    const float* __restrict__ W_vel1, const float* __restrict__ b_vel1,
    const float* __restrict__ W_vel2,
    float* __restrict__ out, int N, int nIter)
{
  __shared__ float sW2[128 * 64];
  __shared__ float sWv1[64 * 32];
  __shared__ float sb2[64];
  __shared__ float sbv1[32];
  __shared__ float sWv2[32];
  __shared__ float snh[4][128];
  __shared__ float shu[4][64];

  const int tid = threadIdx.x;
  for (int k = tid; k < 128 * 64; k += 256) sW2[k] = W_node2[k];
  for (int k = tid; k < 64 * 32; k += 256) sWv1[k] = W_vel1[k];
  for (int k = tid; k < 64; k += 256) sb2[k] = b_node2[k];
  for (int k = tid; k < 32; k += 256) sbv1[k] = b_vel1[k];
  for (int k = tid; k < 32; k += 256) sWv2[k] = W_vel2[k];
  __syncthreads();

  const int lane = tid & 63;
  const int w = tid >> 6;
  const int gw = blockIdx.x * 4 + w;
  const int stride = gridDim.x * 4;

  for (int it = 0; it < nIter; ++it) {
    const int n = gw + it * stride;
    const bool active = (n < N);
    if (active) {
      snh[w][lane] = nh[(size_t)n * 128 + lane];
      snh[w][64 + lane] = nh[(size_t)n * 128 + 64 + lane];
    }
    __syncthreads();
    if (active) {
      float acc = sb2[lane];
      #pragma unroll 8
      for (int k = 0; k < 128; ++k) acc += snh[w][k] * sW2[k * 64 + lane];
      const float hu = h[n * DA + lane] + siluf(acc);
      out[(size_t)n * DA + lane] = hu;
      shu[w][lane] = hu;
    }
    __syncthreads();
    if (active) {
      float p = 0.f;
      if (lane < 32) {
        float acc = sbv1[lane];
        #pragma unroll 8
        for (int k = 0; k < 64; ++k) acc += shu[w][k] * sWv1[k * 32 + lane];
        p = siluf(acc) * sWv2[lane];
      }
      p += __shfl_xor(p, 16);
      p += __shfl_xor(p, 8);
      p += __shfl_xor(p, 4);
      p += __shfl_xor(p, 2);
      p += __shfl_xor(p, 1);
      const float s = __shfl(p, 0);
      const float gate = 2.0f / (1.0f + __expf(-s));
      if (lane < 3) {
        const float cnt = fmaxf(counts[n], 1.0f);
        const float dvx = dv_sum[n * 3 + lane] / cnt;
        const float vu = gate * v[n * 3 + lane] + dvx;
        out[(size_t)N * 64 + n * 3 + lane] = x[n * 3 + lane] + vu;
        out[(size_t)N * 64 + (size_t)N * 3 + n * 3 + lane] = vu;
      }
    }
    __syncthreads();
  }
}

// ---------------------------------------------------------------------------
extern "C" void kernel_launch(void* const* d_in, const int* in_sizes, int n_in,
                              void* d_out, int out_size, void* d_ws, size_t ws_size,
                              hipStream_t stream) {
  const float* h   = (const float*)d_in[0];
  const float* x   = (const float*)d_in[1];
  const float* v   = (const float*)d_in[2];
  const int* idx_i = (const int*)d_in[3];
  const int* idx_j = (const int*)d_in[4];
  const float* W_edge_in  = (const float*)d_in[5];
  const float* b_edge_in  = (const float*)d_in[6];
  const float* W_edge_h   = (const float*)d_in[7];
  const float* b_edge_h   = (const float*)d_in[8];
  const float* W_edge_out = (const float*)d_in[9];
  const float* b_edge_out = (const float*)d_in[10];
  const float* W_att      = (const float*)d_in[11];
  const float* b_att      = (const float*)d_in[12];
  const float* W_x_mix    = (const float*)d_in[13];
  const float* W_node1    = (const float*)d_in[14];
  const float* b_node1    = (const float*)d_in[15];
  const float* W_node2    = (const float*)d_in[16];
  const float* b_node2    = (const float*)d_in[17];
  const float* W_post1    = (const float*)d_in[18];
  const float* b_post1    = (const float*)d_in[19];
  const float* W_post2    = (const float*)d_in[20];
  const float* b_post2    = (const float*)d_in[21];
  const float* W_vel1     = (const float*)d_in[22];
  const float* b_vel1     = (const float*)d_in[23];
  const float* W_vel2     = (const float*)d_in[24];
  const float* w_v_mix    = (const float*)d_in[25];

  const int E = in_sizes[3];
  const int N = in_sizes[0] / DA;

  float* ws = (float*)d_ws;
  size_t off = 0;
  float* denom    = ws + off; off += (size_t)N * 4;     // zeroed
  int*   deg      = (int*)(ws + off); off += (size_t)N; // zeroed
  const size_t zeroBytes = off * sizeof(float);
  float* counts   = ws + off; off += (size_t)N;
  int*   rowstart = (int*)(ws + off); off += (size_t)N + 4;
  int*   cursor   = (int*)(ws + off); off += (size_t)N;
  int*   tsum     = (int*)(ws + off); off += (size_t)SCAN_T;
  int*   perm     = (int*)(ws + off); off += (size_t)E;
  float* pE       = ws + off; off += (size_t)E;
  float* expl     = ws + off; off += (size_t)E * 4;
  float* dirb     = ws + off; off += (size_t)E * 3;
  float* hsemR    = ws + off; off += (size_t)N * 64;    // hsem bf16 [N,128]
  float* comb_sum = ws + off; off += (size_t)N * 96;
  float* dv_sum   = ws + off; off += (size_t)N * 4;
  float* hbfR     = ws + off; off += (size_t)N * 32;    // h_bf bf16 [N,64]
  float* fltR     = ws + off; off += (size_t)E * 16;    // Filt / mixE / nh
  float* hebR     = ws + off; off += (size_t)E * 16;    // heb bf16 [E,32]

  ushort_t* h_bf = (ushort_t*)hbfR;
  ushort_t* hsem = (ushort_t*)hsemR;
  ushort_t* Filt = (ushort_t*)fltR;
  ushort_t* heb  = (ushort_t*)hebR;
  ushort_t* mixE = (ushort_t*)fltR;  // aliases Filt (dead after edge_f2)
  float* nh = fltR;                  // aliases mixE (dead after node_reduce)

  hipMemsetAsync(d_ws, 0, zeroBytes, stream);

  {
    const int n4 = (N * 64) / 4;
    cast_h<<<(n4 + 255) / 256, 256, 0, stream>>>(h, h_bf, n4);
  }
  edge_f1<<<1024, 256, 0, stream>>>(h_bf, x, idx_i, idx_j, W_edge_in,
                                    b_edge_in, Filt, dirb, deg, E);
  {
    const int C = (N + SCAN_T - 1) / SCAN_T;
    deg_tsum<<<SCAN_B, 256, 0, stream>>>(deg, tsum, N, C);
    scan_tsum<<<1, 256, 0, stream>>>(tsum);
    write_csr<<<SCAN_B, 256, 0, stream>>>(deg, tsum, rowstart, cursor, counts, N, C);
  }
  bucket_edges<<<512, 256, 0, stream>>>(idx_i, cursor, perm, E);
  edge_f2<<<1024, 256, 0, stream>>>(h_bf, idx_i, idx_j, Filt, W_edge_h,
                                    b_edge_h, W_edge_out, b_edge_out, heb, E);
  att_kernel<<<1024, 256, 0, stream>>>(heb, idx_i, W_att, b_att, expl, denom, E);
  mix_kernel<<<1024, 256, 0, stream>>>(heb, idx_i, expl, denom, W_x_mix,
                                       w_v_mix, mixE, pE, E);
  node_reduce<<<2048, 256, 0, stream>>>(rowstart, perm, heb, mixE, expl, denom,
                                        dirb, pE, hsem, comb_sum, dv_sum, N);
  node_c1_mfma<<<512, 256, 0, stream>>>(
      h_bf, hsem, comb_sum, counts, W_post1, b_post1, W_post2, b_post2,
      W_node1, b_node1, nh, N);
  {
    const int grid = 1024;
    const int nIter = (N + grid * 4 - 1) / (grid * 4);
    node_pass_c2<<<grid, 256, 0, stream>>>(
        h, x, v, nh, dv_sum, counts, W_node2, b_node2, W_vel1, b_vel1, W_vel2,
        (float*)d_out, N, nIter);
  }
}

// Round 7
// 590.495 us; speedup vs baseline: 4.6295x; 1.1246x over previous
//
#include <hip/hip_runtime.h>
#include <math.h>

// Problem dims (fixed by reference)
#define DA 64    // A
#define NODEIN_DIM 224 // A + H*EB + S

#define EPSC 1e-8f

typedef short v8s __attribute__((ext_vector_type(8)));
typedef float v4f __attribute__((ext_vector_type(4)));
typedef unsigned short ushort_t;

__device__ __forceinline__ float siluf(float v) { return v / (1.0f + __expf(-v)); }

__device__ __forceinline__ void atomAddF(float* p, float v) {
#if defined(__HIP_DEVICE_COMPILE__)
  unsafeAtomicAdd(p, v);
#else
  atomicAdd(p, v);
#endif
}

__device__ __forceinline__ unsigned short f2bfu(float f) {
  union { float f; unsigned u; } v; v.f = f;
  unsigned r = v.u + 0x7fffu + ((v.u >> 16) & 1u);
  return (unsigned short)(r >> 16);
}
__device__ __forceinline__ short f2bfs(float f) { return (short)f2bfu(f); }
__device__ __forceinline__ float bf2f(ushort_t s) {
  union { unsigned u; float f; } v; v.u = ((unsigned)s) << 16; return v.f;
}

#define MU0 0.60653065971263342f
#define DMU ((1.0f - 0.60653065971263342f) / 19.0f)
#define BETA ((float)(1.0 / (0.039346934028736658 * 0.039346934028736658)))

// ---------------------------------------------------------------------------
// cast_h: h fp32 -> bf16 copy
// ---------------------------------------------------------------------------
__global__ __launch_bounds__(256) void cast_h(
    const float* __restrict__ hsrc, ushort_t* __restrict__ hb, int n4)
{
  const int i = blockIdx.x * blockDim.x + threadIdx.x;
  if (i < n4) {
    const float4 fv = ((const float4*)hsrc)[i];
    ushort4 o;
    o.x = f2bfu(fv.x); o.y = f2bfu(fv.y); o.z = f2bfu(fv.z); o.w = f2bfu(fv.w);
    ((ushort4*)hb)[i] = o;
  }
}

// ---------------------------------------------------------------------------
// F1: gather + geometry + M1 ([E,128] x W_in[128,20]) + RBF epilogue.
// ---------------------------------------------------------------------------
__global__ __launch_bounds__(256) void edge_f1(
    const ushort_t* __restrict__ h_bf, const float* __restrict__ x,
    const int* __restrict__ idx_i, const int* __restrict__ idx_j,
    const float* __restrict__ W_in, const float* __restrict__ b_in,
    ushort_t* __restrict__ Filt, float* __restrict__ dirb,
    int* __restrict__ deg, int E)
{
  const int tid = blockIdx.x * blockDim.x + threadIdx.x;
  const int wid = tid >> 6;
  const int lane = threadIdx.x & 63;
  const int nw = (gridDim.x * blockDim.x) >> 6;
  const int l15 = lane & 15;
  const int q = lane >> 4;

  v8s bfr[4][2];
  #pragma unroll
  for (int kc = 0; kc < 4; ++kc)
    #pragma unroll
    for (int nt = 0; nt < 2; ++nt)
      #pragma unroll
      for (int j = 0; j < 8; ++j) {
        const int k = kc * 32 + q * 8 + j;
        const int col = nt * 16 + l15;
        bfr[kc][nt][j] = (col < 20) ? f2bfs(W_in[k * 20 + col]) : (short)0;
      }
  float bin[2], mu[2];
  #pragma unroll
  for (int nt = 0; nt < 2; ++nt) {
    const int col = nt * 16 + l15;
    bin[nt] = (col < 20) ? b_in[col] : 0.0f;
    mu[nt] = MU0 + (float)col * DMU;
  }

  const int ntiles = (E + 15) >> 4;
  for (int t = wid; t < ntiles; t += nw) {
    const int row = t * 16 + l15;
    const int rowL = (row < E) ? row : (E - 1);
    const int ii = idx_i[rowL];
    const int jj = idx_j[rowL];

    v8s afr[4];
    afr[0] = *(const v8s*)(h_bf + (size_t)ii * 64 + q * 8);
    afr[1] = *(const v8s*)(h_bf + (size_t)ii * 64 + 32 + q * 8);
    afr[2] = *(const v8s*)(h_bf + (size_t)jj * 64 + q * 8);
    afr[3] = *(const v8s*)(h_bf + (size_t)jj * 64 + 32 + q * 8);

    float dval = 0.0f;
    if (lane < 16 && row < E) {
      const float rx = x[jj * 3 + 0] - x[ii * 3 + 0];
      const float ry = x[jj * 3 + 1] - x[ii * 3 + 1];
      const float rz = x[jj * 3 + 2] - x[ii * 3 + 2];
      const float d = sqrtf(rx * rx + ry * ry + rz * rz + EPSC);
      dval = d;
      const float inv = 1.0f / (d + EPSC);
      dirb[row * 3 + 0] = rx * inv;
      dirb[row * 3 + 1] = ry * inv;
      dirb[row * 3 + 2] = rz * inv;
      atomicAdd(&deg[ii], 1);
    }

    v4f acc[2];
    #pragma unroll
    for (int nt = 0; nt < 2; ++nt) {
      v4f a = {0.f, 0.f, 0.f, 0.f};
      #pragma unroll
      for (int kc = 0; kc < 4; ++kc)
        a = __builtin_amdgcn_mfma_f32_16x16x32_bf16(afr[kc], bfr[kc][nt], a, 0, 0, 0);
      acc[nt] = a;
    }

    const int rowb = t * 16 + q * 4;
    float dr[4], edr[4];
    #pragma unroll
    for (int r = 0; r < 4; ++r) {
      dr[r] = __shfl(dval, q * 4 + r);
      edr[r] = __expf(-dr[r]);
    }
    #pragma unroll
    for (int nt = 0; nt < 2; ++nt) {
      const int col = nt * 16 + l15;
      #pragma unroll
      for (int r = 0; r < 4; ++r) {
        ushort_t ov;
        if (col < 20) {
          const float tt = edr[r] - mu[nt];
          ov = f2bfu((acc[nt][r] + bin[nt]) * __expf(-BETA * tt * tt));
        } else if (col == 20) {
          ov = f2bfu(dr[r]);
        } else {
          ov = 0;
        }
        if (rowb + r < E) Filt[(size_t)(rowb + r) * 32 + col] = ov;
      }
    }
  }
}

// ---------------------------------------------------------------------------
// F2: M2 ([E,160] x W_h, silu) + LDS transpose + M3 -> heb[E,32] bf16
//   + fused att epilogue (celu logits -> exp -> expl, denom atomics).
// W_h/W_out B-fragments live in LDS (shared by the block's 4 waves) to keep
// VGPR <= ~100: at 132 VGPRs occupancy was 2 waves/SIMD (halves at 128) and
// the kernel was gather-latency-bound at 11% occupancy.
// ---------------------------------------------------------------------------
#define THS 72
__global__ __launch_bounds__(256) void edge_f2(
    const ushort_t* __restrict__ h_bf,
    const int* __restrict__ idx_i, const int* __restrict__ idx_j,
    const ushort_t* __restrict__ Filt,
    const float* __restrict__ W_h, const float* __restrict__ b_h,
    const float* __restrict__ W_out, const float* __restrict__ b_out,
    const float* __restrict__ W_att, const float* __restrict__ b_att,
    ushort_t* __restrict__ heb, float* __restrict__ expl,
    float* __restrict__ denom, int E)
{
  __shared__ ushort_t sB2[20 * 64 * 8];   // 20 KB: W_h fragments (kc,nt)
  __shared__ ushort_t sB3[4 * 64 * 8];    // 4 KB: W_out fragments
  __shared__ ushort_t tH[4][16 * THS];    // 9 KB: per-wave transpose tile
  __shared__ float sWa[132];              // W_att + b_att

  const int tid = threadIdx.x;
  for (int idx = tid; idx < 20 * 64 * 8; idx += 256) {
    const int j = idx & 7;
    const int ln = (idx >> 3) & 63;
    const int f = idx >> 9;               // 0..19 = kc*4+nt
    const int k = (f >> 2) * 32 + (ln >> 4) * 8 + j;
    const int col = (f & 3) * 16 + (ln & 15);
    sB2[idx] = (k < 149) ? f2bfu(W_h[k * 64 + col]) : (ushort_t)0;
  }
  for (int idx = tid; idx < 4 * 64 * 8; idx += 256) {
    const int j = idx & 7;
    const int ln = (idx >> 3) & 63;
    const int f = idx >> 9;               // 0..3 = kc*2+nt
    const int k = (f >> 1) * 32 + (ln >> 4) * 8 + j;
    const int col = (f & 1) * 16 + (ln & 15);
    sB3[idx] = f2bfu(W_out[k * 32 + col]);
  }
  if (tid < 128) sWa[tid] = W_att[tid];
  if (tid < 4) sWa[128 + tid] = b_att[tid];
  __syncthreads();

  const int gtid = blockIdx.x * blockDim.x + tid;
  const int wid = gtid >> 6;
  const int lane = tid & 63;
  const int w = tid >> 6;
  const int nw = (gridDim.x * blockDim.x) >> 6;
  const int l15 = lane & 15;
  const int q = lane >> 4;

  const ushort_t* b2l = sB2 + lane * 8;
  const ushort_t* b3l = sB3 + lane * 8;

  float bias2[4];
  #pragma unroll
  for (int nt = 0; nt < 4; ++nt) bias2[nt] = b_h[nt * 16 + l15];
  float bias3[2];
  #pragma unroll
  for (int nt = 0; nt < 2; ++nt) bias3[nt] = b_out[nt * 16 + l15];

  const int ntiles = (E + 15) >> 4;
  for (int t = wid; t < ntiles; t += nw) {
    const int row = t * 16 + l15;
    const int rowL = (row < E) ? row : (E - 1);
    const int ii = idx_i[rowL];
    const int jj = idx_j[rowL];

    v8s afr[5];
    afr[0] = *(const v8s*)(h_bf + (size_t)ii * 64 + q * 8);
    afr[1] = *(const v8s*)(h_bf + (size_t)ii * 64 + 32 + q * 8);
    afr[2] = *(const v8s*)(h_bf + (size_t)jj * 64 + q * 8);
    afr[3] = *(const v8s*)(h_bf + (size_t)jj * 64 + 32 + q * 8);
    afr[4] = *(const v8s*)(Filt + (size_t)rowL * 32 + q * 8);

    v4f acc2[4];
    #pragma unroll
    for (int nt = 0; nt < 4; ++nt) {
      v4f a = {0.f, 0.f, 0.f, 0.f};
      #pragma unroll
      for (int kc = 0; kc < 5; ++kc) {
        const v8s bfrag = *(const v8s*)(b2l + (kc * 4 + nt) * 512);
        a = __builtin_amdgcn_mfma_f32_16x16x32_bf16(afr[kc], bfrag, a, 0, 0, 0);
      }
      acc2[nt] = a;
    }

    #pragma unroll
    for (int nt = 0; nt < 4; ++nt) {
      #pragma unroll
      for (int r = 0; r < 4; ++r)
        tH[w][(q * 4 + r) * THS + nt * 16 + l15] =
            f2bfu(siluf(acc2[nt][r] + bias2[nt]));
    }
    __builtin_amdgcn_wave_barrier();

    v8s af3[2];
    af3[0] = *(const v8s*)&tH[w][l15 * THS + q * 8];
    af3[1] = *(const v8s*)&tH[w][l15 * THS + 32 + q * 8];

    v4f acc3[2];
    #pragma unroll
    for (int nt = 0; nt < 2; ++nt) {
      v4f a = {0.f, 0.f, 0.f, 0.f};
      #pragma unroll
      for (int kc = 0; kc < 2; ++kc) {
        const v8s bfrag = *(const v8s*)(b3l + (kc * 2 + nt) * 512);
        a = __builtin_amdgcn_mfma_f32_16x16x32_bf16(af3[kc], bfrag, a, 0, 0, 0);
      }
      acc3[nt] = a;
    }
    __builtin_amdgcn_wave_barrier();  // tH reuse below

    const int rowb = t * 16 + q * 4;
    #pragma unroll
    for (int nt = 0; nt < 2; ++nt) {
      const int col = nt * 16 + l15;
      #pragma unroll
      for (int r = 0; r < 4; ++r) {
        const ushort_t hv = f2bfu(acc3[nt][r] + bias3[nt]);
        tH[w][(q * 4 + r) * THS + col] = hv;
        if (rowb + r < E) heb[(size_t)(rowb + r) * 32 + col] = hv;
      }
    }
    __builtin_amdgcn_wave_barrier();

    // fused att: lanes q==0 each own row l15 of the tile
    if (q == 0 && row < E) {
      float la[4] = {sWa[128], sWa[129], sWa[130], sWa[131]};
      const ushort_t* rp = &tH[w][l15 * THS];
      #pragma unroll
      for (int c = 0; c < 32; ++c) {
        const float he = bf2f(rp[c]);
        #pragma unroll
        for (int t4 = 0; t4 < 4; ++t4) la[t4] += he * sWa[c * 4 + t4];
      }
      float ev[4];
      #pragma unroll
      for (int t4 = 0; t4 < 4; ++t4) {
        const float l = (la[t4] > 0.f) ? la[t4]
                                       : 2.0f * (__expf(0.5f * la[t4]) - 1.0f);
        ev[t4] = __expf(l);
      }
      float4 evv = {ev[0], ev[1], ev[2], ev[3]};
      *(float4*)(expl + (size_t)row * 4) = evv;
      #pragma unroll
      for (int t4 = 0; t4 < 4; ++t4) atomAddF(&denom[ii * 4 + t4], ev[t4]);
    }
    __builtin_amdgcn_wave_barrier();
  }
}

// ---------------------------------------------------------------------------
// Parallel CSR scan
// ---------------------------------------------------------------------------
#define SCAN_B 64
#define SCAN_T (SCAN_B * 256)

__global__ __launch_bounds__(256) void deg_tsum(
    const int* __restrict__ deg, int* __restrict__ tsum, int N, int C)
{
  const int g = blockIdx.x * blockDim.x + threadIdx.x;
  const int lo = g * C;
  const int hi = (lo + C < N) ? (lo + C) : N;
  int s = 0;
  for (int i = lo; i < hi; ++i) s += deg[i];
  tsum[g] = s;
}

__global__ __launch_bounds__(256) void scan_tsum(int* __restrict__ tsum)
{
  __shared__ int ps[256];
  const int t = threadIdx.x;
  const int per = SCAN_T / 256;
  const int lo = t * per;
  int s = 0;
  for (int i = 0; i < per; ++i) s += tsum[lo + i];
  ps[t] = s;
  __syncthreads();
  if (t == 0) {
    int a = 0;
    for (int i = 0; i < 256; ++i) { const int v = ps[i]; ps[i] = a; a += v; }
  }
  __syncthreads();
  int acc = ps[t];
  for (int i = 0; i < per; ++i) {
    const int v = tsum[lo + i];
    tsum[lo + i] = acc;
    acc += v;
  }
}

__global__ __launch_bounds__(256) void write_csr(
    const int* __restrict__ deg, const int* __restrict__ tpre,
    int* __restrict__ rowstart, int* __restrict__ cursor,
    float* __restrict__ counts, int N, int C)
{
  const int g = blockIdx.x * blockDim.x + threadIdx.x;
  const int lo = g * C;
  const int hi = (lo + C < N) ? (lo + C) : N;
  int acc = tpre[g];
  for (int i = lo; i < hi; ++i) {
    const int d = deg[i];
    rowstart[i] = acc;
    cursor[i] = acc;
    counts[i] = (float)d;
    acc += d;
  }
  if (hi == N) rowstart[N] = acc;
}

// ---------------------------------------------------------------------------
// bucket_edges: perm[pos] = e, pos from cursor atomics
// ---------------------------------------------------------------------------
__global__ __launch_bounds__(256) void bucket_edges(
    const int* __restrict__ idx_i, int* __restrict__ cursor,
    int* __restrict__ perm, int E)
{
  const int stride = gridDim.x * blockDim.x;
  for (int e = blockIdx.x * blockDim.x + threadIdx.x; e < E; e += stride) {
    const int pos = atomicAdd(&cursor[idx_i[e]], 1);
    perm[pos] = e;
  }
}

// ---------------------------------------------------------------------------
// mix_kernel: per-edge A = att (x) he  ->  MFMA [E,128] x W_x_mix[128,32]
// ---------------------------------------------------------------------------
__global__ __launch_bounds__(256) void mix_kernel(
    const ushort_t* __restrict__ heb, const int* __restrict__ idx_i,
    const float* __restrict__ expl, const float* __restrict__ denom,
    const float* __restrict__ W_xmix, const float* __restrict__ w_vmix,
    ushort_t* __restrict__ mixE, float* __restrict__ pE, int E)
{
  const int tid = blockIdx.x * blockDim.x + threadIdx.x;
  const int wid = tid >> 6;
  const int lane = threadIdx.x & 63;
  const int nw = (gridDim.x * blockDim.x) >> 6;
  const int l15 = lane & 15;
  const int q = lane >> 4;

  v8s bfr[4][2];
  #pragma unroll
  for (int kc = 0; kc < 4; ++kc)
    #pragma unroll
    for (int nt = 0; nt < 2; ++nt)
      #pragma unroll
      for (int j = 0; j < 8; ++j) {
        const int k = kc * 32 + q * 8 + j;
        const int col = nt * 16 + l15;
        bfr[kc][nt][j] = f2bfs(W_xmix[k * 32 + col]);
      }
  float wv[2];
  wv[0] = w_vmix[l15];
  wv[1] = w_vmix[16 + l15];

  const int ntiles = (E + 15) >> 4;
  for (int t = wid; t < ntiles; t += nw) {
    const int row = t * 16 + l15;
    const int rowL = (row < E) ? row : (E - 1);
    const int ii = idx_i[rowL];
    float att[4];
    #pragma unroll
    for (int hh = 0; hh < 4; ++hh)
      att[hh] = expl[(size_t)rowL * 4 + hh] / (denom[ii * 4 + hh] + EPSC);

    const v8s hech = *(const v8s*)(heb + (size_t)rowL * 32 + q * 8);
    float hef[8];
    #pragma unroll
    for (int j = 0; j < 8; ++j) hef[j] = bf2f((ushort_t)hech[j]);

    v8s afr[4];
    #pragma unroll
    for (int kc = 0; kc < 4; ++kc)
      #pragma unroll
      for (int j = 0; j < 8; ++j)
        afr[kc][j] = f2bfs(att[kc] * hef[j]);

    v4f acc[2];
    #pragma unroll
    for (int nt = 0; nt < 2; ++nt) {
      v4f a = {0.f, 0.f, 0.f, 0.f};
      #pragma unroll
      for (int kc = 0; kc < 4; ++kc)
        a = __builtin_amdgcn_mfma_f32_16x16x32_bf16(afr[kc], bfr[kc][nt], a, 0, 0, 0);
      acc[nt] = a;
    }

    const int rowb = t * 16 + q * 4;
    float pr[4];
    #pragma unroll
    for (int r = 0; r < 4; ++r) {
      const float m0 = tanhf(acc[0][r]);
      const float m1 = tanhf(acc[1][r]);
      if (rowb + r < E) {
        mixE[(size_t)(rowb + r) * 32 + l15] = f2bfu(m0);
        mixE[(size_t)(rowb + r) * 32 + 16 + l15] = f2bfu(m1);
      }
      pr[r] = m0 * wv[0] + m1 * wv[1];
    }
    #pragma unroll
    for (int r = 0; r < 4; ++r) {
      pr[r] += __shfl_xor(pr[r], 1);
      pr[r] += __shfl_xor(pr[r], 2);
      pr[r] += __shfl_xor(pr[r], 4);
      pr[r] += __shfl_xor(pr[r], 8);
      if (l15 == 0 && rowb + r < E) pE[rowb + r] = pr[r];
    }
  }
}

// ---------------------------------------------------------------------------
// node_reduce: wave per node, CSR gather-reduce.
// ---------------------------------------------------------------------------
__global__ __launch_bounds__(256) void node_reduce(
    const int* __restrict__ rowstart, const int* __restrict__ perm,
    const ushort_t* __restrict__ heb, const ushort_t* __restrict__ mixE,
    const float* __restrict__ expl, const float* __restrict__ denom,
    const float* __restrict__ dirb, const float* __restrict__ pE,
    ushort_t* __restrict__ hsem, float* __restrict__ comb_sum,
    float* __restrict__ dv_sum, int N)
{
  const int tid = blockIdx.x * blockDim.x + threadIdx.x;
  const int wid = tid >> 6;
  const int lane = threadIdx.x & 63;
  const int nw = (gridDim.x * blockDim.x) >> 6;
  const int hh = lane >> 5;
  const int eb = lane & 31;

  for (int n = wid; n < N; n += nw) {
    const int s = rowstart[n];
    const int epd = rowstart[n + 1];
    float semA = 0.f, semB = 0.f;
    float cx = 0.f, cy = 0.f, cz = 0.f;
    float dvx = 0.f, dvy = 0.f, dvz = 0.f;
    for (int k = s; k < epd; ++k) {
      const int e = perm[k];
      const float he = bf2f(heb[(size_t)e * 32 + eb]);
      const float ea = expl[(size_t)e * 4 + hh];
      const float ec = expl[(size_t)e * 4 + 2 + hh];
      semA += ea * he;
      semB += ec * he;
      const float dx = dirb[e * 3 + 0];
      const float dy = dirb[e * 3 + 1];
      const float dz = dirb[e * 3 + 2];
      if (lane < 32) {
        const float m = bf2f(mixE[(size_t)e * 32 + lane]);
        cx += dx * m; cy += dy * m; cz += dz * m;
      }
      if (lane == 0) {
        const float pe = pE[e];
        dvx += dx * pe; dvy += dy * pe; dvz += dz * pe;
      }
    }
    const float dA = denom[n * 4 + hh] + EPSC;
    const float dB = denom[n * 4 + 2 + hh] + EPSC;
    hsem[(size_t)n * 128 + lane] = f2bfu(semA / dA);
    hsem[(size_t)n * 128 + 64 + lane] = f2bfu(semB / dB);
    if (lane < 32) {
      comb_sum[(size_t)n * 96 + lane * 3 + 0] = cx;
      comb_sum[(size_t)n * 96 + lane * 3 + 1] = cy;
      comb_sum[(size_t)n * 96 + lane * 3 + 2] = cz;
    }
    if (lane == 0) {
      dv_sum[n * 3 + 0] = dvx;
      dv_sum[n * 3 + 1] = dvy;
      dv_sum[n * 3 + 2] = dvz;
    }
  }
}

// ---------------------------------------------------------------------------
// C1 (MFMA): spatial MLP (post1/post2) + node1, wave per 16-node tile.
// ---------------------------------------------------------------------------
#define W1S 232
__global__ __launch_bounds__(256) void node_c1_mfma(
    const ushort_t* __restrict__ h_bf, const ushort_t* __restrict__ hsem,
    const float* __restrict__ comb_sum, const float* __restrict__ counts,
    const float* __restrict__ W_post1, const float* __restrict__ b_post1,
    const float* __restrict__ W_post2, const float* __restrict__ b_post2,
    const float* __restrict__ W_node1, const float* __restrict__ b_node1,
    float* __restrict__ nh_out, int N)
{
  __shared__ ushort_t sW1t[128 * W1S];
  __shared__ ushort_t tp[4][16 * THS];

  const int tid = threadIdx.x;
  for (int idx = tid; idx < 224 * 128; idx += 256) {
    const int k = idx >> 7;
    const int c = idx & 127;
    sW1t[c * W1S + k] = f2bfu(W_node1[idx]);
  }
  __syncthreads();

  const int lane = tid & 63;
  const int w = tid >> 6;
  const int l15 = lane & 15;
  const int q = lane >> 4;

  v8s bp1[4];
  #pragma unroll
  for (int nt = 0; nt < 4; ++nt)
    #pragma unroll
    for (int j = 0; j < 8; ++j)
      bp1[nt][j] = f2bfs(W_post1[(q * 8 + j) * 64 + nt * 16 + l15]);
  v8s bp2[2][2];
  #pragma unroll
  for (int kc = 0; kc < 2; ++kc)
    #pragma unroll
    for (int nt = 0; nt < 2; ++nt)
      #pragma unroll
      for (int j = 0; j < 8; ++j)
        bp2[kc][nt][j] = f2bfs(W_post2[(kc * 32 + q * 8 + j) * 32 + nt * 16 + l15]);
  float bb1[4];
  #pragma unroll
  for (int nt = 0; nt < 4; ++nt) bb1[nt] = b_post1[nt * 16 + l15];
  float bb2[2];
  #pragma unroll
  for (int nt = 0; nt < 2; ++nt) bb2[nt] = b_post2[nt * 16 + l15];
  float b1[8];
  #pragma unroll
  for (int nt = 0; nt < 8; ++nt) b1[nt] = b_node1[nt * 16 + l15];

  const int gw = blockIdx.x * 4 + w;
  const int nwv = gridDim.x * 4;
  const int ntiles = (N + 15) >> 4;

  for (int t = gw; t < ntiles; t += nwv) {
    const int row = t * 16 + l15;
    const int rowL = (row < N) ? row : (N - 1);

    const float inv = 1.0f / fmaxf(counts[rowL], 1.0f);
    const float4* cs = (const float4*)(comb_sum + (size_t)rowL * 96 + q * 24);
    float cf[24];
    #pragma unroll
    for (int b = 0; b < 6; ++b) {
      const float4 cv = cs[b];
      cf[b * 4 + 0] = cv.x; cf[b * 4 + 1] = cv.y;
      cf[b * 4 + 2] = cv.z; cf[b * 4 + 3] = cv.w;
    }
    v8s a1;
    #pragma unroll
    for (int j = 0; j < 8; ++j) {
      const float vx = cf[j * 3 + 0] * inv;
      const float vy = cf[j * 3 + 1] * inv;
      const float vz = cf[j * 3 + 2] * inv;
      a1[j] = f2bfs(vx * vx + vy * vy + vz * vz);
    }

    v4f p1[4];
    #pragma unroll
    for (int nt = 0; nt < 4; ++nt) {
      v4f a = {0.f, 0.f, 0.f, 0.f};
      p1[nt] = __builtin_amdgcn_mfma_f32_16x16x32_bf16(a1, bp1[nt], a, 0, 0, 0);
    }
    #pragma unroll
    for (int nt = 0; nt < 4; ++nt)
      #pragma unroll
      for (int r = 0; r < 4; ++r)
        tp[w][(q * 4 + r) * THS + nt * 16 + l15] =
            f2bfu(siluf(p1[nt][r] + bb1[nt]));
    __builtin_amdgcn_wave_barrier();

    v8s a2[2];
    a2[0] = *(const v8s*)&tp[w][l15 * THS + q * 8];
    a2[1] = *(const v8s*)&tp[w][l15 * THS + 32 + q * 8];

    v4f p2[2];
    #pragma unroll
    for (int nt = 0; nt < 2; ++nt) {
      v4f a = {0.f, 0.f, 0.f, 0.f};
      #pragma unroll
      for (int kc = 0; kc < 2; ++kc)
        a = __builtin_amdgcn_mfma_f32_16x16x32_bf16(a2[kc], bp2[kc][nt], a, 0, 0, 0);
      p2[nt] = a;
    }
    __builtin_amdgcn_wave_barrier();
    #pragma unroll
    for (int nt = 0; nt < 2; ++nt)
      #pragma unroll
      for (int r = 0; r < 4; ++r)
        tp[w][(q * 4 + r) * THS + nt * 16 + l15] =
            f2bfu(siluf(p2[nt][r] + bb2[nt]));
    __builtin_amdgcn_wave_barrier();

    v8s af[7];
    af[0] = *(const v8s*)(h_bf + (size_t)rowL * 64 + q * 8);
    af[1] = *(const v8s*)(h_bf + (size_t)rowL * 64 + 32 + q * 8);
    #pragma unroll
    for (int kc = 0; kc < 4; ++kc)
      af[2 + kc] = *(const v8s*)(hsem + (size_t)rowL * 128 + kc * 32 + q * 8);
    af[6] = *(const v8s*)&tp[w][l15 * THS + q * 8];

    v4f acc[8];
    #pragma unroll
    for (int nt = 0; nt < 8; ++nt) acc[nt] = (v4f){0.f, 0.f, 0.f, 0.f};
    #pragma unroll
    for (int kc = 0; kc < 7; ++kc) {
      #pragma unroll
      for (int nt = 0; nt < 8; ++nt) {
        const v8s bfrag =
            *(const v8s*)&sW1t[(nt * 16 + l15) * W1S + kc * 32 + q * 8];
        acc[nt] = __builtin_amdgcn_mfma_f32_16x16x32_bf16(af[kc], bfrag, acc[nt], 0, 0, 0);
      }
    }

    const int rowb = t * 16 + q * 4;
    #pragma unroll
    for (int nt = 0; nt < 8; ++nt) {
      #pragma unroll
      for (int r = 0; r < 4; ++r)
        if (rowb + r < N)
          nh_out[(size_t)(rowb + r) * 128 + nt * 16 + l15] =
              siluf(acc[nt][r] + b1[nt]);
    }
  }
}

// ---------------------------------------------------------------------------
// Pass C2: h_upd, gate, v_upd, x_upd -> d_out
// ---------------------------------------------------------------------------
__global__ __launch_bounds__(256) void node_pass_c2(
    const float* __restrict__ h, const float* __restrict__ x,
    const float* __restrict__ v, const float* __restrict__ nh,
    const float* __restrict__ dv_sum, const float* __restrict__ counts,
    const float* __restrict__ W_node2, const float* __restrict__ b_node2,
    const float* __restrict__ W_vel1, const float* __restrict__ b_vel1,
    const float* __restrict__ W_vel2,
    float* __restrict__ out, int N, int nIter)
{
  __shared__ float sW2[128 * 64];
  __shared__ float sWv1[64 * 32];
  __shared__ float sb2[64];
  __shared__ float sbv1[32];
  __shared__ float sWv2[32];
  __shared__ float snh[4][128];
  __shared__ float shu[4][64];

  const int tid = threadIdx.x;
  for (int k = tid; k < 128 * 64; k += 256) sW2[k] = W_node2[k];
  for (int k = tid; k < 64 * 32; k += 256) sWv1[k] = W_vel1[k];
  for (int k = tid; k < 64; k += 256) sb2[k] = b_node2[k];
  for (int k = tid; k < 32; k += 256) sbv1[k] = b_vel1[k];
  for (int k = tid; k < 32; k += 256) sWv2[k] = W_vel2[k];
  __syncthreads();

  const int lane = tid & 63;
  const int w = tid >> 6;
  const int gw = blockIdx.x * 4 + w;
  const int stride = gridDim.x * 4;

  for (int it = 0; it < nIter; ++it) {
    const int n = gw + it * stride;
    const bool active = (n < N);
    if (active) {
      snh[w][lane] = nh[(size_t)n * 128 + lane];
      snh[w][64 + lane] = nh[(size_t)n * 128 + 64 + lane];
    }
    __syncthreads();
    if (active) {
      float acc = sb2[lane];
      #pragma unroll 8
      for (int k = 0; k < 128; ++k) acc += snh[w][k] * sW2[k * 64 + lane];
      const float hu = h[n * DA + lane] + siluf(acc);
      out[(size_t)n * DA + lane] = hu;
      shu[w][lane] = hu;
    }
    __syncthreads();
    if (active) {
      float p = 0.f;
      if (lane < 32) {
        float acc = sbv1[lane];
        #pragma unroll 8
        for (int k = 0; k < 64; ++k) acc += shu[w][k] * sWv1[k * 32 + lane];
        p = siluf(acc) * sWv2[lane];
      }
      p += __shfl_xor(p, 16);
      p += __shfl_xor(p, 8);
      p += __shfl_xor(p, 4);
      p += __shfl_xor(p, 2);
      p += __shfl_xor(p, 1);
      const float s = __shfl(p, 0);
      const float gate = 2.0f / (1.0f + __expf(-s));
      if (lane < 3) {
        const float cnt = fmaxf(counts[n], 1.0f);
        const float dvx = dv_sum[n * 3 + lane] / cnt;
        const float vu = gate * v[n * 3 + lane] + dvx;
        out[(size_t)N * 64 + n * 3 + lane] = x[n * 3 + lane] + vu;
        out[(size_t)N * 64 + (size_t)N * 3 + n * 3 + lane] = vu;
      }
    }
    __syncthreads();
  }
}

// ---------------------------------------------------------------------------
extern "C" void kernel_launch(void* const* d_in, const int* in_sizes, int n_in,
                              void* d_out, int out_size, void* d_ws, size_t ws_size,
                              hipStream_t stream) {
  const float* h   = (const float*)d_in[0];
  const float* x   = (const float*)d_in[1];
  const float* v   = (const float*)d_in[2];
  const int* idx_i = (const int*)d_in[3];
  const int* idx_j = (const int*)d_in[4];
  const float* W_edge_in  = (const float*)d_in[5];
  const float* b_edge_in  = (const float*)d_in[6];
  const float* W_edge_h   = (const float*)d_in[7];
  const float* b_edge_h   = (const float*)d_in[8];
  const float* W_edge_out = (const float*)d_in[9];
  const float* b_edge_out = (const float*)d_in[10];
  const float* W_att      = (const float*)d_in[11];
  const float* b_att      = (const float*)d_in[12];
  const float* W_x_mix    = (const float*)d_in[13];
  const float* W_node1    = (const float*)d_in[14];
  const float* b_node1    = (const float*)d_in[15];
  const float* W_node2    = (const float*)d_in[16];
  const float* b_node2    = (const float*)d_in[17];
  const float* W_post1    = (const float*)d_in[18];
  const float* b_post1    = (const float*)d_in[19];
  const float* W_post2    = (const float*)d_in[20];
  const float* b_post2    = (const float*)d_in[21];
  const float* W_vel1     = (const float*)d_in[22];
  const float* b_vel1     = (const float*)d_in[23];
  const float* W_vel2     = (const float*)d_in[24];
  const float* w_v_mix    = (const float*)d_in[25];

  const int E = in_sizes[3];
  const int N = in_sizes[0] / DA;

  float* ws = (float*)d_ws;
  size_t off = 0;
  float* denom    = ws + off; off += (size_t)N * 4;     // zeroed
  int*   deg      = (int*)(ws + off); off += (size_t)N; // zeroed
  const size_t zeroBytes = off * sizeof(float);
  float* counts   = ws + off; off += (size_t)N;
  int*   rowstart = (int*)(ws + off); off += (size_t)N + 4;
  int*   cursor   = (int*)(ws + off); off += (size_t)N;
  int*   tsum     = (int*)(ws + off); off += (size_t)SCAN_T;
  int*   perm     = (int*)(ws + off); off += (size_t)E;
  float* pE       = ws + off; off += (size_t)E;
  float* expl     = ws + off; off += (size_t)E * 4;
  float* dirb     = ws + off; off += (size_t)E * 3;
  float* hsemR    = ws + off; off += (size_t)N * 64;    // hsem bf16 [N,128]
  float* comb_sum = ws + off; off += (size_t)N * 96;
  float* dv_sum   = ws + off; off += (size_t)N * 4;
  float* hbfR     = ws + off; off += (size_t)N * 32;    // h_bf bf16 [N,64]
  float* fltR     = ws + off; off += (size_t)E * 16;    // Filt / mixE / nh
  float* hebR     = ws + off; off += (size_t)E * 16;    // heb bf16 [E,32]

  ushort_t* h_bf = (ushort_t*)hbfR;
  ushort_t* hsem = (ushort_t*)hsemR;
  ushort_t* Filt = (ushort_t*)fltR;
  ushort_t* heb  = (ushort_t*)hebR;
  ushort_t* mixE = (ushort_t*)fltR;  // aliases Filt (dead after edge_f2)
  float* nh = fltR;                  // aliases mixE (dead after node_reduce)

  hipMemsetAsync(d_ws, 0, zeroBytes, stream);

  {
    const int n4 = (N * 64) / 4;
    cast_h<<<(n4 + 255) / 256, 256, 0, stream>>>(h, h_bf, n4);
  }
  edge_f1<<<1024, 256, 0, stream>>>(h_bf, x, idx_i, idx_j, W_edge_in,
                                    b_edge_in, Filt, dirb, deg, E);
  {
    const int C = (N + SCAN_T - 1) / SCAN_T;
    deg_tsum<<<SCAN_B, 256, 0, stream>>>(deg, tsum, N, C);
    scan_tsum<<<1, 256, 0, stream>>>(tsum);
    write_csr<<<SCAN_B, 256, 0, stream>>>(deg, tsum, rowstart, cursor, counts, N, C);
  }
  bucket_edges<<<512, 256, 0, stream>>>(idx_i, cursor, perm, E);
  edge_f2<<<1024, 256, 0, stream>>>(h_bf, idx_i, idx_j, Filt, W_edge_h,
                                    b_edge_h, W_edge_out, b_edge_out,
                                    W_att, b_att, heb, expl, denom, E);
  mix_kernel<<<1024, 256, 0, stream>>>(heb, idx_i, expl, denom, W_x_mix,
                                       w_v_mix, mixE, pE, E);
  node_reduce<<<2048, 256, 0, stream>>>(rowstart, perm, heb, mixE, expl, denom,
                                        dirb, pE, hsem, comb_sum, dv_sum, N);
  node_c1_mfma<<<512, 256, 0, stream>>>(
      h_bf, hsem, comb_sum, counts, W_post1, b_post1, W_post2, b_post2,
      W_node1, b_node1, nh, N);
  {
    const int grid = 1024;
    const int nIter = (N + grid * 4 - 1) / (grid * 4);
    node_pass_c2<<<grid, 256, 0, stream>>>(
        h, x, v, nh, dv_sum, counts, W_node2, b_node2, W_vel1, b_vel1, W_vel2,
        (float*)d_out, N, nIter);
  }
}

// Round 8
// 495.273 us; speedup vs baseline: 5.5196x; 1.1923x over previous
//
#include <hip/hip_runtime.h>
#include <math.h>

// Problem dims (fixed by reference)
#define DA 64    // A
#define NODEIN_DIM 224 // A + H*EB + S

#define EPSC 1e-8f

typedef short v8s __attribute__((ext_vector_type(8)));
typedef float v4f __attribute__((ext_vector_type(4)));
typedef unsigned short ushort_t;

__device__ __forceinline__ float siluf(float v) { return v / (1.0f + __expf(-v)); }

__device__ __forceinline__ void atomAddF(float* p, float v) {
#if defined(__HIP_DEVICE_COMPILE__)
  unsafeAtomicAdd(p, v);
#else
  atomicAdd(p, v);
#endif
}

__device__ __forceinline__ unsigned short f2bfu(float f) {
  union { float f; unsigned u; } v; v.f = f;
  unsigned r = v.u + 0x7fffu + ((v.u >> 16) & 1u);
  return (unsigned short)(r >> 16);
}
__device__ __forceinline__ short f2bfs(float f) { return (short)f2bfu(f); }
__device__ __forceinline__ float bf2f(ushort_t s) {
  union { unsigned u; float f; } v; v.u = ((unsigned)s) << 16; return v.f;
}

#define MU0 0.60653065971263342f
#define DMU ((1.0f - 0.60653065971263342f) / 19.0f)
#define BETA ((float)(1.0 / (0.039346934028736658 * 0.039346934028736658)))

// ---------------------------------------------------------------------------
// cast_h: h fp32 -> bf16 copy
// ---------------------------------------------------------------------------
__global__ __launch_bounds__(256) void cast_h(
    const float* __restrict__ hsrc, ushort_t* __restrict__ hb, int n4)
{
  const int i = blockIdx.x * blockDim.x + threadIdx.x;
  if (i < n4) {
    const float4 fv = ((const float4*)hsrc)[i];
    ushort4 o;
    o.x = f2bfu(fv.x); o.y = f2bfu(fv.y); o.z = f2bfu(fv.z); o.w = f2bfu(fv.w);
    ((ushort4*)hb)[i] = o;
  }
}

// ---------------------------------------------------------------------------
// F1: gather + geometry + M1 ([E,128] x W_in[128,20]) + RBF epilogue.
// ---------------------------------------------------------------------------
__global__ __launch_bounds__(256) void edge_f1(
    const ushort_t* __restrict__ h_bf, const float* __restrict__ x,
    const int* __restrict__ idx_i, const int* __restrict__ idx_j,
    const float* __restrict__ W_in, const float* __restrict__ b_in,
    ushort_t* __restrict__ Filt, float* __restrict__ dirb,
    int* __restrict__ deg, int E)
{
  const int tid = blockIdx.x * blockDim.x + threadIdx.x;
  const int wid = tid >> 6;
  const int lane = threadIdx.x & 63;
  const int nw = (gridDim.x * blockDim.x) >> 6;
  const int l15 = lane & 15;
  const int q = lane >> 4;

  v8s bfr[4][2];
  #pragma unroll
  for (int kc = 0; kc < 4; ++kc)
    #pragma unroll
    for (int nt = 0; nt < 2; ++nt)
      #pragma unroll
      for (int j = 0; j < 8; ++j) {
        const int k = kc * 32 + q * 8 + j;
        const int col = nt * 16 + l15;
        bfr[kc][nt][j] = (col < 20) ? f2bfs(W_in[k * 20 + col]) : (short)0;
      }
  float bin[2], mu[2];
  #pragma unroll
  for (int nt = 0; nt < 2; ++nt) {
    const int col = nt * 16 + l15;
    bin[nt] = (col < 20) ? b_in[col] : 0.0f;
    mu[nt] = MU0 + (float)col * DMU;
  }

  const int ntiles = (E + 15) >> 4;
  for (int t = wid; t < ntiles; t += nw) {
    const int row = t * 16 + l15;
    const int rowL = (row < E) ? row : (E - 1);
    const int ii = idx_i[rowL];
    const int jj = idx_j[rowL];

    v8s afr[4];
    afr[0] = *(const v8s*)(h_bf + (size_t)ii * 64 + q * 8);
    afr[1] = *(const v8s*)(h_bf + (size_t)ii * 64 + 32 + q * 8);
    afr[2] = *(const v8s*)(h_bf + (size_t)jj * 64 + q * 8);
    afr[3] = *(const v8s*)(h_bf + (size_t)jj * 64 + 32 + q * 8);

    float dval = 0.0f;
    if (lane < 16 && row < E) {
      const float rx = x[jj * 3 + 0] - x[ii * 3 + 0];
      const float ry = x[jj * 3 + 1] - x[ii * 3 + 1];
      const float rz = x[jj * 3 + 2] - x[ii * 3 + 2];
      const float d = sqrtf(rx * rx + ry * ry + rz * rz + EPSC);
      dval = d;
      const float inv = 1.0f / (d + EPSC);
      dirb[row * 3 + 0] = rx * inv;
      dirb[row * 3 + 1] = ry * inv;
      dirb[row * 3 + 2] = rz * inv;
      atomicAdd(&deg[ii], 1);
    }

    v4f acc[2];
    #pragma unroll
    for (int nt = 0; nt < 2; ++nt) {
      v4f a = {0.f, 0.f, 0.f, 0.f};
      #pragma unroll
      for (int kc = 0; kc < 4; ++kc)
        a = __builtin_amdgcn_mfma_f32_16x16x32_bf16(afr[kc], bfr[kc][nt], a, 0, 0, 0);
      acc[nt] = a;
    }

    const int rowb = t * 16 + q * 4;
    float dr[4], edr[4];
    #pragma unroll
    for (int r = 0; r < 4; ++r) {
      dr[r] = __shfl(dval, q * 4 + r);
      edr[r] = __expf(-dr[r]);
    }
    #pragma unroll
    for (int nt = 0; nt < 2; ++nt) {
      const int col = nt * 16 + l15;
      #pragma unroll
      for (int r = 0; r < 4; ++r) {
        ushort_t ov;
        if (col < 20) {
          const float tt = edr[r] - mu[nt];
          ov = f2bfu((acc[nt][r] + bin[nt]) * __expf(-BETA * tt * tt));
        } else if (col == 20) {
          ov = f2bfu(dr[r]);
        } else {
          ov = 0;
        }
        if (rowb + r < E) Filt[(size_t)(rowb + r) * 32 + col] = ov;
      }
    }
  }
}

// ---------------------------------------------------------------------------
// F2: M2 ([E,160] x W_h, silu) + LDS transpose + M3 -> heb[E,32] bf16
//   + att epilogue via MFMA (W_att padded to 16 cols, 1 mfma/tile).
// 2-deep software pipeline on the random h_bf/Filt gathers.
// ---------------------------------------------------------------------------
#define THS 72
__global__ __launch_bounds__(256) void edge_f2(
    const ushort_t* __restrict__ h_bf,
    const int* __restrict__ idx_i, const int* __restrict__ idx_j,
    const ushort_t* __restrict__ Filt,
    const float* __restrict__ W_h, const float* __restrict__ b_h,
    const float* __restrict__ W_out, const float* __restrict__ b_out,
    const float* __restrict__ W_att, const float* __restrict__ b_att,
    ushort_t* __restrict__ heb, float* __restrict__ expl,
    float* __restrict__ denom, int E)
{
  __shared__ ushort_t sB2[20 * 64 * 8];   // 20 KB: W_h fragments (kc,nt)
  __shared__ ushort_t sB3[4 * 64 * 8];    // 4 KB: W_out fragments
  __shared__ ushort_t tH[4][16 * THS];    // 9 KB: per-wave transpose tile

  const int tid = threadIdx.x;
  for (int idx = tid; idx < 20 * 64 * 8; idx += 256) {
    const int j = idx & 7;
    const int ln = (idx >> 3) & 63;
    const int f = idx >> 9;               // 0..19 = kc*4+nt
    const int k = (f >> 2) * 32 + (ln >> 4) * 8 + j;
    const int col = (f & 3) * 16 + (ln & 15);
    sB2[idx] = (k < 149) ? f2bfu(W_h[k * 64 + col]) : (ushort_t)0;
  }
  for (int idx = tid; idx < 4 * 64 * 8; idx += 256) {
    const int j = idx & 7;
    const int ln = (idx >> 3) & 63;
    const int f = idx >> 9;               // 0..3 = kc*2+nt
    const int k = (f >> 1) * 32 + (ln >> 4) * 8 + j;
    const int col = (f & 1) * 16 + (ln & 15);
    sB3[idx] = f2bfu(W_out[k * 32 + col]);
  }
  __syncthreads();

  const int gtid = blockIdx.x * blockDim.x + tid;
  const int wid = gtid >> 6;
  const int lane = tid & 63;
  const int w = tid >> 6;
  const int nw = (gridDim.x * blockDim.x) >> 6;
  const int l15 = lane & 15;
  const int q = lane >> 4;

  const ushort_t* b2l = sB2 + lane * 8;
  const ushort_t* b3l = sB3 + lane * 8;

  float bias2[4];
  #pragma unroll
  for (int nt = 0; nt < 4; ++nt) bias2[nt] = b_h[nt * 16 + l15];
  float bias3[2];
  #pragma unroll
  for (int nt = 0; nt < 2; ++nt) bias3[nt] = b_out[nt * 16 + l15];

  // W_att fragment: [32,4] padded to 16 cols (cols >= 4 zero)
  v8s battf;
  #pragma unroll
  for (int j = 0; j < 8; ++j)
    battf[j] = (l15 < 4) ? f2bfs(W_att[(q * 8 + j) * 4 + l15]) : (short)0;
  const float bav = (l15 < 4) ? b_att[l15] : 0.0f;

  const int ntiles = (E + 15) >> 4;

  // prime the pipeline
  int iiC = 0;
  v8s afr[5];
  if (wid < ntiles) {
    const int row0 = wid * 16 + l15;
    const int rowL0 = (row0 < E) ? row0 : (E - 1);
    iiC = idx_i[rowL0];
    const int jj0 = idx_j[rowL0];
    afr[0] = *(const v8s*)(h_bf + (size_t)iiC * 64 + q * 8);
    afr[1] = *(const v8s*)(h_bf + (size_t)iiC * 64 + 32 + q * 8);
    afr[2] = *(const v8s*)(h_bf + (size_t)jj0 * 64 + q * 8);
    afr[3] = *(const v8s*)(h_bf + (size_t)jj0 * 64 + 32 + q * 8);
    afr[4] = *(const v8s*)(Filt + (size_t)rowL0 * 32 + q * 8);
  }

  for (int t = wid; t < ntiles; t += nw) {
    // prefetch next tile's gathers (overlaps with this tile's compute)
    const int tn = t + nw;
    int iiN = 0;
    v8s nfr[5];
    if (tn < ntiles) {
      const int rowN = tn * 16 + l15;
      const int rowLN = (rowN < E) ? rowN : (E - 1);
      iiN = idx_i[rowLN];
      const int jjN = idx_j[rowLN];
      nfr[0] = *(const v8s*)(h_bf + (size_t)iiN * 64 + q * 8);
      nfr[1] = *(const v8s*)(h_bf + (size_t)iiN * 64 + 32 + q * 8);
      nfr[2] = *(const v8s*)(h_bf + (size_t)jjN * 64 + q * 8);
      nfr[3] = *(const v8s*)(h_bf + (size_t)jjN * 64 + 32 + q * 8);
      nfr[4] = *(const v8s*)(Filt + (size_t)rowLN * 32 + q * 8);
    }

    // M2
    v4f acc2[4];
    #pragma unroll
    for (int nt = 0; nt < 4; ++nt) {
      v4f a = {0.f, 0.f, 0.f, 0.f};
      #pragma unroll
      for (int kc = 0; kc < 5; ++kc) {
        const v8s bfrag = *(const v8s*)(b2l + (kc * 4 + nt) * 512);
        a = __builtin_amdgcn_mfma_f32_16x16x32_bf16(afr[kc], bfrag, a, 0, 0, 0);
      }
      acc2[nt] = a;
    }

    #pragma unroll
    for (int nt = 0; nt < 4; ++nt) {
      #pragma unroll
      for (int r = 0; r < 4; ++r)
        tH[w][(q * 4 + r) * THS + nt * 16 + l15] =
            f2bfu(siluf(acc2[nt][r] + bias2[nt]));
    }
    __builtin_amdgcn_wave_barrier();

    v8s af3[2];
    af3[0] = *(const v8s*)&tH[w][l15 * THS + q * 8];
    af3[1] = *(const v8s*)&tH[w][l15 * THS + 32 + q * 8];

    v4f acc3[2];
    #pragma unroll
    for (int nt = 0; nt < 2; ++nt) {
      v4f a = {0.f, 0.f, 0.f, 0.f};
      #pragma unroll
      for (int kc = 0; kc < 2; ++kc) {
        const v8s bfrag = *(const v8s*)(b3l + (kc * 2 + nt) * 512);
        a = __builtin_amdgcn_mfma_f32_16x16x32_bf16(af3[kc], bfrag, a, 0, 0, 0);
      }
      acc3[nt] = a;
    }
    __builtin_amdgcn_wave_barrier();  // tH reuse below

    const int rowb = t * 16 + q * 4;
    #pragma unroll
    for (int nt = 0; nt < 2; ++nt) {
      const int col = nt * 16 + l15;
      #pragma unroll
      for (int r = 0; r < 4; ++r) {
        const ushort_t hv = f2bfu(acc3[nt][r] + bias3[nt]);
        tH[w][(q * 4 + r) * THS + col] = hv;
        if (rowb + r < E) heb[(size_t)(rowb + r) * 32 + col] = hv;
      }
    }
    __builtin_amdgcn_wave_barrier();

    // att via MFMA: he rows (A-layout from tH) x W_att fragment
    const v8s afA = *(const v8s*)&tH[w][l15 * THS + q * 8];
    v4f az = {0.f, 0.f, 0.f, 0.f};
    const v4f aacc = __builtin_amdgcn_mfma_f32_16x16x32_bf16(afA, battf, az, 0, 0, 0);

    int ii_r[4];
    #pragma unroll
    for (int r = 0; r < 4; ++r) ii_r[r] = __shfl(iiC, q * 4 + r);

    if (l15 < 4) {
      #pragma unroll
      for (int r = 0; r < 4; ++r) {
        if (rowb + r < E) {
          const float la = aacc[r] + bav;
          const float l = (la > 0.f) ? la : 2.0f * (__expf(0.5f * la) - 1.0f);
          const float ev = __expf(l);
          expl[(size_t)(rowb + r) * 4 + l15] = ev;
          atomAddF(&denom[ii_r[r] * 4 + l15], ev);
        }
      }
    }
    __builtin_amdgcn_wave_barrier();

    iiC = iiN;
    afr[0] = nfr[0]; afr[1] = nfr[1]; afr[2] = nfr[2];
    afr[3] = nfr[3]; afr[4] = nfr[4];
  }
}

// ---------------------------------------------------------------------------
// Parallel CSR scan
// ---------------------------------------------------------------------------
#define SCAN_B 64
#define SCAN_T (SCAN_B * 256)

__global__ __launch_bounds__(256) void deg_tsum(
    const int* __restrict__ deg, int* __restrict__ tsum, int N, int C)
{
  const int g = blockIdx.x * blockDim.x + threadIdx.x;
  const int lo = g * C;
  const int hi = (lo + C < N) ? (lo + C) : N;
  int s = 0;
  for (int i = lo; i < hi; ++i) s += deg[i];
  tsum[g] = s;
}

__global__ __launch_bounds__(256) void scan_tsum(int* __restrict__ tsum)
{
  __shared__ int ps[256];
  const int t = threadIdx.x;
  const int per = SCAN_T / 256;
  const int lo = t * per;
  int s = 0;
  for (int i = 0; i < per; ++i) s += tsum[lo + i];
  ps[t] = s;
  __syncthreads();
  if (t == 0) {
    int a = 0;
    for (int i = 0; i < 256; ++i) { const int v = ps[i]; ps[i] = a; a += v; }
  }
  __syncthreads();
  int acc = ps[t];
  for (int i = 0; i < per; ++i) {
    const int v = tsum[lo + i];
    tsum[lo + i] = acc;
    acc += v;
  }
}

__global__ __launch_bounds__(256) void write_csr(
    const int* __restrict__ deg, const int* __restrict__ tpre,
    int* __restrict__ rowstart, int* __restrict__ cursor,
    float* __restrict__ counts, int N, int C)
{
  const int g = blockIdx.x * blockDim.x + threadIdx.x;
  const int lo = g * C;
  const int hi = (lo + C < N) ? (lo + C) : N;
  int acc = tpre[g];
  for (int i = lo; i < hi; ++i) {
    const int d = deg[i];
    rowstart[i] = acc;
    cursor[i] = acc;
    counts[i] = (float)d;
    acc += d;
  }
  if (hi == N) rowstart[N] = acc;
}

// ---------------------------------------------------------------------------
// bucket_edges: perm[pos] = e, pos from cursor atomics
// ---------------------------------------------------------------------------
__global__ __launch_bounds__(256) void bucket_edges(
    const int* __restrict__ idx_i, int* __restrict__ cursor,
    int* __restrict__ perm, int E)
{
  const int stride = gridDim.x * blockDim.x;
  for (int e = blockIdx.x * blockDim.x + threadIdx.x; e < E; e += stride) {
    const int pos = atomicAdd(&cursor[idx_i[e]], 1);
    perm[pos] = e;
  }
}

// ---------------------------------------------------------------------------
// mix_kernel: per-edge A = att (x) he  ->  MFMA [E,128] x W_x_mix[128,32]
// ---------------------------------------------------------------------------
__global__ __launch_bounds__(256) void mix_kernel(
    const ushort_t* __restrict__ heb, const int* __restrict__ idx_i,
    const float* __restrict__ expl, const float* __restrict__ denom,
    const float* __restrict__ W_xmix, const float* __restrict__ w_vmix,
    ushort_t* __restrict__ mixE, float* __restrict__ pE, int E)
{
  const int tid = blockIdx.x * blockDim.x + threadIdx.x;
  const int wid = tid >> 6;
  const int lane = threadIdx.x & 63;
  const int nw = (gridDim.x * blockDim.x) >> 6;
  const int l15 = lane & 15;
  const int q = lane >> 4;

  v8s bfr[4][2];
  #pragma unroll
  for (int kc = 0; kc < 4; ++kc)
    #pragma unroll
    for (int nt = 0; nt < 2; ++nt)
      #pragma unroll
      for (int j = 0; j < 8; ++j) {
        const int k = kc * 32 + q * 8 + j;
        const int col = nt * 16 + l15;
        bfr[kc][nt][j] = f2bfs(W_xmix[k * 32 + col]);
      }
  float wv[2];
  wv[0] = w_vmix[l15];
  wv[1] = w_vmix[16 + l15];

  const int ntiles = (E + 15) >> 4;
  for (int t = wid; t < ntiles; t += nw) {
    const int row = t * 16 + l15;
    const int rowL = (row < E) ? row : (E - 1);
    const int ii = idx_i[rowL];
    float att[4];
    #pragma unroll
    for (int hh = 0; hh < 4; ++hh)
      att[hh] = expl[(size_t)rowL * 4 + hh] / (denom[ii * 4 + hh] + EPSC);

    const v8s hech = *(const v8s*)(heb + (size_t)rowL * 32 + q * 8);
    float hef[8];
    #pragma unroll
    for (int j = 0; j < 8; ++j) hef[j] = bf2f((ushort_t)hech[j]);

    v8s afr[4];
    #pragma unroll
    for (int kc = 0; kc < 4; ++kc)
      #pragma unroll
      for (int j = 0; j < 8; ++j)
        afr[kc][j] = f2bfs(att[kc] * hef[j]);

    v4f acc[2];
    #pragma unroll
    for (int nt = 0; nt < 2; ++nt) {
      v4f a = {0.f, 0.f, 0.f, 0.f};
      #pragma unroll
      for (int kc = 0; kc < 4; ++kc)
        a = __builtin_amdgcn_mfma_f32_16x16x32_bf16(afr[kc], bfr[kc][nt], a, 0, 0, 0);
      acc[nt] = a;
    }

    const int rowb = t * 16 + q * 4;
    float pr[4];
    #pragma unroll
    for (int r = 0; r < 4; ++r) {
      const float m0 = tanhf(acc[0][r]);
      const float m1 = tanhf(acc[1][r]);
      if (rowb + r < E) {
        mixE[(size_t)(rowb + r) * 32 + l15] = f2bfu(m0);
        mixE[(size_t)(rowb + r) * 32 + 16 + l15] = f2bfu(m1);
      }
      pr[r] = m0 * wv[0] + m1 * wv[1];
    }
    #pragma unroll
    for (int r = 0; r < 4; ++r) {
      pr[r] += __shfl_xor(pr[r], 1);
      pr[r] += __shfl_xor(pr[r], 2);
      pr[r] += __shfl_xor(pr[r], 4);
      pr[r] += __shfl_xor(pr[r], 8);
      if (l15 == 0 && rowb + r < E) pE[rowb + r] = pr[r];
    }
  }
}

// ---------------------------------------------------------------------------
// node_reduce: wave per node, CSR gather-reduce.
// ---------------------------------------------------------------------------
__global__ __launch_bounds__(256) void node_reduce(
    const int* __restrict__ rowstart, const int* __restrict__ perm,
    const ushort_t* __restrict__ heb, const ushort_t* __restrict__ mixE,
    const float* __restrict__ expl, const float* __restrict__ denom,
    const float* __restrict__ dirb, const float* __restrict__ pE,
    ushort_t* __restrict__ hsem, float* __restrict__ comb_sum,
    float* __restrict__ dv_sum, int N)
{
  const int tid = blockIdx.x * blockDim.x + threadIdx.x;
  const int wid = tid >> 6;
  const int lane = threadIdx.x & 63;
  const int nw = (gridDim.x * blockDim.x) >> 6;
  const int hh = lane >> 5;
  const int eb = lane & 31;

  for (int n = wid; n < N; n += nw) {
    const int s = rowstart[n];
    const int epd = rowstart[n + 1];
    float semA = 0.f, semB = 0.f;
    float cx = 0.f, cy = 0.f, cz = 0.f;
    float dvx = 0.f, dvy = 0.f, dvz = 0.f;
    for (int k = s; k < epd; ++k) {
      const int e = perm[k];
      const float he = bf2f(heb[(size_t)e * 32 + eb]);
      const float ea = expl[(size_t)e * 4 + hh];
      const float ec = expl[(size_t)e * 4 + 2 + hh];
      semA += ea * he;
      semB += ec * he;
      const float dx = dirb[e * 3 + 0];
      const float dy = dirb[e * 3 + 1];
      const float dz = dirb[e * 3 + 2];
      if (lane < 32) {
        const float m = bf2f(mixE[(size_t)e * 32 + lane]);
        cx += dx * m; cy += dy * m; cz += dz * m;
      }
      if (lane == 0) {
        const float pe = pE[e];
        dvx += dx * pe; dvy += dy * pe; dvz += dz * pe;
      }
    }
    const float dA = denom[n * 4 + hh] + EPSC;
    const float dB = denom[n * 4 + 2 + hh] + EPSC;
    hsem[(size_t)n * 128 + lane] = f2bfu(semA / dA);
    hsem[(size_t)n * 128 + 64 + lane] = f2bfu(semB / dB);
    if (lane < 32) {
      comb_sum[(size_t)n * 96 + lane * 3 + 0] = cx;
      comb_sum[(size_t)n * 96 + lane * 3 + 1] = cy;
      comb_sum[(size_t)n * 96 + lane * 3 + 2] = cz;
    }
    if (lane == 0) {
      dv_sum[n * 3 + 0] = dvx;
      dv_sum[n * 3 + 1] = dvy;
      dv_sum[n * 3 + 2] = dvz;
    }
  }
}

// ---------------------------------------------------------------------------
// C1 (MFMA): spatial MLP (post1/post2) + node1, wave per 16-node tile.
// ---------------------------------------------------------------------------
#define W1S 232
__global__ __launch_bounds__(256) void node_c1_mfma(
    const ushort_t* __restrict__ h_bf, const ushort_t* __restrict__ hsem,
    const float* __restrict__ comb_sum, const float* __restrict__ counts,
    const float* __restrict__ W_post1, const float* __restrict__ b_post1,
    const float* __restrict__ W_post2, const float* __restrict__ b_post2,
    const float* __restrict__ W_node1, const float* __restrict__ b_node1,
    float* __restrict__ nh_out, int N)
{
  __shared__ ushort_t sW1t[128 * W1S];
  __shared__ ushort_t tp[4][16 * THS];

  const int tid = threadIdx.x;
  for (int idx = tid; idx < 224 * 128; idx += 256) {
    const int k = idx >> 7;
    const int c = idx & 127;
    sW1t[c * W1S + k] = f2bfu(W_node1[idx]);
  }
  __syncthreads();

  const int lane = tid & 63;
  const int w = tid >> 6;
  const int l15 = lane & 15;
  const int q = lane >> 4;

  v8s bp1[4];
  #pragma unroll
  for (int nt = 0; nt < 4; ++nt)
    #pragma unroll
    for (int j = 0; j < 8; ++j)
      bp1[nt][j] = f2bfs(W_post1[(q * 8 + j) * 64 + nt * 16 + l15]);
  v8s bp2[2][2];
  #pragma unroll
  for (int kc = 0; kc < 2; ++kc)
    #pragma unroll
    for (int nt = 0; nt < 2; ++nt)
      #pragma unroll
      for (int j = 0; j < 8; ++j)
        bp2[kc][nt][j] = f2bfs(W_post2[(kc * 32 + q * 8 + j) * 32 + nt * 16 + l15]);
  float bb1[4];
  #pragma unroll
  for (int nt = 0; nt < 4; ++nt) bb1[nt] = b_post1[nt * 16 + l15];
  float bb2[2];
  #pragma unroll
  for (int nt = 0; nt < 2; ++nt) bb2[nt] = b_post2[nt * 16 + l15];
  float b1[8];
  #pragma unroll
  for (int nt = 0; nt < 8; ++nt) b1[nt] = b_node1[nt * 16 + l15];

  const int gw = blockIdx.x * 4 + w;
  const int nwv = gridDim.x * 4;
  const int ntiles = (N + 15) >> 4;

  for (int t = gw; t < ntiles; t += nwv) {
    const int row = t * 16 + l15;
    const int rowL = (row < N) ? row : (N - 1);

    const float inv = 1.0f / fmaxf(counts[rowL], 1.0f);
    const float4* cs = (const float4*)(comb_sum + (size_t)rowL * 96 + q * 24);
    float cf[24];
    #pragma unroll
    for (int b = 0; b < 6; ++b) {
      const float4 cv = cs[b];
      cf[b * 4 + 0] = cv.x; cf[b * 4 + 1] = cv.y;
      cf[b * 4 + 2] = cv.z; cf[b * 4 + 3] = cv.w;
    }
    v8s a1;
    #pragma unroll
    for (int j = 0; j < 8; ++j) {
      const float vx = cf[j * 3 + 0] * inv;
      const float vy = cf[j * 3 + 1] * inv;
      const float vz = cf[j * 3 + 2] * inv;
      a1[j] = f2bfs(vx * vx + vy * vy + vz * vz);
    }

    v4f p1[4];
    #pragma unroll
    for (int nt = 0; nt < 4; ++nt) {
      v4f a = {0.f, 0.f, 0.f, 0.f};
      p1[nt] = __builtin_amdgcn_mfma_f32_16x16x32_bf16(a1, bp1[nt], a, 0, 0, 0);
    }
    #pragma unroll
    for (int nt = 0; nt < 4; ++nt)
      #pragma unroll
      for (int r = 0; r < 4; ++r)
        tp[w][(q * 4 + r) * THS + nt * 16 + l15] =
            f2bfu(siluf(p1[nt][r] + bb1[nt]));
    __builtin_amdgcn_wave_barrier();

    v8s a2[2];
    a2[0] = *(const v8s*)&tp[w][l15 * THS + q * 8];
    a2[1] = *(const v8s*)&tp[w][l15 * THS + 32 + q * 8];

    v4f p2[2];
    #pragma unroll
    for (int nt = 0; nt < 2; ++nt) {
      v4f a = {0.f, 0.f, 0.f, 0.f};
      #pragma unroll
      for (int kc = 0; kc < 2; ++kc)
        a = __builtin_amdgcn_mfma_f32_16x16x32_bf16(a2[kc], bp2[kc][nt], a, 0, 0, 0);
      p2[nt] = a;
    }
    __builtin_amdgcn_wave_barrier();
    #pragma unroll
    for (int nt = 0; nt < 2; ++nt)
      #pragma unroll
      for (int r = 0; r < 4; ++r)
        tp[w][(q * 4 + r) * THS + nt * 16 + l15] =
            f2bfu(siluf(p2[nt][r] + bb2[nt]));
    __builtin_amdgcn_wave_barrier();

    v8s af[7];
    af[0] = *(const v8s*)(h_bf + (size_t)rowL * 64 + q * 8);
    af[1] = *(const v8s*)(h_bf + (size_t)rowL * 64 + 32 + q * 8);
    #pragma unroll
    for (int kc = 0; kc < 4; ++kc)
      af[2 + kc] = *(const v8s*)(hsem + (size_t)rowL * 128 + kc * 32 + q * 8);
    af[6] = *(const v8s*)&tp[w][l15 * THS + q * 8];

    v4f acc[8];
    #pragma unroll
    for (int nt = 0; nt < 8; ++nt) acc[nt] = (v4f){0.f, 0.f, 0.f, 0.f};
    #pragma unroll
    for (int kc = 0; kc < 7; ++kc) {
      #pragma unroll
      for (int nt = 0; nt < 8; ++nt) {
        const v8s bfrag =
            *(const v8s*)&sW1t[(nt * 16 + l15) * W1S + kc * 32 + q * 8];
        acc[nt] = __builtin_amdgcn_mfma_f32_16x16x32_bf16(af[kc], bfrag, acc[nt], 0, 0, 0);
      }
    }

    const int rowb = t * 16 + q * 4;
    #pragma unroll
    for (int nt = 0; nt < 8; ++nt) {
      #pragma unroll
      for (int r = 0; r < 4; ++r)
        if (rowb + r < N)
          nh_out[(size_t)(rowb + r) * 128 + nt * 16 + l15] =
              siluf(acc[nt][r] + b1[nt]);
    }
  }
}

// ---------------------------------------------------------------------------
// Pass C2: h_upd, gate, v_upd, x_upd -> d_out
// ---------------------------------------------------------------------------
__global__ __launch_bounds__(256) void node_pass_c2(
    const float* __restrict__ h, const float* __restrict__ x,
    const float* __restrict__ v, const float* __restrict__ nh,
    const float* __restrict__ dv_sum, const float* __restrict__ counts,
    const float* __restrict__ W_node2, const float* __restrict__ b_node2,
    const float* __restrict__ W_vel1, const float* __restrict__ b_vel1,
    const float* __restrict__ W_vel2,
    float* __restrict__ out, int N, int nIter)
{
  __shared__ float sW2[128 * 64];
  __shared__ float sWv1[64 * 32];
  __shared__ float sb2[64];
  __shared__ float sbv1[32];
  __shared__ float sWv2[32];
  __shared__ float snh[4][128];
  __shared__ float shu[4][64];

  const int tid = threadIdx.x;
  for (int k = tid; k < 128 * 64; k += 256) sW2[k] = W_node2[k];
  for (int k = tid; k < 64 * 32; k += 256) sWv1[k] = W_vel1[k];
  for (int k = tid; k < 64; k += 256) sb2[k] = b_node2[k];
  for (int k = tid; k < 32; k += 256) sbv1[k] = b_vel1[k];
  for (int k = tid; k < 32; k += 256) sWv2[k] = W_vel2[k];
  __syncthreads();

  const int lane = tid & 63;
  const int w = tid >> 6;
  const int gw = blockIdx.x * 4 + w;
  const int stride = gridDim.x * 4;

  for (int it = 0; it < nIter; ++it) {
    const int n = gw + it * stride;
    const bool active = (n < N);
    if (active) {
      snh[w][lane] = nh[(size_t)n * 128 + lane];
      snh[w][64 + lane] = nh[(size_t)n * 128 + 64 + lane];
    }
    __syncthreads();
    if (active) {
      float acc = sb2[lane];
      #pragma unroll 8
      for (int k = 0; k < 128; ++k) acc += snh[w][k] * sW2[k * 64 + lane];
      const float hu = h[n * DA + lane] + siluf(acc);
      out[(size_t)n * DA + lane] = hu;
      shu[w][lane] = hu;
    }
    __syncthreads();
    if (active) {
      float p = 0.f;
      if (lane < 32) {
        float acc = sbv1[lane];
        #pragma unroll 8
        for (int k = 0; k < 64; ++k) acc += shu[w][k] * sWv1[k * 32 + lane];
        p = siluf(acc) * sWv2[lane];
      }
      p += __shfl_xor(p, 16);
      p += __shfl_xor(p, 8);
      p += __shfl_xor(p, 4);
      p += __shfl_xor(p, 2);
      p += __shfl_xor(p, 1);
      const float s = __shfl(p, 0);
      const float gate = 2.0f / (1.0f + __expf(-s));
      if (lane < 3) {
        const float cnt = fmaxf(counts[n], 1.0f);
        const float dvx = dv_sum[n * 3 + lane] / cnt;
        const float vu = gate * v[n * 3 + lane] + dvx;
        out[(size_t)N * 64 + n * 3 + lane] = x[n * 3 + lane] + vu;
        out[(size_t)N * 64 + (size_t)N * 3 + n * 3 + lane] = vu;
      }
    }
    __syncthreads();
  }
}

// ---------------------------------------------------------------------------
extern "C" void kernel_launch(void* const* d_in, const int* in_sizes, int n_in,
                              void* d_out, int out_size, void* d_ws, size_t ws_size,
                              hipStream_t stream) {
  const float* h   = (const float*)d_in[0];
  const float* x   = (const float*)d_in[1];
  const float* v   = (const float*)d_in[2];
  const int* idx_i = (const int*)d_in[3];
  const int* idx_j = (const int*)d_in[4];
  const float* W_edge_in  = (const float*)d_in[5];
  const float* b_edge_in  = (const float*)d_in[6];
  const float* W_edge_h   = (const float*)d_in[7];
  const float* b_edge_h   = (const float*)d_in[8];
  const float* W_edge_out = (const float*)d_in[9];
  const float* b_edge_out = (const float*)d_in[10];
  const float* W_att      = (const float*)d_in[11];
  const float* b_att      = (const float*)d_in[12];
  const float* W_x_mix    = (const float*)d_in[13];
  const float* W_node1    = (const float*)d_in[14];
  const float* b_node1    = (const float*)d_in[15];
  const float* W_node2    = (const float*)d_in[16];
  const float* b_node2    = (const float*)d_in[17];
  const float* W_post1    = (const float*)d_in[18];
  const float* b_post1    = (const float*)d_in[19];
  const float* W_post2    = (const float*)d_in[20];
  const float* b_post2    = (const float*)d_in[21];
  const float* W_vel1     = (const float*)d_in[22];
  const float* b_vel1     = (const float*)d_in[23];
  const float* W_vel2     = (const float*)d_in[24];
  const float* w_v_mix    = (const float*)d_in[25];

  const int E = in_sizes[3];
  const int N = in_sizes[0] / DA;

  float* ws = (float*)d_ws;
  size_t off = 0;
  float* denom    = ws + off; off += (size_t)N * 4;     // zeroed
  int*   deg      = (int*)(ws + off); off += (size_t)N; // zeroed
  const size_t zeroBytes = off * sizeof(float);
  float* counts   = ws + off; off += (size_t)N;
  int*   rowstart = (int*)(ws + off); off += (size_t)N + 4;
  int*   cursor   = (int*)(ws + off); off += (size_t)N;
  int*   tsum     = (int*)(ws + off); off += (size_t)SCAN_T;
  int*   perm     = (int*)(ws + off); off += (size_t)E;
  float* pE       = ws + off; off += (size_t)E;
  float* expl     = ws + off; off += (size_t)E * 4;
  float* dirb     = ws + off; off += (size_t)E * 3;
  float* hsemR    = ws + off; off += (size_t)N * 64;    // hsem bf16 [N,128]
  float* comb_sum = ws + off; off += (size_t)N * 96;
  float* dv_sum   = ws + off; off += (size_t)N * 4;
  float* hbfR     = ws + off; off += (size_t)N * 32;    // h_bf bf16 [N,64]
  float* fltR     = ws + off; off += (size_t)E * 16;    // Filt / mixE / nh
  float* hebR     = ws + off; off += (size_t)E * 16;    // heb bf16 [E,32]

  ushort_t* h_bf = (ushort_t*)hbfR;
  ushort_t* hsem = (ushort_t*)hsemR;
  ushort_t* Filt = (ushort_t*)fltR;
  ushort_t* heb  = (ushort_t*)hebR;
  ushort_t* mixE = (ushort_t*)fltR;  // aliases Filt (dead after edge_f2)
  float* nh = fltR;                  // aliases mixE (dead after node_reduce)

  hipMemsetAsync(d_ws, 0, zeroBytes, stream);

  {
    const int n4 = (N * 64) / 4;
    cast_h<<<(n4 + 255) / 256, 256, 0, stream>>>(h, h_bf, n4);
  }
  edge_f1<<<1024, 256, 0, stream>>>(h_bf, x, idx_i, idx_j, W_edge_in,
                                    b_edge_in, Filt, dirb, deg, E);
  {
    const int C = (N + SCAN_T - 1) / SCAN_T;
    deg_tsum<<<SCAN_B, 256, 0, stream>>>(deg, tsum, N, C);
    scan_tsum<<<1, 256, 0, stream>>>(tsum);
    write_csr<<<SCAN_B, 256, 0, stream>>>(deg, tsum, rowstart, cursor, counts, N, C);
  }
  bucket_edges<<<512, 256, 0, stream>>>(idx_i, cursor, perm, E);
  edge_f2<<<1024, 256, 0, stream>>>(h_bf, idx_i, idx_j, Filt, W_edge_h,
                                    b_edge_h, W_edge_out, b_edge_out,
                                    W_att, b_att, heb, expl, denom, E);
  mix_kernel<<<1024, 256, 0, stream>>>(heb, idx_i, expl, denom, W_x_mix,
                                       w_v_mix, mixE, pE, E);
  node_reduce<<<2048, 256, 0, stream>>>(rowstart, perm, heb, mixE, expl, denom,
                                        dirb, pE, hsem, comb_sum, dv_sum, N);
  node_c1_mfma<<<512, 256, 0, stream>>>(
      h_bf, hsem, comb_sum, counts, W_post1, b_post1, W_post2, b_post2,
      W_node1, b_node1, nh, N);
  {
    const int grid = 1024;
    const int nIter = (N + grid * 4 - 1) / (grid * 4);
    node_pass_c2<<<grid, 256, 0, stream>>>(
        h, x, v, nh, dv_sum, counts, W_node2, b_node2, W_vel1, b_vel1, W_vel2,
        (float*)d_out, N, nIter);
  }
}

// Round 9
// 483.418 us; speedup vs baseline: 5.6549x; 1.0245x over previous
//
#include <hip/hip_runtime.h>
#include <math.h>

#define DA 64
#define NODEIN_DIM 224
#define EPSC 1e-8f

typedef short v8s __attribute__((ext_vector_type(8)));
typedef float v4f __attribute__((ext_vector_type(4)));
typedef unsigned short ushort_t;

__device__ __forceinline__ float siluf(float v) { return v / (1.0f + __expf(-v)); }

__device__ __forceinline__ void atomAddF(float* p, float v) {
#if defined(__HIP_DEVICE_COMPILE__)
  unsafeAtomicAdd(p, v);
#else
  atomicAdd(p, v);
#endif
}

__device__ __forceinline__ unsigned short f2bfu(float f) {
  union { float f; unsigned u; } v; v.f = f;
  unsigned r = v.u + 0x7fffu + ((v.u >> 16) & 1u);
  return (unsigned short)(r >> 16);
}
__device__ __forceinline__ short f2bfs(float f) { return (short)f2bfu(f); }
__device__ __forceinline__ float bf2f(ushort_t s) {
  union { unsigned u; float f; } v; v.u = ((unsigned)s) << 16; return v.f;
}

#define MU0 0.60653065971263342f
#define DMU ((1.0f - 0.60653065971263342f) / 19.0f)
#define BETA ((float)(1.0 / (0.039346934028736658 * 0.039346934028736658)))

// ---------------------------------------------------------------------------
__global__ __launch_bounds__(256) void cast_h(
    const float* __restrict__ hsrc, ushort_t* __restrict__ hb, int n4)
{
  const int i = blockIdx.x * blockDim.x + threadIdx.x;
  if (i < n4) {
    const float4 fv = ((const float4*)hsrc)[i];
    ushort4 o;
    o.x = f2bfu(fv.x); o.y = f2bfu(fv.y); o.z = f2bfu(fv.z); o.w = f2bfu(fv.w);
    ((ushort4*)hb)[i] = o;
  }
}

// ---------------------------------------------------------------------------
// deg_count: histogram of idx_i
// ---------------------------------------------------------------------------
__global__ __launch_bounds__(256) void deg_count(
    const int* __restrict__ idx_i, int* __restrict__ deg, int E)
{
  const int stride = gridDim.x * blockDim.x;
  for (int e = blockIdx.x * blockDim.x + threadIdx.x; e < E; e += stride)
    atomicAdd(&deg[idx_i[e]], 1);
}

// ---------------------------------------------------------------------------
// Parallel CSR scan
// ---------------------------------------------------------------------------
#define SCAN_B 64
#define SCAN_T (SCAN_B * 256)

__global__ __launch_bounds__(256) void deg_tsum(
    const int* __restrict__ deg, int* __restrict__ tsum, int N, int C)
{
  const int g = blockIdx.x * blockDim.x + threadIdx.x;
  const int lo = g * C;
  const int hi = (lo + C < N) ? (lo + C) : N;
  int s = 0;
  for (int i = lo; i < hi; ++i) s += deg[i];
  tsum[g] = s;
}

__global__ __launch_bounds__(256) void scan_tsum(int* __restrict__ tsum)
{
  __shared__ int ps[256];
  const int t = threadIdx.x;
  const int per = SCAN_T / 256;
  const int lo = t * per;
  int s = 0;
  for (int i = 0; i < per; ++i) s += tsum[lo + i];
  ps[t] = s;
  __syncthreads();
  if (t == 0) {
    int a = 0;
    for (int i = 0; i < 256; ++i) { const int v = ps[i]; ps[i] = a; a += v; }
  }
  __syncthreads();
  int acc = ps[t];
  for (int i = 0; i < per; ++i) {
    const int v = tsum[lo + i];
    tsum[lo + i] = acc;
    acc += v;
  }
}

__global__ __launch_bounds__(256) void write_csr(
    const int* __restrict__ deg, const int* __restrict__ tpre,
    int* __restrict__ rowstart, int* __restrict__ cursor,
    float* __restrict__ counts, int N, int C)
{
  const int g = blockIdx.x * blockDim.x + threadIdx.x;
  const int lo = g * C;
  const int hi = (lo + C < N) ? (lo + C) : N;
  int acc = tpre[g];
  for (int i = lo; i < hi; ++i) {
    const int d = deg[i];
    rowstart[i] = acc;
    cursor[i] = acc;
    counts[i] = (float)d;
    acc += d;
  }
  if (hi == N) rowstart[N] = acc;
}

// ---------------------------------------------------------------------------
// bucket_edges: scatter idx pairs into CSR slots
// ---------------------------------------------------------------------------
__global__ __launch_bounds__(256) void bucket_edges(
    const int* __restrict__ idx_i, const int* __restrict__ idx_j,
    int* __restrict__ cursor, int* __restrict__ iperm,
    int* __restrict__ jperm, int E)
{
  const int stride = gridDim.x * blockDim.x;
  for (int e = blockIdx.x * blockDim.x + threadIdx.x; e < E; e += stride) {
    const int ii = idx_i[e];
    const int pos = atomicAdd(&cursor[ii], 1);
    iperm[pos] = ii;
    jperm[pos] = idx_j[e];
  }
}

// ---------------------------------------------------------------------------
// F1 (CSR order): gather + geometry + M1 + RBF -> Filt[slot], dirb[slot]
// ---------------------------------------------------------------------------
__global__ __launch_bounds__(256) void edge_f1(
    const ushort_t* __restrict__ h_bf, const float* __restrict__ x,
    const int* __restrict__ iperm, const int* __restrict__ jperm,
    const float* __restrict__ W_in, const float* __restrict__ b_in,
    ushort_t* __restrict__ Filt, float* __restrict__ dirb, int E)
{
  const int tid = blockIdx.x * blockDim.x + threadIdx.x;
  const int wid = tid >> 6;
  const int lane = threadIdx.x & 63;
  const int nw = (gridDim.x * blockDim.x) >> 6;
  const int l15 = lane & 15;
  const int q = lane >> 4;

  v8s bfr[4][2];
  #pragma unroll
  for (int kc = 0; kc < 4; ++kc)
    #pragma unroll
    for (int nt = 0; nt < 2; ++nt)
      #pragma unroll
      for (int j = 0; j < 8; ++j) {
        const int k = kc * 32 + q * 8 + j;
        const int col = nt * 16 + l15;
        bfr[kc][nt][j] = (col < 20) ? f2bfs(W_in[k * 20 + col]) : (short)0;
      }
  float bin[2], mu[2];
  #pragma unroll
  for (int nt = 0; nt < 2; ++nt) {
    const int col = nt * 16 + l15;
    bin[nt] = (col < 20) ? b_in[col] : 0.0f;
    mu[nt] = MU0 + (float)col * DMU;
  }

  const int ntiles = (E + 15) >> 4;
  for (int t = wid; t < ntiles; t += nw) {
    const int row = t * 16 + l15;
    const int rowL = (row < E) ? row : (E - 1);
    const int ii = iperm[rowL];
    const int jj = jperm[rowL];

    v8s afr[4];
    afr[0] = *(const v8s*)(h_bf + (size_t)ii * 64 + q * 8);
    afr[1] = *(const v8s*)(h_bf + (size_t)ii * 64 + 32 + q * 8);
    afr[2] = *(const v8s*)(h_bf + (size_t)jj * 64 + q * 8);
    afr[3] = *(const v8s*)(h_bf + (size_t)jj * 64 + 32 + q * 8);

    float dval = 0.0f;
    if (lane < 16 && row < E) {
      const float rx = x[jj * 3 + 0] - x[ii * 3 + 0];
      const float ry = x[jj * 3 + 1] - x[ii * 3 + 1];
      const float rz = x[jj * 3 + 2] - x[ii * 3 + 2];
      const float d = sqrtf(rx * rx + ry * ry + rz * rz + EPSC);
      dval = d;
      const float inv = 1.0f / (d + EPSC);
      dirb[row * 3 + 0] = rx * inv;
      dirb[row * 3 + 1] = ry * inv;
      dirb[row * 3 + 2] = rz * inv;
    }

    v4f acc[2];
    #pragma unroll
    for (int nt = 0; nt < 2; ++nt) {
      v4f a = {0.f, 0.f, 0.f, 0.f};
      #pragma unroll
      for (int kc = 0; kc < 4; ++kc)
        a = __builtin_amdgcn_mfma_f32_16x16x32_bf16(afr[kc], bfr[kc][nt], a, 0, 0, 0);
      acc[nt] = a;
    }

    const int rowb = t * 16 + q * 4;
    float dr[4], edr[4];
    #pragma unroll
    for (int r = 0; r < 4; ++r) {
      dr[r] = __shfl(dval, q * 4 + r);
      edr[r] = __expf(-dr[r]);
    }
    #pragma unroll
    for (int nt = 0; nt < 2; ++nt) {
      const int col = nt * 16 + l15;
      #pragma unroll
      for (int r = 0; r < 4; ++r) {
        ushort_t ov;
        if (col < 20) {
          const float tt = edr[r] - mu[nt];
          ov = f2bfu((acc[nt][r] + bin[nt]) * __expf(-BETA * tt * tt));
        } else if (col == 20) {
          ov = f2bfu(dr[r]);
        } else {
          ov = 0;
        }
        if (rowb + r < E) Filt[(size_t)(rowb + r) * 32 + col] = ov;
      }
    }
  }
}

// ---------------------------------------------------------------------------
// F2 (CSR order): M2 + transpose + M3 -> heb[slot] + MFMA att epilogue
// ---------------------------------------------------------------------------
#define THS 72
__global__ __launch_bounds__(256) void edge_f2(
    const ushort_t* __restrict__ h_bf,
    const int* __restrict__ iperm, const int* __restrict__ jperm,
    const ushort_t* __restrict__ Filt,
    const float* __restrict__ W_h, const float* __restrict__ b_h,
    const float* __restrict__ W_out, const float* __restrict__ b_out,
    const float* __restrict__ W_att, const float* __restrict__ b_att,
    ushort_t* __restrict__ heb, float* __restrict__ expl,
    float* __restrict__ denom, int E)
{
  __shared__ ushort_t sB2[20 * 64 * 8];
  __shared__ ushort_t sB3[4 * 64 * 8];
  __shared__ ushort_t tH[4][16 * THS];

  const int tid = threadIdx.x;
  for (int idx = tid; idx < 20 * 64 * 8; idx += 256) {
    const int j = idx & 7;
    const int ln = (idx >> 3) & 63;
    const int f = idx >> 9;
    const int k = (f >> 2) * 32 + (ln >> 4) * 8 + j;
    const int col = (f & 3) * 16 + (ln & 15);
    sB2[idx] = (k < 149) ? f2bfu(W_h[k * 64 + col]) : (ushort_t)0;
  }
  for (int idx = tid; idx < 4 * 64 * 8; idx += 256) {
    const int j = idx & 7;
    const int ln = (idx >> 3) & 63;
    const int f = idx >> 9;
    const int k = (f >> 1) * 32 + (ln >> 4) * 8 + j;
    const int col = (f & 1) * 16 + (ln & 15);
    sB3[idx] = f2bfu(W_out[k * 32 + col]);
  }
  __syncthreads();

  const int gtid = blockIdx.x * blockDim.x + tid;
  const int wid = gtid >> 6;
  const int lane = tid & 63;
  const int w = tid >> 6;
  const int nw = (gridDim.x * blockDim.x) >> 6;
  const int l15 = lane & 15;
  const int q = lane >> 4;

  const ushort_t* b2l = sB2 + lane * 8;
  const ushort_t* b3l = sB3 + lane * 8;

  float bias2[4];
  #pragma unroll
  for (int nt = 0; nt < 4; ++nt) bias2[nt] = b_h[nt * 16 + l15];
  float bias3[2];
  #pragma unroll
  for (int nt = 0; nt < 2; ++nt) bias3[nt] = b_out[nt * 16 + l15];

  v8s battf;
  #pragma unroll
  for (int j = 0; j < 8; ++j)
    battf[j] = (l15 < 4) ? f2bfs(W_att[(q * 8 + j) * 4 + l15]) : (short)0;
  const float bav = (l15 < 4) ? b_att[l15] : 0.0f;

  const int ntiles = (E + 15) >> 4;

  int iiC = 0;
  v8s afr[5];
  if (wid < ntiles) {
    const int row0 = wid * 16 + l15;
    const int rowL0 = (row0 < E) ? row0 : (E - 1);
    iiC = iperm[rowL0];
    const int jj0 = jperm[rowL0];
    afr[0] = *(const v8s*)(h_bf + (size_t)iiC * 64 + q * 8);
    afr[1] = *(const v8s*)(h_bf + (size_t)iiC * 64 + 32 + q * 8);
    afr[2] = *(const v8s*)(h_bf + (size_t)jj0 * 64 + q * 8);
    afr[3] = *(const v8s*)(h_bf + (size_t)jj0 * 64 + 32 + q * 8);
    afr[4] = *(const v8s*)(Filt + (size_t)rowL0 * 32 + q * 8);
  }

  for (int t = wid; t < ntiles; t += nw) {
    const int tn = t + nw;
    int iiN = 0;
    v8s nfr[5];
    if (tn < ntiles) {
      const int rowN = tn * 16 + l15;
      const int rowLN = (rowN < E) ? rowN : (E - 1);
      iiN = iperm[rowLN];
      const int jjN = jperm[rowLN];
      nfr[0] = *(const v8s*)(h_bf + (size_t)iiN * 64 + q * 8);
      nfr[1] = *(const v8s*)(h_bf + (size_t)iiN * 64 + 32 + q * 8);
      nfr[2] = *(const v8s*)(h_bf + (size_t)jjN * 64 + q * 8);
      nfr[3] = *(const v8s*)(h_bf + (size_t)jjN * 64 + 32 + q * 8);
      nfr[4] = *(const v8s*)(Filt + (size_t)rowLN * 32 + q * 8);
    }

    v4f acc2[4];
    #pragma unroll
    for (int nt = 0; nt < 4; ++nt) {
      v4f a = {0.f, 0.f, 0.f, 0.f};
      #pragma unroll
      for (int kc = 0; kc < 5; ++kc) {
        const v8s bfrag = *(const v8s*)(b2l + (kc * 4 + nt) * 512);
        a = __builtin_amdgcn_mfma_f32_16x16x32_bf16(afr[kc], bfrag, a, 0, 0, 0);
      }
      acc2[nt] = a;
    }

    #pragma unroll
    for (int nt = 0; nt < 4; ++nt) {
      #pragma unroll
      for (int r = 0; r < 4; ++r)
        tH[w][(q * 4 + r) * THS + nt * 16 + l15] =
            f2bfu(siluf(acc2[nt][r] + bias2[nt]));
    }
    __builtin_amdgcn_wave_barrier();

    v8s af3[2];
    af3[0] = *(const v8s*)&tH[w][l15 * THS + q * 8];
    af3[1] = *(const v8s*)&tH[w][l15 * THS + 32 + q * 8];

    v4f acc3[2];
    #pragma unroll
    for (int nt = 0; nt < 2; ++nt) {
      v4f a = {0.f, 0.f, 0.f, 0.f};
      #pragma unroll
      for (int kc = 0; kc < 2; ++kc) {
        const v8s bfrag = *(const v8s*)(b3l + (kc * 2 + nt) * 512);
        a = __builtin_amdgcn_mfma_f32_16x16x32_bf16(af3[kc], bfrag, a, 0, 0, 0);
      }
      acc3[nt] = a;
    }
    __builtin_amdgcn_wave_barrier();

    const int rowb = t * 16 + q * 4;
    #pragma unroll
    for (int nt = 0; nt < 2; ++nt) {
      const int col = nt * 16 + l15;
      #pragma unroll
      for (int r = 0; r < 4; ++r) {
        const ushort_t hv = f2bfu(acc3[nt][r] + bias3[nt]);
        tH[w][(q * 4 + r) * THS + col] = hv;
        if (rowb + r < E) heb[(size_t)(rowb + r) * 32 + col] = hv;
      }
    }
    __builtin_amdgcn_wave_barrier();

    const v8s afA = *(const v8s*)&tH[w][l15 * THS + q * 8];
    v4f az = {0.f, 0.f, 0.f, 0.f};
    const v4f aacc = __builtin_amdgcn_mfma_f32_16x16x32_bf16(afA, battf, az, 0, 0, 0);

    int ii_r[4];
    #pragma unroll
    for (int r = 0; r < 4; ++r) ii_r[r] = __shfl(iiC, q * 4 + r);

    if (l15 < 4) {
      #pragma unroll
      for (int r = 0; r < 4; ++r) {
        if (rowb + r < E) {
          const float la = aacc[r] + bav;
          const float l = (la > 0.f) ? la : 2.0f * (__expf(0.5f * la) - 1.0f);
          const float ev = __expf(l);
          expl[(size_t)(rowb + r) * 4 + l15] = ev;
          atomAddF(&denom[ii_r[r] * 4 + l15], ev);
        }
      }
    }
    __builtin_amdgcn_wave_barrier();

    iiC = iiN;
    afr[0] = nfr[0]; afr[1] = nfr[1]; afr[2] = nfr[2];
    afr[3] = nfr[3]; afr[4] = nfr[4];
  }
}

// ---------------------------------------------------------------------------
// mix_kernel (CSR order)
// ---------------------------------------------------------------------------
__global__ __launch_bounds__(256) void mix_kernel(
    const ushort_t* __restrict__ heb, const int* __restrict__ iperm,
    const float* __restrict__ expl, const float* __restrict__ denom,
    const float* __restrict__ W_xmix, const float* __restrict__ w_vmix,
    ushort_t* __restrict__ mixE, float* __restrict__ pE, int E)
{
  const int tid = blockIdx.x * blockDim.x + threadIdx.x;
  const int wid = tid >> 6;
  const int lane = threadIdx.x & 63;
  const int nw = (gridDim.x * blockDim.x) >> 6;
  const int l15 = lane & 15;
  const int q = lane >> 4;

  v8s bfr[4][2];
  #pragma unroll
  for (int kc = 0; kc < 4; ++kc)
    #pragma unroll
    for (int nt = 0; nt < 2; ++nt)
      #pragma unroll
      for (int j = 0; j < 8; ++j) {
        const int k = kc * 32 + q * 8 + j;
        const int col = nt * 16 + l15;
        bfr[kc][nt][j] = f2bfs(W_xmix[k * 32 + col]);
      }
  float wv[2];
  wv[0] = w_vmix[l15];
  wv[1] = w_vmix[16 + l15];

  const int ntiles = (E + 15) >> 4;
  for (int t = wid; t < ntiles; t += nw) {
    const int row = t * 16 + l15;
    const int rowL = (row < E) ? row : (E - 1);
    const int ii = iperm[rowL];
    float att[4];
    #pragma unroll
    for (int hh = 0; hh < 4; ++hh)
      att[hh] = expl[(size_t)rowL * 4 + hh] / (denom[ii * 4 + hh] + EPSC);

    const v8s hech = *(const v8s*)(heb + (size_t)rowL * 32 + q * 8);
    float hef[8];
    #pragma unroll
    for (int j = 0; j < 8; ++j) hef[j] = bf2f((ushort_t)hech[j]);

    v8s afr[4];
    #pragma unroll
    for (int kc = 0; kc < 4; ++kc)
      #pragma unroll
      for (int j = 0; j < 8; ++j)
        afr[kc][j] = f2bfs(att[kc] * hef[j]);

    v4f acc[2];
    #pragma unroll
    for (int nt = 0; nt < 2; ++nt) {
      v4f a = {0.f, 0.f, 0.f, 0.f};
      #pragma unroll
      for (int kc = 0; kc < 4; ++kc)
        a = __builtin_amdgcn_mfma_f32_16x16x32_bf16(afr[kc], bfr[kc][nt], a, 0, 0, 0);
      acc[nt] = a;
    }

    const int rowb = t * 16 + q * 4;
    float pr[4];
    #pragma unroll
    for (int r = 0; r < 4; ++r) {
      const float m0 = tanhf(acc[0][r]);
      const float m1 = tanhf(acc[1][r]);
      if (rowb + r < E) {
        mixE[(size_t)(rowb + r) * 32 + l15] = f2bfu(m0);
        mixE[(size_t)(rowb + r) * 32 + 16 + l15] = f2bfu(m1);
      }
      pr[r] = m0 * wv[0] + m1 * wv[1];
    }
    #pragma unroll
    for (int r = 0; r < 4; ++r) {
      pr[r] += __shfl_xor(pr[r], 1);
      pr[r] += __shfl_xor(pr[r], 2);
      pr[r] += __shfl_xor(pr[r], 4);
      pr[r] += __shfl_xor(pr[r], 8);
      if (l15 == 0 && rowb + r < E) pE[rowb + r] = pr[r];
    }
  }
}

// ---------------------------------------------------------------------------
// node_reduce: wave per node, STREAMING reads (edge data in CSR order)
// ---------------------------------------------------------------------------
__global__ __launch_bounds__(256) void node_reduce(
    const int* __restrict__ rowstart,
    const ushort_t* __restrict__ heb, const ushort_t* __restrict__ mixE,
    const float* __restrict__ expl, const float* __restrict__ denom,
    const float* __restrict__ dirb, const float* __restrict__ pE,
    ushort_t* __restrict__ hsem, float* __restrict__ comb_sum,
    float* __restrict__ dv_sum, int N)
{
  const int tid = blockIdx.x * blockDim.x + threadIdx.x;
  const int wid = tid >> 6;
  const int lane = threadIdx.x & 63;
  const int nw = (gridDim.x * blockDim.x) >> 6;
  const int hh = lane >> 5;
  const int eb = lane & 31;

  for (int n = wid; n < N; n += nw) {
    const int s = rowstart[n];
    const int epd = rowstart[n + 1];
    float semA = 0.f, semB = 0.f;
    float cx = 0.f, cy = 0.f, cz = 0.f;
    float dvx = 0.f, dvy = 0.f, dvz = 0.f;
    for (int k = s; k < epd; ++k) {
      const float he = bf2f(heb[(size_t)k * 32 + eb]);
      const float ea = expl[(size_t)k * 4 + hh];
      const float ec = expl[(size_t)k * 4 + 2 + hh];
      semA += ea * he;
      semB += ec * he;
      const float dx = dirb[k * 3 + 0];
      const float dy = dirb[k * 3 + 1];
      const float dz = dirb[k * 3 + 2];
      if (lane < 32) {
        const float m = bf2f(mixE[(size_t)k * 32 + lane]);
        cx += dx * m; cy += dy * m; cz += dz * m;
      }
      if (lane == 0) {
        const float pe = pE[k];
        dvx += dx * pe; dvy += dy * pe; dvz += dz * pe;
      }
    }
    const float dA = denom[n * 4 + hh] + EPSC;
    const float dB = denom[n * 4 + 2 + hh] + EPSC;
    hsem[(size_t)n * 128 + lane] = f2bfu(semA / dA);
    hsem[(size_t)n * 128 + 64 + lane] = f2bfu(semB / dB);
    if (lane < 32) {
      comb_sum[(size_t)n * 96 + lane * 3 + 0] = cx;
      comb_sum[(size_t)n * 96 + lane * 3 + 1] = cy;
      comb_sum[(size_t)n * 96 + lane * 3 + 2] = cz;
    }
    if (lane == 0) {
      dv_sum[n * 3 + 0] = dvx;
      dv_sum[n * 3 + 1] = dvy;
      dv_sum[n * 3 + 2] = dvz;
    }
  }
}

// ---------------------------------------------------------------------------
// C1 (MFMA): spatial MLP (post1/post2) + node1, wave per 16-node tile.
// ---------------------------------------------------------------------------
#define W1S 232
__global__ __launch_bounds__(256) void node_c1_mfma(
    const ushort_t* __restrict__ h_bf, const ushort_t* __restrict__ hsem,
    const float* __restrict__ comb_sum, const float* __restrict__ counts,
    const float* __restrict__ W_post1, const float* __restrict__ b_post1,
    const float* __restrict__ W_post2, const float* __restrict__ b_post2,
    const float* __restrict__ W_node1, const float* __restrict__ b_node1,
    float* __restrict__ nh_out, int N)
{
  __shared__ ushort_t sW1t[128 * W1S];
  __shared__ ushort_t tp[4][16 * THS];

  const int tid = threadIdx.x;
  for (int idx = tid; idx < 224 * 128; idx += 256) {
    const int k = idx >> 7;
    const int c = idx & 127;
    sW1t[c * W1S + k] = f2bfu(W_node1[idx]);
  }
  __syncthreads();

  const int lane = tid & 63;
  const int w = tid >> 6;
  const int l15 = lane & 15;
  const int q = lane >> 4;

  v8s bp1[4];
  #pragma unroll
  for (int nt = 0; nt < 4; ++nt)
    #pragma unroll
    for (int j = 0; j < 8; ++j)
      bp1[nt][j] = f2bfs(W_post1[(q * 8 + j) * 64 + nt * 16 + l15]);
  v8s bp2[2][2];
  #pragma unroll
  for (int kc = 0; kc < 2; ++kc)
    #pragma unroll
    for (int nt = 0; nt < 2; ++nt)
      #pragma unroll
      for (int j = 0; j < 8; ++j)
        bp2[kc][nt][j] = f2bfs(W_post2[(kc * 32 + q * 8 + j) * 32 + nt * 16 + l15]);
  float bb1[4];
  #pragma unroll
  for (int nt = 0; nt < 4; ++nt) bb1[nt] = b_post1[nt * 16 + l15];
  float bb2[2];
  #pragma unroll
  for (int nt = 0; nt < 2; ++nt) bb2[nt] = b_post2[nt * 16 + l15];
  float b1[8];
  #pragma unroll
  for (int nt = 0; nt < 8; ++nt) b1[nt] = b_node1[nt * 16 + l15];

  const int gw = blockIdx.x * 4 + w;
  const int nwv = gridDim.x * 4;
  const int ntiles = (N + 15) >> 4;

  for (int t = gw; t < ntiles; t += nwv) {
    const int row = t * 16 + l15;
    const int rowL = (row < N) ? row : (N - 1);

    const float inv = 1.0f / fmaxf(counts[rowL], 1.0f);
    const float4* cs = (const float4*)(comb_sum + (size_t)rowL * 96 + q * 24);
    float cf[24];
    #pragma unroll
    for (int b = 0; b < 6; ++b) {
      const float4 cv = cs[b];
      cf[b * 4 + 0] = cv.x; cf[b * 4 + 1] = cv.y;
      cf[b * 4 + 2] = cv.z; cf[b * 4 + 3] = cv.w;
    }
    v8s a1;
    #pragma unroll
    for (int j = 0; j < 8; ++j) {
      const float vx = cf[j * 3 + 0] * inv;
      const float vy = cf[j * 3 + 1] * inv;
      const float vz = cf[j * 3 + 2] * inv;
      a1[j] = f2bfs(vx * vx + vy * vy + vz * vz);
    }

    v4f p1[4];
    #pragma unroll
    for (int nt = 0; nt < 4; ++nt) {
      v4f a = {0.f, 0.f, 0.f, 0.f};
      p1[nt] = __builtin_amdgcn_mfma_f32_16x16x32_bf16(a1, bp1[nt], a, 0, 0, 0);
    }
    #pragma unroll
    for (int nt = 0; nt < 4; ++nt)
      #pragma unroll
      for (int r = 0; r < 4; ++r)
        tp[w][(q * 4 + r) * THS + nt * 16 + l15] =
            f2bfu(siluf(p1[nt][r] + bb1[nt]));
    __builtin_amdgcn_wave_barrier();

    v8s a2[2];
    a2[0] = *(const v8s*)&tp[w][l15 * THS + q * 8];
    a2[1] = *(const v8s*)&tp[w][l15 * THS + 32 + q * 8];

    v4f p2[2];
    #pragma unroll
    for (int nt = 0; nt < 2; ++nt) {
      v4f a = {0.f, 0.f, 0.f, 0.f};
      #pragma unroll
      for (int kc = 0; kc < 2; ++kc)
        a = __builtin_amdgcn_mfma_f32_16x16x32_bf16(a2[kc], bp2[kc][nt], a, 0, 0, 0);
      p2[nt] = a;
    }
    __builtin_amdgcn_wave_barrier();
    #pragma unroll
    for (int nt = 0; nt < 2; ++nt)
      #pragma unroll
      for (int r = 0; r < 4; ++r)
        tp[w][(q * 4 + r) * THS + nt * 16 + l15] =
            f2bfu(siluf(p2[nt][r] + bb2[nt]));
    __builtin_amdgcn_wave_barrier();

    v8s af[7];
    af[0] = *(const v8s*)(h_bf + (size_t)rowL * 64 + q * 8);
    af[1] = *(const v8s*)(h_bf + (size_t)rowL * 64 + 32 + q * 8);
    #pragma unroll
    for (int kc = 0; kc < 4; ++kc)
      af[2 + kc] = *(const v8s*)(hsem + (size_t)rowL * 128 + kc * 32 + q * 8);
    af[6] = *(const v8s*)&tp[w][l15 * THS + q * 8];

    v4f acc[8];
    #pragma unroll
    for (int nt = 0; nt < 8; ++nt) acc[nt] = (v4f){0.f, 0.f, 0.f, 0.f};
    #pragma unroll
    for (int kc = 0; kc < 7; ++kc) {
      #pragma unroll
      for (int nt = 0; nt < 8; ++nt) {
        const v8s bfrag =
            *(const v8s*)&sW1t[(nt * 16 + l15) * W1S + kc * 32 + q * 8];
        acc[nt] = __builtin_amdgcn_mfma_f32_16x16x32_bf16(af[kc], bfrag, acc[nt], 0, 0, 0);
      }
    }

    const int rowb = t * 16 + q * 4;
    #pragma unroll
    for (int nt = 0; nt < 8; ++nt) {
      #pragma unroll
      for (int r = 0; r < 4; ++r)
        if (rowb + r < N)
          nh_out[(size_t)(rowb + r) * 128 + nt * 16 + l15] =
              siluf(acc[nt][r] + b1[nt]);
    }
  }
}

// ---------------------------------------------------------------------------
// Pass C2: h_upd, gate, v_upd, x_upd -> d_out
// ---------------------------------------------------------------------------
__global__ __launch_bounds__(256) void node_pass_c2(
    const float* __restrict__ h, const float* __restrict__ x,
    const float* __restrict__ v, const float* __restrict__ nh,
    const float* __restrict__ dv_sum, const float* __restrict__ counts,
    const float* __restrict__ W_node2, const float* __restrict__ b_node2,
    const float* __restrict__ W_vel1, const float* __restrict__ b_vel1,
    const float* __restrict__ W_vel2,
    float* __restrict__ out, int N, int nIter)
{
  __shared__ float sW2[128 * 64];
  __shared__ float sWv1[64 * 32];
  __shared__ float sb2[64];
  __shared__ float sbv1[32];
  __shared__ float sWv2[32];
  __shared__ float snh[4][128];
  __shared__ float shu[4][64];

  const int tid = threadIdx.x;
  for (int k = tid; k < 128 * 64; k += 256) sW2[k] = W_node2[k];
  for (int k = tid; k < 64 * 32; k += 256) sWv1[k] = W_vel1[k];
  for (int k = tid; k < 64; k += 256) sb2[k] = b_node2[k];
  for (int k = tid; k < 32; k += 256) sbv1[k] = b_vel1[k];
  for (int k = tid; k < 32; k += 256) sWv2[k] = W_vel2[k];
  __syncthreads();

  const int lane = tid & 63;
  const int w = tid >> 6;
  const int gw = blockIdx.x * 4 + w;
  const int stride = gridDim.x * 4;

  for (int it = 0; it < nIter; ++it) {
    const int n = gw + it * stride;
    const bool active = (n < N);
    if (active) {
      snh[w][lane] = nh[(size_t)n * 128 + lane];
      snh[w][64 + lane] = nh[(size_t)n * 128 + 64 + lane];
    }
    __syncthreads();
    if (active) {
      float acc = sb2[lane];
      #pragma unroll 8
      for (int k = 0; k < 128; ++k) acc += snh[w][k] * sW2[k * 64 + lane];
      const float hu = h[n * DA + lane] + siluf(acc);
      out[(size_t)n * DA + lane] = hu;
      shu[w][lane] = hu;
    }
    __syncthreads();
    if (active) {
      float p = 0.f;
      if (lane < 32) {
        float acc = sbv1[lane];
        #pragma unroll 8
        for (int k = 0; k < 64; ++k) acc += shu[w][k] * sWv1[k * 32 + lane];
        p = siluf(acc) * sWv2[lane];
      }
      p += __shfl_xor(p, 16);
      p += __shfl_xor(p, 8);
      p += __shfl_xor(p, 4);
      p += __shfl_xor(p, 2);
      p += __shfl_xor(p, 1);
      const float s = __shfl(p, 0);
      const float gate = 2.0f / (1.0f + __expf(-s));
      if (lane < 3) {
        const float cnt = fmaxf(counts[n], 1.0f);
        const float dvx = dv_sum[n * 3 + lane] / cnt;
        const float vu = gate * v[n * 3 + lane] + dvx;
        out[(size_t)N * 64 + n * 3 + lane] = x[n * 3 + lane] + vu;
        out[(size_t)N * 64 + (size_t)N * 3 + n * 3 + lane] = vu;
      }
    }
    __syncthreads();
  }
}

// ---------------------------------------------------------------------------
extern "C" void kernel_launch(void* const* d_in, const int* in_sizes, int n_in,
                              void* d_out, int out_size, void* d_ws, size_t ws_size,
                              hipStream_t stream) {
  const float* h   = (const float*)d_in[0];
  const float* x   = (const float*)d_in[1];
  const float* v   = (const float*)d_in[2];
  const int* idx_i = (const int*)d_in[3];
  const int* idx_j = (const int*)d_in[4];
  const float* W_edge_in  = (const float*)d_in[5];
  const float* b_edge_in  = (const float*)d_in[6];
  const float* W_edge_h   = (const float*)d_in[7];
  const float* b_edge_h   = (const float*)d_in[8];
  const float* W_edge_out = (const float*)d_in[9];
  const float* b_edge_out = (const float*)d_in[10];
  const float* W_att      = (const float*)d_in[11];
  const float* b_att      = (const float*)d_in[12];
  const float* W_x_mix    = (const float*)d_in[13];
  const float* W_node1    = (const float*)d_in[14];
  const float* b_node1    = (const float*)d_in[15];
  const float* W_node2    = (const float*)d_in[16];
  const float* b_node2    = (const float*)d_in[17];
  const float* W_post1    = (const float*)d_in[18];
  const float* b_post1    = (const float*)d_in[19];
  const float* W_post2    = (const float*)d_in[20];
  const float* b_post2    = (const float*)d_in[21];
  const float* W_vel1     = (const float*)d_in[22];
  const float* b_vel1     = (const float*)d_in[23];
  const float* W_vel2     = (const float*)d_in[24];
  const float* w_v_mix    = (const float*)d_in[25];

  const int E = in_sizes[3];
  const int N = in_sizes[0] / DA;

  float* ws = (float*)d_ws;
  size_t off = 0;
  float* denom    = ws + off; off += (size_t)N * 4;     // zeroed
  int*   deg      = (int*)(ws + off); off += (size_t)N; // zeroed
  const size_t zeroBytes = off * sizeof(float);
  float* counts   = ws + off; off += (size_t)N;
  int*   rowstart = (int*)(ws + off); off += (size_t)N + 4;
  int*   cursor   = (int*)(ws + off); off += (size_t)N;
  int*   tsum     = (int*)(ws + off); off += (size_t)SCAN_T;
  int*   iperm    = (int*)(ws + off); off += (size_t)E;
  int*   jperm    = (int*)(ws + off); off += (size_t)E;
  float* pE       = ws + off; off += (size_t)E;
  float* expl     = ws + off; off += (size_t)E * 4;
  float* dirb     = ws + off; off += (size_t)E * 3;
  float* hsemR    = ws + off; off += (size_t)N * 64;    // hsem bf16 [N,128]
  float* comb_sum = ws + off; off += (size_t)N * 96;
  float* dv_sum   = ws + off; off += (size_t)N * 4;
  float* hbfR     = ws + off; off += (size_t)N * 32;    // h_bf bf16 [N,64]
  float* fltR     = ws + off; off += (size_t)E * 16;    // Filt / mixE / nh
  float* hebR     = ws + off; off += (size_t)E * 16;    // heb bf16 [E,32]

  ushort_t* h_bf = (ushort_t*)hbfR;
  ushort_t* hsem = (ushort_t*)hsemR;
  ushort_t* Filt = (ushort_t*)fltR;
  ushort_t* heb  = (ushort_t*)hebR;
  ushort_t* mixE = (ushort_t*)fltR;  // aliases Filt (dead after edge_f2)
  float* nh = fltR;                  // aliases mixE (dead after node_reduce)

  hipMemsetAsync(d_ws, 0, zeroBytes, stream);

  {
    const int n4 = (N * 64) / 4;
    cast_h<<<(n4 + 255) / 256, 256, 0, stream>>>(h, h_bf, n4);
  }
  deg_count<<<512, 256, 0, stream>>>(idx_i, deg, E);
  {
    const int C = (N + SCAN_T - 1) / SCAN_T;
    deg_tsum<<<SCAN_B, 256, 0, stream>>>(deg, tsum, N, C);
    scan_tsum<<<1, 256, 0, stream>>>(tsum);
    write_csr<<<SCAN_B, 256, 0, stream>>>(deg, tsum, rowstart, cursor, counts, N, C);
  }
  bucket_edges<<<512, 256, 0, stream>>>(idx_i, idx_j, cursor, iperm, jperm, E);
  edge_f1<<<1024, 256, 0, stream>>>(h_bf, x, iperm, jperm, W_edge_in,
                                    b_edge_in, Filt, dirb, E);
  edge_f2<<<1024, 256, 0, stream>>>(h_bf, iperm, jperm, Filt, W_edge_h,
                                    b_edge_h, W_edge_out, b_edge_out,
                                    W_att, b_att, heb, expl, denom, E);
  mix_kernel<<<1024, 256, 0, stream>>>(heb, iperm, expl, denom, W_x_mix,
                                       w_v_mix, mixE, pE, E);
  node_reduce<<<2048, 256, 0, stream>>>(rowstart, heb, mixE, expl, denom,
                                        dirb, pE, hsem, comb_sum, dv_sum, N);
  node_c1_mfma<<<512, 256, 0, stream>>>(
      h_bf, hsem, comb_sum, counts, W_post1, b_post1, W_post2, b_post2,
      W_node1, b_node1, nh, N);
  {
    const int grid = 1024;
    const int nIter = (N + grid * 4 - 1) / (grid * 4);
    node_pass_c2<<<grid, 256, 0, stream>>>(
        h, x, v, nh, dv_sum, counts, W_node2, b_node2, W_vel1, b_vel1, W_vel2,
        (float*)d_out, N, nIter);
  }
}

// Round 10
// 409.959 us; speedup vs baseline: 6.6682x; 1.1792x over previous
//
#include <hip/hip_runtime.h>
#include <math.h>

#define DA 64
#define NODEIN_DIM 224
#define EPSC 1e-8f

typedef short v8s __attribute__((ext_vector_type(8)));
typedef float v4f __attribute__((ext_vector_type(4)));
typedef unsigned short ushort_t;

__device__ __forceinline__ float siluf(float v) { return v / (1.0f + __expf(-v)); }

__device__ __forceinline__ void atomAddF(float* p, float v) {
#if defined(__HIP_DEVICE_COMPILE__)
  unsafeAtomicAdd(p, v);
#else
  atomicAdd(p, v);
#endif
}

__device__ __forceinline__ unsigned short f2bfu(float f) {
  union { float f; unsigned u; } v; v.f = f;
  unsigned r = v.u + 0x7fffu + ((v.u >> 16) & 1u);
  return (unsigned short)(r >> 16);
}
__device__ __forceinline__ short f2bfs(float f) { return (short)f2bfu(f); }
__device__ __forceinline__ float bf2f(ushort_t s) {
  union { unsigned u; float f; } v; v.u = ((unsigned)s) << 16; return v.f;
}

#define MU0 0.60653065971263342f
#define DMU ((1.0f - 0.60653065971263342f) / 19.0f)
#define BETA ((float)(1.0 / (0.039346934028736658 * 0.039346934028736658)))

// ---------------------------------------------------------------------------
__global__ __launch_bounds__(256) void cast_h(
    const float* __restrict__ hsrc, ushort_t* __restrict__ hb, int n4)
{
  const int i = blockIdx.x * blockDim.x + threadIdx.x;
  if (i < n4) {
    const float4 fv = ((const float4*)hsrc)[i];
    ushort4 o;
    o.x = f2bfu(fv.x); o.y = f2bfu(fv.y); o.z = f2bfu(fv.z); o.w = f2bfu(fv.w);
    ((ushort4*)hb)[i] = o;
  }
}

// ---------------------------------------------------------------------------
__global__ __launch_bounds__(256) void deg_count(
    const int* __restrict__ idx_i, int* __restrict__ deg, int E)
{
  const int stride = gridDim.x * blockDim.x;
  for (int e = blockIdx.x * blockDim.x + threadIdx.x; e < E; e += stride)
    atomicAdd(&deg[idx_i[e]], 1);
}

// ---------------------------------------------------------------------------
#define SCAN_B 64
#define SCAN_T (SCAN_B * 256)

__global__ __launch_bounds__(256) void deg_tsum(
    const int* __restrict__ deg, int* __restrict__ tsum, int N, int C)
{
  const int g = blockIdx.x * blockDim.x + threadIdx.x;
  const int lo = g * C;
  const int hi = (lo + C < N) ? (lo + C) : N;
  int s = 0;
  for (int i = lo; i < hi; ++i) s += deg[i];
  tsum[g] = s;
}

__global__ __launch_bounds__(256) void scan_tsum(int* __restrict__ tsum)
{
  __shared__ int ps[256];
  const int t = threadIdx.x;
  const int per = SCAN_T / 256;
  const int lo = t * per;
  int s = 0;
  for (int i = 0; i < per; ++i) s += tsum[lo + i];
  ps[t] = s;
  __syncthreads();
  if (t == 0) {
    int a = 0;
    for (int i = 0; i < 256; ++i) { const int v = ps[i]; ps[i] = a; a += v; }
  }
  __syncthreads();
  int acc = ps[t];
  for (int i = 0; i < per; ++i) {
    const int v = tsum[lo + i];
    tsum[lo + i] = acc;
    acc += v;
  }
}

__global__ __launch_bounds__(256) void write_csr(
    const int* __restrict__ deg, const int* __restrict__ tpre,
    int* __restrict__ rowstart, int* __restrict__ cursor,
    float* __restrict__ counts, int N, int C)
{
  const int g = blockIdx.x * blockDim.x + threadIdx.x;
  const int lo = g * C;
  const int hi = (lo + C < N) ? (lo + C) : N;
  int acc = tpre[g];
  for (int i = lo; i < hi; ++i) {
    const int d = deg[i];
    rowstart[i] = acc;
    cursor[i] = acc;
    counts[i] = (float)d;
    acc += d;
  }
  if (hi == N) rowstart[N] = acc;
}

// ---------------------------------------------------------------------------
__global__ __launch_bounds__(256) void bucket_edges(
    const int* __restrict__ idx_i, const int* __restrict__ idx_j,
    int* __restrict__ cursor, int* __restrict__ iperm,
    int* __restrict__ jperm, int E)
{
  const int stride = gridDim.x * blockDim.x;
  for (int e = blockIdx.x * blockDim.x + threadIdx.x; e < E; e += stride) {
    const int ii = idx_i[e];
    const int pos = atomicAdd(&cursor[ii], 1);
    iperm[pos] = ii;
    jperm[pos] = idx_j[e];
  }
}

// ---------------------------------------------------------------------------
// F1 (CSR order): gather + geometry + M1 + RBF -> Filt[slot], dirb[slot]
// ---------------------------------------------------------------------------
__global__ __launch_bounds__(256) void edge_f1(
    const ushort_t* __restrict__ h_bf, const float* __restrict__ x,
    const int* __restrict__ iperm, const int* __restrict__ jperm,
    const float* __restrict__ W_in, const float* __restrict__ b_in,
    ushort_t* __restrict__ Filt, float* __restrict__ dirb, int E)
{
  const int tid = blockIdx.x * blockDim.x + threadIdx.x;
  const int wid = tid >> 6;
  const int lane = threadIdx.x & 63;
  const int nw = (gridDim.x * blockDim.x) >> 6;
  const int l15 = lane & 15;
  const int q = lane >> 4;

  v8s bfr[4][2];
  #pragma unroll
  for (int kc = 0; kc < 4; ++kc)
    #pragma unroll
    for (int nt = 0; nt < 2; ++nt)
      #pragma unroll
      for (int j = 0; j < 8; ++j) {
        const int k = kc * 32 + q * 8 + j;
        const int col = nt * 16 + l15;
        bfr[kc][nt][j] = (col < 20) ? f2bfs(W_in[k * 20 + col]) : (short)0;
      }
  float bin[2], mu[2];
  #pragma unroll
  for (int nt = 0; nt < 2; ++nt) {
    const int col = nt * 16 + l15;
    bin[nt] = (col < 20) ? b_in[col] : 0.0f;
    mu[nt] = MU0 + (float)col * DMU;
  }

  const int ntiles = (E + 15) >> 4;
  for (int t = wid; t < ntiles; t += nw) {
    const int row = t * 16 + l15;
    const int rowL = (row < E) ? row : (E - 1);
    const int ii = iperm[rowL];
    const int jj = jperm[rowL];

    v8s afr[4];
    afr[0] = *(const v8s*)(h_bf + (size_t)ii * 64 + q * 8);
    afr[1] = *(const v8s*)(h_bf + (size_t)ii * 64 + 32 + q * 8);
    afr[2] = *(const v8s*)(h_bf + (size_t)jj * 64 + q * 8);
    afr[3] = *(const v8s*)(h_bf + (size_t)jj * 64 + 32 + q * 8);

    float dval = 0.0f;
    if (lane < 16 && row < E) {
      const float rx = x[jj * 3 + 0] - x[ii * 3 + 0];
      const float ry = x[jj * 3 + 1] - x[ii * 3 + 1];
      const float rz = x[jj * 3 + 2] - x[ii * 3 + 2];
      const float d = sqrtf(rx * rx + ry * ry + rz * rz + EPSC);
      dval = d;
      const float inv = 1.0f / (d + EPSC);
      dirb[row * 3 + 0] = rx * inv;
      dirb[row * 3 + 1] = ry * inv;
      dirb[row * 3 + 2] = rz * inv;
    }

    v4f acc[2];
    #pragma unroll
    for (int nt = 0; nt < 2; ++nt) {
      v4f a = {0.f, 0.f, 0.f, 0.f};
      #pragma unroll
      for (int kc = 0; kc < 4; ++kc)
        a = __builtin_amdgcn_mfma_f32_16x16x32_bf16(afr[kc], bfr[kc][nt], a, 0, 0, 0);
      acc[nt] = a;
    }

    const int rowb = t * 16 + q * 4;
    float dr[4], edr[4];
    #pragma unroll
    for (int r = 0; r < 4; ++r) {
      dr[r] = __shfl(dval, q * 4 + r);
      edr[r] = __expf(-dr[r]);
    }
    #pragma unroll
    for (int nt = 0; nt < 2; ++nt) {
      const int col = nt * 16 + l15;
      #pragma unroll
      for (int r = 0; r < 4; ++r) {
        ushort_t ov;
        if (col < 20) {
          const float tt = edr[r] - mu[nt];
          ov = f2bfu((acc[nt][r] + bin[nt]) * __expf(-BETA * tt * tt));
        } else if (col == 20) {
          ov = f2bfu(dr[r]);
        } else {
          ov = 0;
        }
        if (rowb + r < E) Filt[(size_t)(rowb + r) * 32 + col] = ov;
      }
    }
  }
}

// ---------------------------------------------------------------------------
// F2 (CSR order): M2 + transpose + M3 -> heb[slot] + MFMA att epilogue
// ---------------------------------------------------------------------------
#define THS 72
__global__ __launch_bounds__(256) void edge_f2(
    const ushort_t* __restrict__ h_bf,
    const int* __restrict__ iperm, const int* __restrict__ jperm,
    const ushort_t* __restrict__ Filt,
    const float* __restrict__ W_h, const float* __restrict__ b_h,
    const float* __restrict__ W_out, const float* __restrict__ b_out,
    const float* __restrict__ W_att, const float* __restrict__ b_att,
    ushort_t* __restrict__ heb, float* __restrict__ expl,
    float* __restrict__ denom, int E)
{
  __shared__ ushort_t sB2[20 * 64 * 8];
  __shared__ ushort_t sB3[4 * 64 * 8];
  __shared__ ushort_t tH[4][16 * THS];

  const int tid = threadIdx.x;
  for (int idx = tid; idx < 20 * 64 * 8; idx += 256) {
    const int j = idx & 7;
    const int ln = (idx >> 3) & 63;
    const int f = idx >> 9;
    const int k = (f >> 2) * 32 + (ln >> 4) * 8 + j;
    const int col = (f & 3) * 16 + (ln & 15);
    sB2[idx] = (k < 149) ? f2bfu(W_h[k * 64 + col]) : (ushort_t)0;
  }
  for (int idx = tid; idx < 4 * 64 * 8; idx += 256) {
    const int j = idx & 7;
    const int ln = (idx >> 3) & 63;
    const int f = idx >> 9;
    const int k = (f >> 1) * 32 + (ln >> 4) * 8 + j;
    const int col = (f & 1) * 16 + (ln & 15);
    sB3[idx] = f2bfu(W_out[k * 32 + col]);
  }
  __syncthreads();

  const int gtid = blockIdx.x * blockDim.x + tid;
  const int wid = gtid >> 6;
  const int lane = tid & 63;
  const int w = tid >> 6;
  const int nw = (gridDim.x * blockDim.x) >> 6;
  const int l15 = lane & 15;
  const int q = lane >> 4;

  const ushort_t* b2l = sB2 + lane * 8;
  const ushort_t* b3l = sB3 + lane * 8;

  float bias2[4];
  #pragma unroll
  for (int nt = 0; nt < 4; ++nt) bias2[nt] = b_h[nt * 16 + l15];
  float bias3[2];
  #pragma unroll
  for (int nt = 0; nt < 2; ++nt) bias3[nt] = b_out[nt * 16 + l15];

  v8s battf;
  #pragma unroll
  for (int j = 0; j < 8; ++j)
    battf[j] = (l15 < 4) ? f2bfs(W_att[(q * 8 + j) * 4 + l15]) : (short)0;
  const float bav = (l15 < 4) ? b_att[l15] : 0.0f;

  const int ntiles = (E + 15) >> 4;

  int iiC = 0;
  v8s afr[5];
  if (wid < ntiles) {
    const int row0 = wid * 16 + l15;
    const int rowL0 = (row0 < E) ? row0 : (E - 1);
    iiC = iperm[rowL0];
    const int jj0 = jperm[rowL0];
    afr[0] = *(const v8s*)(h_bf + (size_t)iiC * 64 + q * 8);
    afr[1] = *(const v8s*)(h_bf + (size_t)iiC * 64 + 32 + q * 8);
    afr[2] = *(const v8s*)(h_bf + (size_t)jj0 * 64 + q * 8);
    afr[3] = *(const v8s*)(h_bf + (size_t)jj0 * 64 + 32 + q * 8);
    afr[4] = *(const v8s*)(Filt + (size_t)rowL0 * 32 + q * 8);
  }

  for (int t = wid; t < ntiles; t += nw) {
    const int tn = t + nw;
    int iiN = 0;
    v8s nfr[5];
    if (tn < ntiles) {
      const int rowN = tn * 16 + l15;
      const int rowLN = (rowN < E) ? rowN : (E - 1);
      iiN = iperm[rowLN];
      const int jjN = jperm[rowLN];
      nfr[0] = *(const v8s*)(h_bf + (size_t)iiN * 64 + q * 8);
      nfr[1] = *(const v8s*)(h_bf + (size_t)iiN * 64 + 32 + q * 8);
      nfr[2] = *(const v8s*)(h_bf + (size_t)jjN * 64 + q * 8);
      nfr[3] = *(const v8s*)(h_bf + (size_t)jjN * 64 + 32 + q * 8);
      nfr[4] = *(const v8s*)(Filt + (size_t)rowLN * 32 + q * 8);
    }

    v4f acc2[4];
    #pragma unroll
    for (int nt = 0; nt < 4; ++nt) {
      v4f a = {0.f, 0.f, 0.f, 0.f};
      #pragma unroll
      for (int kc = 0; kc < 5; ++kc) {
        const v8s bfrag = *(const v8s*)(b2l + (kc * 4 + nt) * 512);
        a = __builtin_amdgcn_mfma_f32_16x16x32_bf16(afr[kc], bfrag, a, 0, 0, 0);
      }
      acc2[nt] = a;
    }

    #pragma unroll
    for (int nt = 0; nt < 4; ++nt) {
      #pragma unroll
      for (int r = 0; r < 4; ++r)
        tH[w][(q * 4 + r) * THS + nt * 16 + l15] =
            f2bfu(siluf(acc2[nt][r] + bias2[nt]));
    }
    __builtin_amdgcn_wave_barrier();

    v8s af3[2];
    af3[0] = *(const v8s*)&tH[w][l15 * THS + q * 8];
    af3[1] = *(const v8s*)&tH[w][l15 * THS + 32 + q * 8];

    v4f acc3[2];
    #pragma unroll
    for (int nt = 0; nt < 2; ++nt) {
      v4f a = {0.f, 0.f, 0.f, 0.f};
      #pragma unroll
      for (int kc = 0; kc < 2; ++kc) {
        const v8s bfrag = *(const v8s*)(b3l + (kc * 2 + nt) * 512);
        a = __builtin_amdgcn_mfma_f32_16x16x32_bf16(af3[kc], bfrag, a, 0, 0, 0);
      }
      acc3[nt] = a;
    }
    __builtin_amdgcn_wave_barrier();

    const int rowb = t * 16 + q * 4;
    #pragma unroll
    for (int nt = 0; nt < 2; ++nt) {
      const int col = nt * 16 + l15;
      #pragma unroll
      for (int r = 0; r < 4; ++r) {
        const ushort_t hv = f2bfu(acc3[nt][r] + bias3[nt]);
        tH[w][(q * 4 + r) * THS + col] = hv;
        if (rowb + r < E) heb[(size_t)(rowb + r) * 32 + col] = hv;
      }
    }
    __builtin_amdgcn_wave_barrier();

    const v8s afA = *(const v8s*)&tH[w][l15 * THS + q * 8];
    v4f az = {0.f, 0.f, 0.f, 0.f};
    const v4f aacc = __builtin_amdgcn_mfma_f32_16x16x32_bf16(afA, battf, az, 0, 0, 0);

    int ii_r[4];
    #pragma unroll
    for (int r = 0; r < 4; ++r) ii_r[r] = __shfl(iiC, q * 4 + r);

    if (l15 < 4) {
      #pragma unroll
      for (int r = 0; r < 4; ++r) {
        if (rowb + r < E) {
          const float la = aacc[r] + bav;
          const float l = (la > 0.f) ? la : 2.0f * (__expf(0.5f * la) - 1.0f);
          const float ev = __expf(l);
          expl[(size_t)(rowb + r) * 4 + l15] = ev;
          atomAddF(&denom[ii_r[r] * 4 + l15], ev);
        }
      }
    }
    __builtin_amdgcn_wave_barrier();

    iiC = iiN;
    afr[0] = nfr[0]; afr[1] = nfr[1]; afr[2] = nfr[2];
    afr[3] = nfr[3]; afr[4] = nfr[4];
  }
}

// ---------------------------------------------------------------------------
// mix_kernel (CSR order)
// ---------------------------------------------------------------------------
__global__ __launch_bounds__(256) void mix_kernel(
    const ushort_t* __restrict__ heb, const int* __restrict__ iperm,
    const float* __restrict__ expl, const float* __restrict__ denom,
    const float* __restrict__ W_xmix, const float* __restrict__ w_vmix,
    ushort_t* __restrict__ mixE, float* __restrict__ pE, int E)
{
  const int tid = blockIdx.x * blockDim.x + threadIdx.x;
  const int wid = tid >> 6;
  const int lane = threadIdx.x & 63;
  const int nw = (gridDim.x * blockDim.x) >> 6;
  const int l15 = lane & 15;
  const int q = lane >> 4;

  v8s bfr[4][2];
  #pragma unroll
  for (int kc = 0; kc < 4; ++kc)
    #pragma unroll
    for (int nt = 0; nt < 2; ++nt)
      #pragma unroll
      for (int j = 0; j < 8; ++j) {
        const int k = kc * 32 + q * 8 + j;
        const int col = nt * 16 + l15;
        bfr[kc][nt][j] = f2bfs(W_xmix[k * 32 + col]);
      }
  float wv[2];
  wv[0] = w_vmix[l15];
  wv[1] = w_vmix[16 + l15];

  const int ntiles = (E + 15) >> 4;
  for (int t = wid; t < ntiles; t += nw) {
    const int row = t * 16 + l15;
    const int rowL = (row < E) ? row : (E - 1);
    const int ii = iperm[rowL];
    float att[4];
    #pragma unroll
    for (int hh = 0; hh < 4; ++hh)
      att[hh] = expl[(size_t)rowL * 4 + hh] / (denom[ii * 4 + hh] + EPSC);

    const v8s hech = *(const v8s*)(heb + (size_t)rowL * 32 + q * 8);
    float hef[8];
    #pragma unroll
    for (int j = 0; j < 8; ++j) hef[j] = bf2f((ushort_t)hech[j]);

    v8s afr[4];
    #pragma unroll
    for (int kc = 0; kc < 4; ++kc)
      #pragma unroll
      for (int j = 0; j < 8; ++j)
        afr[kc][j] = f2bfs(att[kc] * hef[j]);

    v4f acc[2];
    #pragma unroll
    for (int nt = 0; nt < 2; ++nt) {
      v4f a = {0.f, 0.f, 0.f, 0.f};
      #pragma unroll
      for (int kc = 0; kc < 4; ++kc)
        a = __builtin_amdgcn_mfma_f32_16x16x32_bf16(afr[kc], bfr[kc][nt], a, 0, 0, 0);
      acc[nt] = a;
    }

    const int rowb = t * 16 + q * 4;
    float pr[4];
    #pragma unroll
    for (int r = 0; r < 4; ++r) {
      const float m0 = tanhf(acc[0][r]);
      const float m1 = tanhf(acc[1][r]);
      if (rowb + r < E) {
        mixE[(size_t)(rowb + r) * 32 + l15] = f2bfu(m0);
        mixE[(size_t)(rowb + r) * 32 + 16 + l15] = f2bfu(m1);
      }
      pr[r] = m0 * wv[0] + m1 * wv[1];
    }
    #pragma unroll
    for (int r = 0; r < 4; ++r) {
      pr[r] += __shfl_xor(pr[r], 1);
      pr[r] += __shfl_xor(pr[r], 2);
      pr[r] += __shfl_xor(pr[r], 4);
      pr[r] += __shfl_xor(pr[r], 8);
      if (l15 == 0 && rowb + r < E) pE[rowb + r] = pr[r];
    }
  }
}

// ---------------------------------------------------------------------------
// node_reduce: wave per node, STREAMING reads (edge data in CSR order)
// ---------------------------------------------------------------------------
__global__ __launch_bounds__(256) void node_reduce(
    const int* __restrict__ rowstart,
    const ushort_t* __restrict__ heb, const ushort_t* __restrict__ mixE,
    const float* __restrict__ expl, const float* __restrict__ denom,
    const float* __restrict__ dirb, const float* __restrict__ pE,
    ushort_t* __restrict__ hsem, float* __restrict__ comb_sum,
    float* __restrict__ dv_sum, int N)
{
  const int tid = blockIdx.x * blockDim.x + threadIdx.x;
  const int wid = tid >> 6;
  const int lane = threadIdx.x & 63;
  const int nw = (gridDim.x * blockDim.x) >> 6;
  const int hh = lane >> 5;
  const int eb = lane & 31;

  for (int n = wid; n < N; n += nw) {
    const int s = rowstart[n];
    const int epd = rowstart[n + 1];
    float semA = 0.f, semB = 0.f;
    float cx = 0.f, cy = 0.f, cz = 0.f;
    float dvx = 0.f, dvy = 0.f, dvz = 0.f;
    for (int k = s; k < epd; ++k) {
      const float he = bf2f(heb[(size_t)k * 32 + eb]);
      const float ea = expl[(size_t)k * 4 + hh];
      const float ec = expl[(size_t)k * 4 + 2 + hh];
      semA += ea * he;
      semB += ec * he;
      const float dx = dirb[k * 3 + 0];
      const float dy = dirb[k * 3 + 1];
      const float dz = dirb[k * 3 + 2];
      if (lane < 32) {
        const float m = bf2f(mixE[(size_t)k * 32 + lane]);
        cx += dx * m; cy += dy * m; cz += dz * m;
      }
      if (lane == 0) {
        const float pe = pE[k];
        dvx += dx * pe; dvy += dy * pe; dvz += dz * pe;
      }
    }
    const float dA = denom[n * 4 + hh] + EPSC;
    const float dB = denom[n * 4 + 2 + hh] + EPSC;
    hsem[(size_t)n * 128 + lane] = f2bfu(semA / dA);
    hsem[(size_t)n * 128 + 64 + lane] = f2bfu(semB / dB);
    if (lane < 32) {
      comb_sum[(size_t)n * 96 + lane * 3 + 0] = cx;
      comb_sum[(size_t)n * 96 + lane * 3 + 1] = cy;
      comb_sum[(size_t)n * 96 + lane * 3 + 2] = cz;
    }
    if (lane == 0) {
      dv_sum[n * 3 + 0] = dvx;
      dv_sum[n * 3 + 1] = dvy;
      dv_sum[n * 3 + 2] = dvz;
    }
  }
}

// ---------------------------------------------------------------------------
// C1 (MFMA): spatial MLP (post1/post2) + node1 -> nh bf16 [N,128]
// ---------------------------------------------------------------------------
#define W1S 232
__global__ __launch_bounds__(256) void node_c1_mfma(
    const ushort_t* __restrict__ h_bf, const ushort_t* __restrict__ hsem,
    const float* __restrict__ comb_sum, const float* __restrict__ counts,
    const float* __restrict__ W_post1, const float* __restrict__ b_post1,
    const float* __restrict__ W_post2, const float* __restrict__ b_post2,
    const float* __restrict__ W_node1, const float* __restrict__ b_node1,
    ushort_t* __restrict__ nh_out, int N)
{
  __shared__ ushort_t sW1t[128 * W1S];
  __shared__ ushort_t tp[4][16 * THS];

  const int tid = threadIdx.x;
  for (int idx = tid; idx < 224 * 128; idx += 256) {
    const int k = idx >> 7;
    const int c = idx & 127;
    sW1t[c * W1S + k] = f2bfu(W_node1[idx]);
  }
  __syncthreads();

  const int lane = tid & 63;
  const int w = tid >> 6;
  const int l15 = lane & 15;
  const int q = lane >> 4;

  v8s bp1[4];
  #pragma unroll
  for (int nt = 0; nt < 4; ++nt)
    #pragma unroll
    for (int j = 0; j < 8; ++j)
      bp1[nt][j] = f2bfs(W_post1[(q * 8 + j) * 64 + nt * 16 + l15]);
  v8s bp2[2][2];
  #pragma unroll
  for (int kc = 0; kc < 2; ++kc)
    #pragma unroll
    for (int nt = 0; nt < 2; ++nt)
      #pragma unroll
      for (int j = 0; j < 8; ++j)
        bp2[kc][nt][j] = f2bfs(W_post2[(kc * 32 + q * 8 + j) * 32 + nt * 16 + l15]);
  float bb1[4];
  #pragma unroll
  for (int nt = 0; nt < 4; ++nt) bb1[nt] = b_post1[nt * 16 + l15];
  float bb2[2];
  #pragma unroll
  for (int nt = 0; nt < 2; ++nt) bb2[nt] = b_post2[nt * 16 + l15];
  float b1[8];
  #pragma unroll
  for (int nt = 0; nt < 8; ++nt) b1[nt] = b_node1[nt * 16 + l15];

  const int gw = blockIdx.x * 4 + w;
  const int nwv = gridDim.x * 4;
  const int ntiles = (N + 15) >> 4;

  for (int t = gw; t < ntiles; t += nwv) {
    const int row = t * 16 + l15;
    const int rowL = (row < N) ? row : (N - 1);

    const float inv = 1.0f / fmaxf(counts[rowL], 1.0f);
    const float4* cs = (const float4*)(comb_sum + (size_t)rowL * 96 + q * 24);
    float cf[24];
    #pragma unroll
    for (int b = 0; b < 6; ++b) {
      const float4 cv = cs[b];
      cf[b * 4 + 0] = cv.x; cf[b * 4 + 1] = cv.y;
      cf[b * 4 + 2] = cv.z; cf[b * 4 + 3] = cv.w;
    }
    v8s a1;
    #pragma unroll
    for (int j = 0; j < 8; ++j) {
      const float vx = cf[j * 3 + 0] * inv;
      const float vy = cf[j * 3 + 1] * inv;
      const float vz = cf[j * 3 + 2] * inv;
      a1[j] = f2bfs(vx * vx + vy * vy + vz * vz);
    }

    v4f p1[4];
    #pragma unroll
    for (int nt = 0; nt < 4; ++nt) {
      v4f a = {0.f, 0.f, 0.f, 0.f};
      p1[nt] = __builtin_amdgcn_mfma_f32_16x16x32_bf16(a1, bp1[nt], a, 0, 0, 0);
    }
    #pragma unroll
    for (int nt = 0; nt < 4; ++nt)
      #pragma unroll
      for (int r = 0; r < 4; ++r)
        tp[w][(q * 4 + r) * THS + nt * 16 + l15] =
            f2bfu(siluf(p1[nt][r] + bb1[nt]));
    __builtin_amdgcn_wave_barrier();

    v8s a2[2];
    a2[0] = *(const v8s*)&tp[w][l15 * THS + q * 8];
    a2[1] = *(const v8s*)&tp[w][l15 * THS + 32 + q * 8];

    v4f p2[2];
    #pragma unroll
    for (int nt = 0; nt < 2; ++nt) {
      v4f a = {0.f, 0.f, 0.f, 0.f};
      #pragma unroll
      for (int kc = 0; kc < 2; ++kc)
        a = __builtin_amdgcn_mfma_f32_16x16x32_bf16(a2[kc], bp2[kc][nt], a, 0, 0, 0);
      p2[nt] = a;
    }
    __builtin_amdgcn_wave_barrier();
    #pragma unroll
    for (int nt = 0; nt < 2; ++nt)
      #pragma unroll
      for (int r = 0; r < 4; ++r)
        tp[w][(q * 4 + r) * THS + nt * 16 + l15] =
            f2bfu(siluf(p2[nt][r] + bb2[nt]));
    __builtin_amdgcn_wave_barrier();

    v8s af[7];
    af[0] = *(const v8s*)(h_bf + (size_t)rowL * 64 + q * 8);
    af[1] = *(const v8s*)(h_bf + (size_t)rowL * 64 + 32 + q * 8);
    #pragma unroll
    for (int kc = 0; kc < 4; ++kc)
      af[2 + kc] = *(const v8s*)(hsem + (size_t)rowL * 128 + kc * 32 + q * 8);
    af[6] = *(const v8s*)&tp[w][l15 * THS + q * 8];

    v4f acc[8];
    #pragma unroll
    for (int nt = 0; nt < 8; ++nt) acc[nt] = (v4f){0.f, 0.f, 0.f, 0.f};
    #pragma unroll
    for (int kc = 0; kc < 7; ++kc) {
      #pragma unroll
      for (int nt = 0; nt < 8; ++nt) {
        const v8s bfrag =
            *(const v8s*)&sW1t[(nt * 16 + l15) * W1S + kc * 32 + q * 8];
        acc[nt] = __builtin_amdgcn_mfma_f32_16x16x32_bf16(af[kc], bfrag, acc[nt], 0, 0, 0);
      }
    }

    const int rowb = t * 16 + q * 4;
    #pragma unroll
    for (int nt = 0; nt < 8; ++nt) {
      #pragma unroll
      for (int r = 0; r < 4; ++r)
        if (rowb + r < N)
          nh_out[(size_t)(rowb + r) * 128 + nt * 16 + l15] =
              f2bfu(siluf(acc[nt][r] + b1[nt]));
    }
  }
}

// ---------------------------------------------------------------------------
// C2 (MFMA): node2 ([N,128]x[128,64], residual) + vel1 ([N,64]x[64,32]) +
// gate + v/x update.  Wave per 16-node tile; W fragments in LDS.
// ---------------------------------------------------------------------------
__global__ __launch_bounds__(256) void node_c2_mfma(
    const float* __restrict__ h, const float* __restrict__ x,
    const float* __restrict__ v, const ushort_t* __restrict__ nh,
    const float* __restrict__ dv_sum, const float* __restrict__ counts,
    const float* __restrict__ W_node2, const float* __restrict__ b_node2,
    const float* __restrict__ W_vel1, const float* __restrict__ b_vel1,
    const float* __restrict__ W_vel2,
    float* __restrict__ out, int N)
{
  __shared__ ushort_t sW2[16 * 64 * 8];   // 16 KB: W_node2 fragments (kc,nt)
  __shared__ ushort_t sWv[4 * 64 * 8];    // 4 KB: W_vel1 fragments
  __shared__ ushort_t tH[4][16 * THS];    // 9 KB: per-wave transpose tile
  __shared__ float sg[4][16];             // per-wave gates

  const int tid = threadIdx.x;
  for (int idx = tid; idx < 16 * 64 * 8; idx += 256) {
    const int j = idx & 7;
    const int ln = (idx >> 3) & 63;
    const int f = idx >> 9;               // 0..15 = kc*4+nt
    const int k = (f >> 2) * 32 + (ln >> 4) * 8 + j;
    const int col = (f & 3) * 16 + (ln & 15);
    sW2[idx] = f2bfu(W_node2[k * 64 + col]);
  }
  for (int idx = tid; idx < 4 * 64 * 8; idx += 256) {
    const int j = idx & 7;
    const int ln = (idx >> 3) & 63;
    const int f = idx >> 9;               // 0..3 = kc*2+nt
    const int k = (f >> 1) * 32 + (ln >> 4) * 8 + j;
    const int col = (f & 1) * 16 + (ln & 15);
    sWv[idx] = f2bfu(W_vel1[k * 32 + col]);
  }
  __syncthreads();

  const int lane = tid & 63;
  const int w = tid >> 6;
  const int l15 = lane & 15;
  const int q = lane >> 4;

  const ushort_t* w2l = sW2 + lane * 8;
  const ushort_t* wvl = sWv + lane * 8;

  float b2[4];
  #pragma unroll
  for (int nt = 0; nt < 4; ++nt) b2[nt] = b_node2[nt * 16 + l15];
  float bv[2];
  #pragma unroll
  for (int nt = 0; nt < 2; ++nt) bv[nt] = b_vel1[nt * 16 + l15];
  float wv2[2];
  #pragma unroll
  for (int nt = 0; nt < 2; ++nt) wv2[nt] = W_vel2[nt * 16 + l15];

  const int gw = blockIdx.x * 4 + w;
  const int nwv = gridDim.x * 4;
  const int ntiles = (N + 15) >> 4;

  for (int t = gw; t < ntiles; t += nwv) {
    const int row = t * 16 + l15;
    const int rowL = (row < N) ? row : (N - 1);

    v8s af[4];
    #pragma unroll
    for (int kc = 0; kc < 4; ++kc)
      af[kc] = *(const v8s*)(nh + (size_t)rowL * 128 + kc * 32 + q * 8);

    v4f acc[4];
    #pragma unroll
    for (int nt = 0; nt < 4; ++nt) {
      v4f a = {0.f, 0.f, 0.f, 0.f};
      #pragma unroll
      for (int kc = 0; kc < 4; ++kc) {
        const v8s bfrag = *(const v8s*)(w2l + (kc * 4 + nt) * 512);
        a = __builtin_amdgcn_mfma_f32_16x16x32_bf16(af[kc], bfrag, a, 0, 0, 0);
      }
      acc[nt] = a;
    }

    // hu = h + silu(acc+b2): write fp32 out + bf16 into transpose tile
    const int rowb = t * 16 + q * 4;
    #pragma unroll
    for (int nt = 0; nt < 4; ++nt) {
      const int col = nt * 16 + l15;
      #pragma unroll
      for (int r = 0; r < 4; ++r) {
        const int n = rowb + r;
        if (n < N) {
          const float hu = h[(size_t)n * 64 + col] + siluf(acc[nt][r] + b2[nt]);
          out[(size_t)n * 64 + col] = hu;
          tH[w][(q * 4 + r) * THS + col] = f2bfu(hu);
        }
      }
    }
    __builtin_amdgcn_wave_barrier();

    // vel1: [16,64] x [64,32]
    v8s a2[2];
    a2[0] = *(const v8s*)&tH[w][l15 * THS + q * 8];
    a2[1] = *(const v8s*)&tH[w][l15 * THS + 32 + q * 8];
    v4f av[2];
    #pragma unroll
    for (int nt = 0; nt < 2; ++nt) {
      v4f a = {0.f, 0.f, 0.f, 0.f};
      #pragma unroll
      for (int kc = 0; kc < 2; ++kc) {
        const v8s bfrag = *(const v8s*)(wvl + (kc * 2 + nt) * 512);
        a = __builtin_amdgcn_mfma_f32_16x16x32_bf16(a2[kc], bfrag, a, 0, 0, 0);
      }
      av[nt] = a;
    }

    // gate logit: p = sum_col silu(av+bv)*wv2, reduce over 16 l15 lanes
    #pragma unroll
    for (int r = 0; r < 4; ++r) {
      float pr = siluf(av[0][r] + bv[0]) * wv2[0] +
                 siluf(av[1][r] + bv[1]) * wv2[1];
      pr += __shfl_xor(pr, 1);
      pr += __shfl_xor(pr, 2);
      pr += __shfl_xor(pr, 4);
      pr += __shfl_xor(pr, 8);
      if (l15 == 0) sg[w][q * 4 + r] = 2.0f / (1.0f + __expf(-pr));
    }
    __builtin_amdgcn_wave_barrier();

    // v/x update: lanes < 48 -> 16 rows x 3 comps
    if (lane < 48) {
      const int rr = lane / 3;
      const int c = lane % 3;
      const int n = t * 16 + rr;
      if (n < N) {
        const float gate = sg[w][rr];
        const float cnt = fmaxf(counts[n], 1.0f);
        const float dv = dv_sum[n * 3 + c] / cnt;
        const float vu = gate * v[n * 3 + c] + dv;
        out[(size_t)N * 64 + (size_t)n * 3 + c] = x[n * 3 + c] + vu;
        out[(size_t)N * 64 + (size_t)N * 3 + (size_t)n * 3 + c] = vu;
      }
    }
    __builtin_amdgcn_wave_barrier();
  }
}

// ---------------------------------------------------------------------------
extern "C" void kernel_launch(void* const* d_in, const int* in_sizes, int n_in,
                              void* d_out, int out_size, void* d_ws, size_t ws_size,
                              hipStream_t stream) {
  const float* h   = (const float*)d_in[0];
  const float* x   = (const float*)d_in[1];
  const float* v   = (const float*)d_in[2];
  const int* idx_i = (const int*)d_in[3];
  const int* idx_j = (const int*)d_in[4];
  const float* W_edge_in  = (const float*)d_in[5];
  const float* b_edge_in  = (const float*)d_in[6];
  const float* W_edge_h   = (const float*)d_in[7];
  const float* b_edge_h   = (const float*)d_in[8];
  const float* W_edge_out = (const float*)d_in[9];
  const float* b_edge_out = (const float*)d_in[10];
  const float* W_att      = (const float*)d_in[11];
  const float* b_att      = (const float*)d_in[12];
  const float* W_x_mix    = (const float*)d_in[13];
  const float* W_node1    = (const float*)d_in[14];
  const float* b_node1    = (const float*)d_in[15];
  const float* W_node2    = (const float*)d_in[16];
  const float* b_node2    = (const float*)d_in[17];
  const float* W_post1    = (const float*)d_in[18];
  const float* b_post1    = (const float*)d_in[19];
  const float* W_post2    = (const float*)d_in[20];
  const float* b_post2    = (const float*)d_in[21];
  const float* W_vel1     = (const float*)d_in[22];
  const float* b_vel1     = (const float*)d_in[23];
  const float* W_vel2     = (const float*)d_in[24];
  const float* w_v_mix    = (const float*)d_in[25];

  const int E = in_sizes[3];
  const int N = in_sizes[0] / DA;

  float* ws = (float*)d_ws;
  size_t off = 0;
  float* denom    = ws + off; off += (size_t)N * 4;     // zeroed
  int*   deg      = (int*)(ws + off); off += (size_t)N; // zeroed
  const size_t zeroBytes = off * sizeof(float);
  float* counts   = ws + off; off += (size_t)N;
  int*   rowstart = (int*)(ws + off); off += (size_t)N + 4;
  int*   cursor   = (int*)(ws + off); off += (size_t)N;
  int*   tsum     = (int*)(ws + off); off += (size_t)SCAN_T;
  int*   iperm    = (int*)(ws + off); off += (size_t)E;
  int*   jperm    = (int*)(ws + off); off += (size_t)E;
  float* pE       = ws + off; off += (size_t)E;
  float* expl     = ws + off; off += (size_t)E * 4;
  float* dirb     = ws + off; off += (size_t)E * 3;
  float* hsemR    = ws + off; off += (size_t)N * 64;    // hsem bf16 [N,128]
  float* comb_sum = ws + off; off += (size_t)N * 96;
  float* dv_sum   = ws + off; off += (size_t)N * 4;
  float* hbfR     = ws + off; off += (size_t)N * 32;    // h_bf bf16 [N,64]
  float* fltR     = ws + off; off += (size_t)E * 16;    // Filt / mixE / nh
  float* hebR     = ws + off; off += (size_t)E * 16;    // heb bf16 [E,32]

  ushort_t* h_bf = (ushort_t*)hbfR;
  ushort_t* hsem = (ushort_t*)hsemR;
  ushort_t* Filt = (ushort_t*)fltR;
  ushort_t* heb  = (ushort_t*)hebR;
  ushort_t* mixE = (ushort_t*)fltR;  // aliases Filt (dead after edge_f2)
  ushort_t* nh   = (ushort_t*)fltR;  // aliases mixE (dead after node_reduce)

  hipMemsetAsync(d_ws, 0, zeroBytes, stream);

  {
    const int n4 = (N * 64) / 4;
    cast_h<<<(n4 + 255) / 256, 256, 0, stream>>>(h, h_bf, n4);
  }
  deg_count<<<512, 256, 0, stream>>>(idx_i, deg, E);
  {
    const int C = (N + SCAN_T - 1) / SCAN_T;
    deg_tsum<<<SCAN_B, 256, 0, stream>>>(deg, tsum, N, C);
    scan_tsum<<<1, 256, 0, stream>>>(tsum);
    write_csr<<<SCAN_B, 256, 0, stream>>>(deg, tsum, rowstart, cursor, counts, N, C);
  }
  bucket_edges<<<512, 256, 0, stream>>>(idx_i, idx_j, cursor, iperm, jperm, E);
  edge_f1<<<1024, 256, 0, stream>>>(h_bf, x, iperm, jperm, W_edge_in,
                                    b_edge_in, Filt, dirb, E);
  edge_f2<<<1024, 256, 0, stream>>>(h_bf, iperm, jperm, Filt, W_edge_h,
                                    b_edge_h, W_edge_out, b_edge_out,
                                    W_att, b_att, heb, expl, denom, E);
  mix_kernel<<<1024, 256, 0, stream>>>(heb, iperm, expl, denom, W_x_mix,
                                       w_v_mix, mixE, pE, E);
  node_reduce<<<2048, 256, 0, stream>>>(rowstart, heb, mixE, expl, denom,
                                        dirb, pE, hsem, comb_sum, dv_sum, N);
  node_c1_mfma<<<512, 256, 0, stream>>>(
      h_bf, hsem, comb_sum, counts, W_post1, b_post1, W_post2, b_post2,
      W_node1, b_node1, nh, N);
  node_c2_mfma<<<512, 256, 0, stream>>>(
      h, x, v, nh, dv_sum, counts, W_node2, b_node2, W_vel1, b_vel1, W_vel2,
      (float*)d_out, N);
}

// Round 11
// 406.195 us; speedup vs baseline: 6.7300x; 1.0093x over previous
//
#include <hip/hip_runtime.h>
#include <math.h>

#define DA 64
#define NODEIN_DIM 224
#define EPSC 1e-8f

typedef short v8s __attribute__((ext_vector_type(8)));
typedef float v4f __attribute__((ext_vector_type(4)));
typedef unsigned short ushort_t;

__device__ __forceinline__ float siluf(float v) { return v / (1.0f + __expf(-v)); }

__device__ __forceinline__ void atomAddF(float* p, float v) {
#if defined(__HIP_DEVICE_COMPILE__)
  unsafeAtomicAdd(p, v);
#else
  atomicAdd(p, v);
#endif
}

__device__ __forceinline__ unsigned short f2bfu(float f) {
  union { float f; unsigned u; } v; v.f = f;
  unsigned r = v.u + 0x7fffu + ((v.u >> 16) & 1u);
  return (unsigned short)(r >> 16);
}
__device__ __forceinline__ short f2bfs(float f) { return (short)f2bfu(f); }
__device__ __forceinline__ float bf2f(ushort_t s) {
  union { unsigned u; float f; } v; v.u = ((unsigned)s) << 16; return v.f;
}

#define MU0 0.60653065971263342f
#define DMU ((1.0f - 0.60653065971263342f) / 19.0f)
#define BETA ((float)(1.0 / (0.039346934028736658 * 0.039346934028736658)))

// ---------------------------------------------------------------------------
__global__ __launch_bounds__(256) void cast_h(
    const float* __restrict__ hsrc, ushort_t* __restrict__ hb, int n4)
{
  const int i = blockIdx.x * blockDim.x + threadIdx.x;
  if (i < n4) {
    const float4 fv = ((const float4*)hsrc)[i];
    ushort4 o;
    o.x = f2bfu(fv.x); o.y = f2bfu(fv.y); o.z = f2bfu(fv.z); o.w = f2bfu(fv.w);
    ((ushort4*)hb)[i] = o;
  }
}

// ---------------------------------------------------------------------------
__global__ __launch_bounds__(256) void deg_count(
    const int* __restrict__ idx_i, int* __restrict__ deg, int E)
{
  const int stride = gridDim.x * blockDim.x;
  for (int e = blockIdx.x * blockDim.x + threadIdx.x; e < E; e += stride)
    atomicAdd(&deg[idx_i[e]], 1);
}

// ---------------------------------------------------------------------------
#define SCAN_B 64
#define SCAN_T (SCAN_B * 256)

__global__ __launch_bounds__(256) void deg_tsum(
    const int* __restrict__ deg, int* __restrict__ tsum, int N, int C)
{
  const int g = blockIdx.x * blockDim.x + threadIdx.x;
  const int lo = g * C;
  const int hi = (lo + C < N) ? (lo + C) : N;
  int s = 0;
  for (int i = lo; i < hi; ++i) s += deg[i];
  tsum[g] = s;
}

__global__ __launch_bounds__(256) void scan_tsum(int* __restrict__ tsum)
{
  __shared__ int ps[256];
  const int t = threadIdx.x;
  const int per = SCAN_T / 256;
  const int lo = t * per;
  int s = 0;
  for (int i = 0; i < per; ++i) s += tsum[lo + i];
  ps[t] = s;
  __syncthreads();
  if (t == 0) {
    int a = 0;
    for (int i = 0; i < 256; ++i) { const int v = ps[i]; ps[i] = a; a += v; }
  }
  __syncthreads();
  int acc = ps[t];
  for (int i = 0; i < per; ++i) {
    const int v = tsum[lo + i];
    tsum[lo + i] = acc;
    acc += v;
  }
}

__global__ __launch_bounds__(256) void write_csr(
    const int* __restrict__ deg, const int* __restrict__ tpre,
    int* __restrict__ rowstart, int* __restrict__ cursor,
    float* __restrict__ counts, int N, int C)
{
  const int g = blockIdx.x * blockDim.x + threadIdx.x;
  const int lo = g * C;
  const int hi = (lo + C < N) ? (lo + C) : N;
  int acc = tpre[g];
  for (int i = lo; i < hi; ++i) {
    const int d = deg[i];
    rowstart[i] = acc;
    cursor[i] = acc;
    counts[i] = (float)d;
    acc += d;
  }
  if (hi == N) rowstart[N] = acc;
}

// ---------------------------------------------------------------------------
__global__ __launch_bounds__(256) void bucket_edges(
    const int* __restrict__ idx_i, const int* __restrict__ idx_j,
    int* __restrict__ cursor, int* __restrict__ iperm,
    int* __restrict__ jperm, int E)
{
  const int stride = gridDim.x * blockDim.x;
  for (int e = blockIdx.x * blockDim.x + threadIdx.x; e < E; e += stride) {
    const int ii = idx_i[e];
    const int pos = atomicAdd(&cursor[ii], 1);
    iperm[pos] = ii;
    jperm[pos] = idx_j[e];
  }
}

// ---------------------------------------------------------------------------
// F12 (CSR order): gather + geometry + M1/RBF (via tH transpose) + M2 +
// transpose + M3 -> heb[slot] + MFMA att epilogue.  All edge-MLP weights
// staged as LDS fragments; 2-deep pipeline on the 4 random h_bf gathers.
// ---------------------------------------------------------------------------
#define THS 72
__global__ __launch_bounds__(256) void edge_f12(
    const ushort_t* __restrict__ h_bf, const float* __restrict__ x,
    const int* __restrict__ iperm, const int* __restrict__ jperm,
    const float* __restrict__ W_in, const float* __restrict__ b_in,
    const float* __restrict__ W_h, const float* __restrict__ b_h,
    const float* __restrict__ W_out, const float* __restrict__ b_out,
    const float* __restrict__ W_att, const float* __restrict__ b_att,
    float* __restrict__ dirb, ushort_t* __restrict__ heb,
    float* __restrict__ expl, float* __restrict__ denom, int E)
{
  __shared__ ushort_t sB1[8 * 512];    // 8 KB: W_in fragments (kc*2+nt)
  __shared__ ushort_t sB2[20 * 512];   // 20 KB: W_h fragments (kc*4+nt)
  __shared__ ushort_t sB3[4 * 512];    // 4 KB: W_out fragments
  __shared__ ushort_t tH[4][16 * THS]; // 9 KB: per-wave transpose tile

  const int tid = threadIdx.x;
  for (int idx = tid; idx < 8 * 512; idx += 256) {
    const int j = idx & 7;
    const int ln = (idx >> 3) & 63;
    const int f = idx >> 9;               // kc*2+nt
    const int k = (f >> 1) * 32 + (ln >> 4) * 8 + j;
    const int col = (f & 1) * 16 + (ln & 15);
    sB1[idx] = (col < 20) ? f2bfu(W_in[k * 20 + col]) : (ushort_t)0;
  }
  for (int idx = tid; idx < 20 * 512; idx += 256) {
    const int j = idx & 7;
    const int ln = (idx >> 3) & 63;
    const int f = idx >> 9;               // kc*4+nt
    const int k = (f >> 2) * 32 + (ln >> 4) * 8 + j;
    const int col = (f & 3) * 16 + (ln & 15);
    sB2[idx] = (k < 149) ? f2bfu(W_h[k * 64 + col]) : (ushort_t)0;
  }
  for (int idx = tid; idx < 4 * 512; idx += 256) {
    const int j = idx & 7;
    const int ln = (idx >> 3) & 63;
    const int f = idx >> 9;               // kc*2+nt
    const int k = (f >> 1) * 32 + (ln >> 4) * 8 + j;
    const int col = (f & 1) * 16 + (ln & 15);
    sB3[idx] = f2bfu(W_out[k * 32 + col]);
  }
  __syncthreads();

  const int gtid = blockIdx.x * blockDim.x + tid;
  const int wid = gtid >> 6;
  const int lane = tid & 63;
  const int w = tid >> 6;
  const int nw = (gridDim.x * blockDim.x) >> 6;
  const int l15 = lane & 15;
  const int q = lane >> 4;

  const ushort_t* b1l = sB1 + lane * 8;
  const ushort_t* b2l = sB2 + lane * 8;
  const ushort_t* b3l = sB3 + lane * 8;

  float bin[2], mu[2];
  #pragma unroll
  for (int nt = 0; nt < 2; ++nt) {
    const int col = nt * 16 + l15;
    bin[nt] = (col < 20) ? b_in[col] : 0.0f;
    mu[nt] = MU0 + (float)col * DMU;
  }
  float bias2[4];
  #pragma unroll
  for (int nt = 0; nt < 4; ++nt) bias2[nt] = b_h[nt * 16 + l15];
  float bias3[2];
  #pragma unroll
  for (int nt = 0; nt < 2; ++nt) bias3[nt] = b_out[nt * 16 + l15];

  v8s battf;
  #pragma unroll
  for (int j = 0; j < 8; ++j)
    battf[j] = (l15 < 4) ? f2bfs(W_att[(q * 8 + j) * 4 + l15]) : (short)0;
  const float bav = (l15 < 4) ? b_att[l15] : 0.0f;

  const int ntiles = (E + 15) >> 4;

  // prime the pipeline (4 h_bf gathers; Filt gather is gone)
  int iiC = 0, jjC = 0;
  v8s afr[4];
  if (wid < ntiles) {
    const int row0 = wid * 16 + l15;
    const int rowL0 = (row0 < E) ? row0 : (E - 1);
    iiC = iperm[rowL0];
    jjC = jperm[rowL0];
    afr[0] = *(const v8s*)(h_bf + (size_t)iiC * 64 + q * 8);
    afr[1] = *(const v8s*)(h_bf + (size_t)iiC * 64 + 32 + q * 8);
    afr[2] = *(const v8s*)(h_bf + (size_t)jjC * 64 + q * 8);
    afr[3] = *(const v8s*)(h_bf + (size_t)jjC * 64 + 32 + q * 8);
  }

  for (int t = wid; t < ntiles; t += nw) {
    const int tn = t + nw;
    int iiN = 0, jjN = 0;
    v8s nfr[4];
    if (tn < ntiles) {
      const int rowN = tn * 16 + l15;
      const int rowLN = (rowN < E) ? rowN : (E - 1);
      iiN = iperm[rowLN];
      jjN = jperm[rowLN];
      nfr[0] = *(const v8s*)(h_bf + (size_t)iiN * 64 + q * 8);
      nfr[1] = *(const v8s*)(h_bf + (size_t)iiN * 64 + 32 + q * 8);
      nfr[2] = *(const v8s*)(h_bf + (size_t)jjN * 64 + q * 8);
      nfr[3] = *(const v8s*)(h_bf + (size_t)jjN * 64 + 32 + q * 8);
    }

    // geometry (lanes 0-15 own rows 0-15 of the tile)
    const int row = t * 16 + l15;
    float dval = 0.0f;
    if (lane < 16 && row < E) {
      const float rx = x[jjC * 3 + 0] - x[iiC * 3 + 0];
      const float ry = x[jjC * 3 + 1] - x[iiC * 3 + 1];
      const float rz = x[jjC * 3 + 2] - x[iiC * 3 + 2];
      const float d = sqrtf(rx * rx + ry * ry + rz * rz + EPSC);
      dval = d;
      const float inv = 1.0f / (d + EPSC);
      dirb[row * 3 + 0] = rx * inv;
      dirb[row * 3 + 1] = ry * inv;
      dirb[row * 3 + 2] = rz * inv;
    }

    // M1: [16,128] x W_in
    v4f acc1[2];
    #pragma unroll
    for (int nt = 0; nt < 2; ++nt) {
      v4f a = {0.f, 0.f, 0.f, 0.f};
      #pragma unroll
      for (int kc = 0; kc < 4; ++kc) {
        const v8s bfrag = *(const v8s*)(b1l + (kc * 2 + nt) * 512);
        a = __builtin_amdgcn_mfma_f32_16x16x32_bf16(afr[kc], bfrag, a, 0, 0, 0);
      }
      acc1[nt] = a;
    }

    // RBF epilogue -> tH (C-layout), col 20 = d, 21-31 = 0
    float dr[4], edr[4];
    #pragma unroll
    for (int r = 0; r < 4; ++r) {
      dr[r] = __shfl(dval, q * 4 + r);
      edr[r] = __expf(-dr[r]);
    }
    #pragma unroll
    for (int nt = 0; nt < 2; ++nt) {
      const int col = nt * 16 + l15;
      #pragma unroll
      for (int r = 0; r < 4; ++r) {
        ushort_t ov;
        if (col < 20) {
          const float tt = edr[r] - mu[nt];
          ov = f2bfu((acc1[nt][r] + bin[nt]) * __expf(-BETA * tt * tt));
        } else if (col == 20) {
          ov = f2bfu(dr[r]);
        } else {
          ov = 0;
        }
        tH[w][(q * 4 + r) * THS + col] = ov;
      }
    }
    __builtin_amdgcn_wave_barrier();

    // filt A-fragment (k-chunk 4 of M2)
    const v8s afr4 = *(const v8s*)&tH[w][l15 * THS + q * 8];
    __builtin_amdgcn_wave_barrier();

    // M2: [16,160] x W_h
    v4f acc2[4];
    #pragma unroll
    for (int nt = 0; nt < 4; ++nt) {
      v4f a = {0.f, 0.f, 0.f, 0.f};
      #pragma unroll
      for (int kc = 0; kc < 4; ++kc) {
        const v8s bfrag = *(const v8s*)(b2l + (kc * 4 + nt) * 512);
        a = __builtin_amdgcn_mfma_f32_16x16x32_bf16(afr[kc], bfrag, a, 0, 0, 0);
      }
      const v8s bfrag4 = *(const v8s*)(b2l + (4 * 4 + nt) * 512);
      a = __builtin_amdgcn_mfma_f32_16x16x32_bf16(afr4, bfrag4, a, 0, 0, 0);
      acc2[nt] = a;
    }

    #pragma unroll
    for (int nt = 0; nt < 4; ++nt) {
      #pragma unroll
      for (int r = 0; r < 4; ++r)
        tH[w][(q * 4 + r) * THS + nt * 16 + l15] =
            f2bfu(siluf(acc2[nt][r] + bias2[nt]));
    }
    __builtin_amdgcn_wave_barrier();

    v8s af3[2];
    af3[0] = *(const v8s*)&tH[w][l15 * THS + q * 8];
    af3[1] = *(const v8s*)&tH[w][l15 * THS + 32 + q * 8];

    v4f acc3[2];
    #pragma unroll
    for (int nt = 0; nt < 2; ++nt) {
      v4f a = {0.f, 0.f, 0.f, 0.f};
      #pragma unroll
      for (int kc = 0; kc < 2; ++kc) {
        const v8s bfrag = *(const v8s*)(b3l + (kc * 2 + nt) * 512);
        a = __builtin_amdgcn_mfma_f32_16x16x32_bf16(af3[kc], bfrag, a, 0, 0, 0);
      }
      acc3[nt] = a;
    }
    __builtin_amdgcn_wave_barrier();

    const int rowb = t * 16 + q * 4;
    #pragma unroll
    for (int nt = 0; nt < 2; ++nt) {
      const int col = nt * 16 + l15;
      #pragma unroll
      for (int r = 0; r < 4; ++r) {
        const ushort_t hv = f2bfu(acc3[nt][r] + bias3[nt]);
        tH[w][(q * 4 + r) * THS + col] = hv;
        if (rowb + r < E) heb[(size_t)(rowb + r) * 32 + col] = hv;
      }
    }
    __builtin_amdgcn_wave_barrier();

    // att via MFMA
    const v8s afA = *(const v8s*)&tH[w][l15 * THS + q * 8];
    v4f az = {0.f, 0.f, 0.f, 0.f};
    const v4f aacc = __builtin_amdgcn_mfma_f32_16x16x32_bf16(afA, battf, az, 0, 0, 0);

    int ii_r[4];
    #pragma unroll
    for (int r = 0; r < 4; ++r) ii_r[r] = __shfl(iiC, q * 4 + r);

    if (l15 < 4) {
      #pragma unroll
      for (int r = 0; r < 4; ++r) {
        if (rowb + r < E) {
          const float la = aacc[r] + bav;
          const float l = (la > 0.f) ? la : 2.0f * (__expf(0.5f * la) - 1.0f);
          const float ev = __expf(l);
          expl[(size_t)(rowb + r) * 4 + l15] = ev;
          atomAddF(&denom[ii_r[r] * 4 + l15], ev);
        }
      }
    }
    __builtin_amdgcn_wave_barrier();

    iiC = iiN; jjC = jjN;
    afr[0] = nfr[0]; afr[1] = nfr[1]; afr[2] = nfr[2]; afr[3] = nfr[3];
  }
}

// ---------------------------------------------------------------------------
// mix_kernel (CSR order)
// ---------------------------------------------------------------------------
__global__ __launch_bounds__(256) void mix_kernel(
    const ushort_t* __restrict__ heb, const int* __restrict__ iperm,
    const float* __restrict__ expl, const float* __restrict__ denom,
    const float* __restrict__ W_xmix, const float* __restrict__ w_vmix,
    ushort_t* __restrict__ mixE, float* __restrict__ pE, int E)
{
  const int tid = blockIdx.x * blockDim.x + threadIdx.x;
  const int wid = tid >> 6;
  const int lane = threadIdx.x & 63;
  const int nw = (gridDim.x * blockDim.x) >> 6;
  const int l15 = lane & 15;
  const int q = lane >> 4;

  v8s bfr[4][2];
  #pragma unroll
  for (int kc = 0; kc < 4; ++kc)
    #pragma unroll
    for (int nt = 0; nt < 2; ++nt)
      #pragma unroll
      for (int j = 0; j < 8; ++j) {
        const int k = kc * 32 + q * 8 + j;
        const int col = nt * 16 + l15;
        bfr[kc][nt][j] = f2bfs(W_xmix[k * 32 + col]);
      }
  float wv[2];
  wv[0] = w_vmix[l15];
  wv[1] = w_vmix[16 + l15];

  const int ntiles = (E + 15) >> 4;
  for (int t = wid; t < ntiles; t += nw) {
    const int row = t * 16 + l15;
    const int rowL = (row < E) ? row : (E - 1);
    const int ii = iperm[rowL];
    float att[4];
    #pragma unroll
    for (int hh = 0; hh < 4; ++hh)
      att[hh] = expl[(size_t)rowL * 4 + hh] / (denom[ii * 4 + hh] + EPSC);

    const v8s hech = *(const v8s*)(heb + (size_t)rowL * 32 + q * 8);
    float hef[8];
    #pragma unroll
    for (int j = 0; j < 8; ++j) hef[j] = bf2f((ushort_t)hech[j]);

    v8s afr[4];
    #pragma unroll
    for (int kc = 0; kc < 4; ++kc)
      #pragma unroll
      for (int j = 0; j < 8; ++j)
        afr[kc][j] = f2bfs(att[kc] * hef[j]);

    v4f acc[2];
    #pragma unroll
    for (int nt = 0; nt < 2; ++nt) {
      v4f a = {0.f, 0.f, 0.f, 0.f};
      #pragma unroll
      for (int kc = 0; kc < 4; ++kc)
        a = __builtin_amdgcn_mfma_f32_16x16x32_bf16(afr[kc], bfr[kc][nt], a, 0, 0, 0);
      acc[nt] = a;
    }

    const int rowb = t * 16 + q * 4;
    float pr[4];
    #pragma unroll
    for (int r = 0; r < 4; ++r) {
      const float m0 = tanhf(acc[0][r]);
      const float m1 = tanhf(acc[1][r]);
      if (rowb + r < E) {
        mixE[(size_t)(rowb + r) * 32 + l15] = f2bfu(m0);
        mixE[(size_t)(rowb + r) * 32 + 16 + l15] = f2bfu(m1);
      }
      pr[r] = m0 * wv[0] + m1 * wv[1];
    }
    #pragma unroll
    for (int r = 0; r < 4; ++r) {
      pr[r] += __shfl_xor(pr[r], 1);
      pr[r] += __shfl_xor(pr[r], 2);
      pr[r] += __shfl_xor(pr[r], 4);
      pr[r] += __shfl_xor(pr[r], 8);
      if (l15 == 0 && rowb + r < E) pE[rowb + r] = pr[r];
    }
  }
}

// ---------------------------------------------------------------------------
// node_reduce: wave per node, streaming CSR reads, 4x unrolled for MLP
// (load-latency hiding: batch 4 edges' loads before accumulating)
// ---------------------------------------------------------------------------
__global__ __launch_bounds__(256) void node_reduce(
    const int* __restrict__ rowstart,
    const ushort_t* __restrict__ heb, const ushort_t* __restrict__ mixE,
    const float* __restrict__ expl, const float* __restrict__ denom,
    const float* __restrict__ dirb, const float* __restrict__ pE,
    ushort_t* __restrict__ hsem, float* __restrict__ comb_sum,
    float* __restrict__ dv_sum, int N)
{
  const int tid = blockIdx.x * blockDim.x + threadIdx.x;
  const int wid = tid >> 6;
  const int lane = threadIdx.x & 63;
  const int nw = (gridDim.x * blockDim.x) >> 6;
  const int hh = lane >> 5;
  const int eb = lane & 31;

  for (int n = wid; n < N; n += nw) {
    const int s = rowstart[n];
    const int epd = rowstart[n + 1];
    float semA = 0.f, semB = 0.f;
    float cx = 0.f, cy = 0.f, cz = 0.f;
    float dvx = 0.f, dvy = 0.f, dvz = 0.f;
    int k = s;
    const int e4 = s + ((epd - s) & ~3);
    for (; k < e4; k += 4) {
      float he[4], ea[4], ec[4], dx[4], dy[4], dz[4], m[4], pe[4];
      #pragma unroll
      for (int u = 0; u < 4; ++u) {
        he[u] = bf2f(heb[(size_t)(k + u) * 32 + eb]);
        ea[u] = expl[(size_t)(k + u) * 4 + hh];
        ec[u] = expl[(size_t)(k + u) * 4 + 2 + hh];
        dx[u] = dirb[(k + u) * 3 + 0];
        dy[u] = dirb[(k + u) * 3 + 1];
        dz[u] = dirb[(k + u) * 3 + 2];
      }
      if (lane < 32) {
        #pragma unroll
        for (int u = 0; u < 4; ++u)
          m[u] = bf2f(mixE[(size_t)(k + u) * 32 + lane]);
      }
      if (lane == 0) {
        #pragma unroll
        for (int u = 0; u < 4; ++u) pe[u] = pE[k + u];
      }
      #pragma unroll
      for (int u = 0; u < 4; ++u) {
        semA += ea[u] * he[u];
        semB += ec[u] * he[u];
        if (lane < 32) {
          cx += dx[u] * m[u]; cy += dy[u] * m[u]; cz += dz[u] * m[u];
        }
        if (lane == 0) {
          dvx += dx[u] * pe[u]; dvy += dy[u] * pe[u]; dvz += dz[u] * pe[u];
        }
      }
    }
    for (; k < epd; ++k) {
      const float he = bf2f(heb[(size_t)k * 32 + eb]);
      const float ea = expl[(size_t)k * 4 + hh];
      const float ec = expl[(size_t)k * 4 + 2 + hh];
      semA += ea * he;
      semB += ec * he;
      const float dx = dirb[k * 3 + 0];
      const float dy = dirb[k * 3 + 1];
      const float dz = dirb[k * 3 + 2];
      if (lane < 32) {
        const float m = bf2f(mixE[(size_t)k * 32 + lane]);
        cx += dx * m; cy += dy * m; cz += dz * m;
      }
      if (lane == 0) {
        const float pe = pE[k];
        dvx += dx * pe; dvy += dy * pe; dvz += dz * pe;
      }
    }
    const float dA = denom[n * 4 + hh] + EPSC;
    const float dB = denom[n * 4 + 2 + hh] + EPSC;
    hsem[(size_t)n * 128 + lane] = f2bfu(semA / dA);
    hsem[(size_t)n * 128 + 64 + lane] = f2bfu(semB / dB);
    if (lane < 32) {
      comb_sum[(size_t)n * 96 + lane * 3 + 0] = cx;
      comb_sum[(size_t)n * 96 + lane * 3 + 1] = cy;
      comb_sum[(size_t)n * 96 + lane * 3 + 2] = cz;
    }
    if (lane == 0) {
      dv_sum[n * 3 + 0] = dvx;
      dv_sum[n * 3 + 1] = dvy;
      dv_sum[n * 3 + 2] = dvz;
    }
  }
}

// ---------------------------------------------------------------------------
// C1 (MFMA): spatial MLP (post1/post2) + node1 -> nh bf16 [N,128]
// ---------------------------------------------------------------------------
#define W1S 232
__global__ __launch_bounds__(256) void node_c1_mfma(
    const ushort_t* __restrict__ h_bf, const ushort_t* __restrict__ hsem,
    const float* __restrict__ comb_sum, const float* __restrict__ counts,
    const float* __restrict__ W_post1, const float* __restrict__ b_post1,
    const float* __restrict__ W_post2, const float* __restrict__ b_post2,
    const float* __restrict__ W_node1, const float* __restrict__ b_node1,
    ushort_t* __restrict__ nh_out, int N)
{
  __shared__ ushort_t sW1t[128 * W1S];
  __shared__ ushort_t tp[4][16 * THS];

  const int tid = threadIdx.x;
  for (int idx = tid; idx < 224 * 128; idx += 256) {
    const int k = idx >> 7;
    const int c = idx & 127;
    sW1t[c * W1S + k] = f2bfu(W_node1[idx]);
  }
  __syncthreads();

  const int lane = tid & 63;
  const int w = tid >> 6;
  const int l15 = lane & 15;
  const int q = lane >> 4;

  v8s bp1[4];
  #pragma unroll
  for (int nt = 0; nt < 4; ++nt)
    #pragma unroll
    for (int j = 0; j < 8; ++j)
      bp1[nt][j] = f2bfs(W_post1[(q * 8 + j) * 64 + nt * 16 + l15]);
  v8s bp2[2][2];
  #pragma unroll
  for (int kc = 0; kc < 2; ++kc)
    #pragma unroll
    for (int nt = 0; nt < 2; ++nt)
      #pragma unroll
      for (int j = 0; j < 8; ++j)
        bp2[kc][nt][j] = f2bfs(W_post2[(kc * 32 + q * 8 + j) * 32 + nt * 16 + l15]);
  float bb1[4];
  #pragma unroll
  for (int nt = 0; nt < 4; ++nt) bb1[nt] = b_post1[nt * 16 + l15];
  float bb2[2];
  #pragma unroll
  for (int nt = 0; nt < 2; ++nt) bb2[nt] = b_post2[nt * 16 + l15];
  float b1[8];
  #pragma unroll
  for (int nt = 0; nt < 8; ++nt) b1[nt] = b_node1[nt * 16 + l15];

  const int gw = blockIdx.x * 4 + w;
  const int nwv = gridDim.x * 4;
  const int ntiles = (N + 15) >> 4;

  for (int t = gw; t < ntiles; t += nwv) {
    const int row = t * 16 + l15;
    const int rowL = (row < N) ? row : (N - 1);

    const float inv = 1.0f / fmaxf(counts[rowL], 1.0f);
    const float4* cs = (const float4*)(comb_sum + (size_t)rowL * 96 + q * 24);
    float cf[24];
    #pragma unroll
    for (int b = 0; b < 6; ++b) {
      const float4 cv = cs[b];
      cf[b * 4 + 0] = cv.x; cf[b * 4 + 1] = cv.y;
      cf[b * 4 + 2] = cv.z; cf[b * 4 + 3] = cv.w;
    }
    v8s a1;
    #pragma unroll
    for (int j = 0; j < 8; ++j) {
      const float vx = cf[j * 3 + 0] * inv;
      const float vy = cf[j * 3 + 1] * inv;
      const float vz = cf[j * 3 + 2] * inv;
      a1[j] = f2bfs(vx * vx + vy * vy + vz * vz);
    }

    v4f p1[4];
    #pragma unroll
    for (int nt = 0; nt < 4; ++nt) {
      v4f a = {0.f, 0.f, 0.f, 0.f};
      p1[nt] = __builtin_amdgcn_mfma_f32_16x16x32_bf16(a1, bp1[nt], a, 0, 0, 0);
    }
    #pragma unroll
    for (int nt = 0; nt < 4; ++nt)
      #pragma unroll
      for (int r = 0; r < 4; ++r)
        tp[w][(q * 4 + r) * THS + nt * 16 + l15] =
            f2bfu(siluf(p1[nt][r] + bb1[nt]));
    __builtin_amdgcn_wave_barrier();

    v8s a2[2];
    a2[0] = *(const v8s*)&tp[w][l15 * THS + q * 8];
    a2[1] = *(const v8s*)&tp[w][l15 * THS + 32 + q * 8];

    v4f p2[2];
    #pragma unroll
    for (int nt = 0; nt < 2; ++nt) {
      v4f a = {0.f, 0.f, 0.f, 0.f};
      #pragma unroll
      for (int kc = 0; kc < 2; ++kc)
        a = __builtin_amdgcn_mfma_f32_16x16x32_bf16(a2[kc], bp2[kc][nt], a, 0, 0, 0);
      p2[nt] = a;
    }
    __builtin_amdgcn_wave_barrier();
    #pragma unroll
    for (int nt = 0; nt < 2; ++nt)
      #pragma unroll
      for (int r = 0; r < 4; ++r)
        tp[w][(q * 4 + r) * THS + nt * 16 + l15] =
            f2bfu(siluf(p2[nt][r] + bb2[nt]));
    __builtin_amdgcn_wave_barrier();

    v8s af[7];
    af[0] = *(const v8s*)(h_bf + (size_t)rowL * 64 + q * 8);
    af[1] = *(const v8s*)(h_bf + (size_t)rowL * 64 + 32 + q * 8);
    #pragma unroll
    for (int kc = 0; kc < 4; ++kc)
      af[2 + kc] = *(const v8s*)(hsem + (size_t)rowL * 128 + kc * 32 + q * 8);
    af[6] = *(const v8s*)&tp[w][l15 * THS + q * 8];

    v4f acc[8];
    #pragma unroll
    for (int nt = 0; nt < 8; ++nt) acc[nt] = (v4f){0.f, 0.f, 0.f, 0.f};
    #pragma unroll
    for (int kc = 0; kc < 7; ++kc) {
      #pragma unroll
      for (int nt = 0; nt < 8; ++nt) {
        const v8s bfrag =
            *(const v8s*)&sW1t[(nt * 16 + l15) * W1S + kc * 32 + q * 8];
        acc[nt] = __builtin_amdgcn_mfma_f32_16x16x32_bf16(af[kc], bfrag, acc[nt], 0, 0, 0);
      }
    }

    const int rowb = t * 16 + q * 4;
    #pragma unroll
    for (int nt = 0; nt < 8; ++nt) {
      #pragma unroll
      for (int r = 0; r < 4; ++r)
        if (rowb + r < N)
          nh_out[(size_t)(rowb + r) * 128 + nt * 16 + l15] =
              f2bfu(siluf(acc[nt][r] + b1[nt]));
    }
  }
}

// ---------------------------------------------------------------------------
// C2 (MFMA): node2 + vel1 + gate + v/x update
// ---------------------------------------------------------------------------
__global__ __launch_bounds__(256) void node_c2_mfma(
    const float* __restrict__ h, const float* __restrict__ x,
    const float* __restrict__ v, const ushort_t* __restrict__ nh,
    const float* __restrict__ dv_sum, const float* __restrict__ counts,
    const float* __restrict__ W_node2, const float* __restrict__ b_node2,
    const float* __restrict__ W_vel1, const float* __restrict__ b_vel1,
    const float* __restrict__ W_vel2,
    float* __restrict__ out, int N)
{
  __shared__ ushort_t sW2[16 * 64 * 8];
  __shared__ ushort_t sWv[4 * 64 * 8];
  __shared__ ushort_t tH[4][16 * THS];
  __shared__ float sg[4][16];

  const int tid = threadIdx.x;
  for (int idx = tid; idx < 16 * 64 * 8; idx += 256) {
    const int j = idx & 7;
    const int ln = (idx >> 3) & 63;
    const int f = idx >> 9;
    const int k = (f >> 2) * 32 + (ln >> 4) * 8 + j;
    const int col = (f & 3) * 16 + (ln & 15);
    sW2[idx] = f2bfu(W_node2[k * 64 + col]);
  }
  for (int idx = tid; idx < 4 * 64 * 8; idx += 256) {
    const int j = idx & 7;
    const int ln = (idx >> 3) & 63;
    const int f = idx >> 9;
    const int k = (f >> 1) * 32 + (ln >> 4) * 8 + j;
    const int col = (f & 1) * 16 + (ln & 15);
    sWv[idx] = f2bfu(W_vel1[k * 32 + col]);
  }
  __syncthreads();

  const int lane = tid & 63;
  const int w = tid >> 6;
  const int l15 = lane & 15;
  const int q = lane >> 4;

  const ushort_t* w2l = sW2 + lane * 8;
  const ushort_t* wvl = sWv + lane * 8;

  float b2[4];
  #pragma unroll
  for (int nt = 0; nt < 4; ++nt) b2[nt] = b_node2[nt * 16 + l15];
  float bv[2];
  #pragma unroll
  for (int nt = 0; nt < 2; ++nt) bv[nt] = b_vel1[nt * 16 + l15];
  float wv2[2];
  #pragma unroll
  for (int nt = 0; nt < 2; ++nt) wv2[nt] = W_vel2[nt * 16 + l15];

  const int gw = blockIdx.x * 4 + w;
  const int nwv = gridDim.x * 4;
  const int ntiles = (N + 15) >> 4;

  for (int t = gw; t < ntiles; t += nwv) {
    const int row = t * 16 + l15;
    const int rowL = (row < N) ? row : (N - 1);

    v8s af[4];
    #pragma unroll
    for (int kc = 0; kc < 4; ++kc)
      af[kc] = *(const v8s*)(nh + (size_t)rowL * 128 + kc * 32 + q * 8);

    v4f acc[4];
    #pragma unroll
    for (int nt = 0; nt < 4; ++nt) {
      v4f a = {0.f, 0.f, 0.f, 0.f};
      #pragma unroll
      for (int kc = 0; kc < 4; ++kc) {
        const v8s bfrag = *(const v8s*)(w2l + (kc * 4 + nt) * 512);
        a = __builtin_amdgcn_mfma_f32_16x16x32_bf16(af[kc], bfrag, a, 0, 0, 0);
      }
      acc[nt] = a;
    }

    const int rowb = t * 16 + q * 4;
    #pragma unroll
    for (int nt = 0; nt < 4; ++nt) {
      const int col = nt * 16 + l15;
      #pragma unroll
      for (int r = 0; r < 4; ++r) {
        const int n = rowb + r;
        if (n < N) {
          const float hu = h[(size_t)n * 64 + col] + siluf(acc[nt][r] + b2[nt]);
          out[(size_t)n * 64 + col] = hu;
          tH[w][(q * 4 + r) * THS + col] = f2bfu(hu);
        }
      }
    }
    __builtin_amdgcn_wave_barrier();

    v8s a2[2];
    a2[0] = *(const v8s*)&tH[w][l15 * THS + q * 8];
    a2[1] = *(const v8s*)&tH[w][l15 * THS + 32 + q * 8];
    v4f av[2];
    #pragma unroll
    for (int nt = 0; nt < 2; ++nt) {
      v4f a = {0.f, 0.f, 0.f, 0.f};
      #pragma unroll
      for (int kc = 0; kc < 2; ++kc) {
        const v8s bfrag = *(const v8s*)(wvl + (kc * 2 + nt) * 512);
        a = __builtin_amdgcn_mfma_f32_16x16x32_bf16(a2[kc], bfrag, a, 0, 0, 0);
      }
      av[nt] = a;
    }

    #pragma unroll
    for (int r = 0; r < 4; ++r) {
      float pr = siluf(av[0][r] + bv[0]) * wv2[0] +
                 siluf(av[1][r] + bv[1]) * wv2[1];
      pr += __shfl_xor(pr, 1);
      pr += __shfl_xor(pr, 2);
      pr += __shfl_xor(pr, 4);
      pr += __shfl_xor(pr, 8);
      if (l15 == 0) sg[w][q * 4 + r] = 2.0f / (1.0f + __expf(-pr));
    }
    __builtin_amdgcn_wave_barrier();

    if (lane < 48) {
      const int rr = lane / 3;
      const int c = lane % 3;
      const int n = t * 16 + rr;
      if (n < N) {
        const float gate = sg[w][rr];
        const float cnt = fmaxf(counts[n], 1.0f);
        const float dv = dv_sum[n * 3 + c] / cnt;
        const float vu = gate * v[n * 3 + c] + dv;
        out[(size_t)N * 64 + (size_t)n * 3 + c] = x[n * 3 + c] + vu;
        out[(size_t)N * 64 + (size_t)N * 3 + (size_t)n * 3 + c] = vu;
      }
    }
    __builtin_amdgcn_wave_barrier();
  }
}

// ---------------------------------------------------------------------------
extern "C" void kernel_launch(void* const* d_in, const int* in_sizes, int n_in,
                              void* d_out, int out_size, void* d_ws, size_t ws_size,
                              hipStream_t stream) {
  const float* h   = (const float*)d_in[0];
  const float* x   = (const float*)d_in[1];
  const float* v   = (const float*)d_in[2];
  const int* idx_i = (const int*)d_in[3];
  const int* idx_j = (const int*)d_in[4];
  const float* W_edge_in  = (const float*)d_in[5];
  const float* b_edge_in  = (const float*)d_in[6];
  const float* W_edge_h   = (const float*)d_in[7];
  const float* b_edge_h   = (const float*)d_in[8];
  const float* W_edge_out = (const float*)d_in[9];
  const float* b_edge_out = (const float*)d_in[10];
  const float* W_att      = (const float*)d_in[11];
  const float* b_att      = (const float*)d_in[12];
  const float* W_x_mix    = (const float*)d_in[13];
  const float* W_node1    = (const float*)d_in[14];
  const float* b_node1    = (const float*)d_in[15];
  const float* W_node2    = (const float*)d_in[16];
  const float* b_node2    = (const float*)d_in[17];
  const float* W_post1    = (const float*)d_in[18];
  const float* b_post1    = (const float*)d_in[19];
  const float* W_post2    = (const float*)d_in[20];
  const float* b_post2    = (const float*)d_in[21];
  const float* W_vel1     = (const float*)d_in[22];
  const float* b_vel1     = (const float*)d_in[23];
  const float* W_vel2     = (const float*)d_in[24];
  const float* w_v_mix    = (const float*)d_in[25];

  const int E = in_sizes[3];
  const int N = in_sizes[0] / DA;

  float* ws = (float*)d_ws;
  size_t off = 0;
  float* denom    = ws + off; off += (size_t)N * 4;     // zeroed
  int*   deg      = (int*)(ws + off); off += (size_t)N; // zeroed
  const size_t zeroBytes = off * sizeof(float);
  float* counts   = ws + off; off += (size_t)N;
  int*   rowstart = (int*)(ws + off); off += (size_t)N + 4;
  int*   cursor   = (int*)(ws + off); off += (size_t)N;
  int*   tsum     = (int*)(ws + off); off += (size_t)SCAN_T;
  int*   iperm    = (int*)(ws + off); off += (size_t)E;
  int*   jperm    = (int*)(ws + off); off += (size_t)E;
  float* pE       = ws + off; off += (size_t)E;
  float* expl     = ws + off; off += (size_t)E * 4;
  float* dirb     = ws + off; off += (size_t)E * 3;
  float* hsemR    = ws + off; off += (size_t)N * 64;    // hsem bf16 [N,128]
  float* comb_sum = ws + off; off += (size_t)N * 96;
  float* dv_sum   = ws + off; off += (size_t)N * 4;
  float* hbfR     = ws + off; off += (size_t)N * 32;    // h_bf bf16 [N,64]
  float* fltR     = ws + off; off += (size_t)E * 16;    // mixE / nh
  float* hebR     = ws + off; off += (size_t)E * 16;    // heb bf16 [E,32]

  ushort_t* h_bf = (ushort_t*)hbfR;
  ushort_t* hsem = (ushort_t*)hsemR;
  ushort_t* heb  = (ushort_t*)hebR;
  ushort_t* mixE = (ushort_t*)fltR;
  ushort_t* nh   = (ushort_t*)fltR;  // aliases mixE (dead after node_reduce)

  hipMemsetAsync(d_ws, 0, zeroBytes, stream);

  {
    const int n4 = (N * 64) / 4;
    cast_h<<<(n4 + 255) / 256, 256, 0, stream>>>(h, h_bf, n4);
  }
  deg_count<<<512, 256, 0, stream>>>(idx_i, deg, E);
  {
    const int C = (N + SCAN_T - 1) / SCAN_T;
    deg_tsum<<<SCAN_B, 256, 0, stream>>>(deg, tsum, N, C);
    scan_tsum<<<1, 256, 0, stream>>>(tsum);
    write_csr<<<SCAN_B, 256, 0, stream>>>(deg, tsum, rowstart, cursor, counts, N, C);
  }
  bucket_edges<<<512, 256, 0, stream>>>(idx_i, idx_j, cursor, iperm, jperm, E);
  edge_f12<<<1024, 256, 0, stream>>>(h_bf, x, iperm, jperm,
                                     W_edge_in, b_edge_in, W_edge_h, b_edge_h,
                                     W_edge_out, b_edge_out, W_att, b_att,
                                     dirb, heb, expl, denom, E);
  mix_kernel<<<1024, 256, 0, stream>>>(heb, iperm, expl, denom, W_x_mix,
                                       w_v_mix, mixE, pE, E);
  node_reduce<<<2048, 256, 0, stream>>>(rowstart, heb, mixE, expl, denom,
                                        dirb, pE, hsem, comb_sum, dv_sum, N);
  node_c1_mfma<<<512, 256, 0, stream>>>(
      h_bf, hsem, comb_sum, counts, W_post1, b_post1, W_post2, b_post2,
      W_node1, b_node1, nh, N);
  node_c2_mfma<<<512, 256, 0, stream>>>(
      h, x, v, nh, dv_sum, counts, W_node2, b_node2, W_vel1, b_vel1, W_vel2,
      (float*)d_out, N);
}